// Round 3
// baseline (4898.932 us; speedup 1.0000x reference)
//
#include <hip/hip_runtime.h>

#define TT 2048
#define EE 400
#define HH 200
#define G4 800
#define NS 20480
#define WMAX 10
#define HS 150
#define FD 20
#define GDIM 1220
#define NK 384
#define NA 128
#define OUTC 129

typedef unsigned int uint;
typedef unsigned short ushort;
typedef _Float16 half4 __attribute__((ext_vector_type(4)));

__device__ __forceinline__ float bf2f(ushort u){ return __uint_as_float(((uint)u)<<16); }
__device__ __forceinline__ int binv(int x){
  int b=0;
  b += (x>=1); b += (x>=2); b += (x>=3); b += (x>=4);
  b += (x>=8); b += (x>=16); b += (x>=32); b += (x>=64);
  return b;
}
__device__ __forceinline__ float sigf(float x){ return 1.0f/(1.0f+__expf(-x)); }
__device__ __forceinline__ float tanhf_fast(float x){
  float t = __expf(-2.0f*fabsf(x));       // in (0,1], never overflows
  float r = (1.0f - t)/(1.0f + t);
  return copysignf(r, x);
}
__device__ __forceinline__ float sanit(float x){ return (fabsf(x) <= 1e30f) ? x : 0.f; }

__device__ __forceinline__ int sdot4(int a, int b, int c){
#if __has_builtin(__builtin_amdgcn_sdot4)
  return __builtin_amdgcn_sdot4(a, b, c, false);
#else
  int r = c;
  r += (int)(signed char)(a)     * (int)(signed char)(b);
  r += (int)(signed char)(a>>8)  * (int)(signed char)(b>>8);
  r += (int)(signed char)(a>>16) * (int)(signed char)(b>>16);
  r += (int)(signed char)(a>>24) * (int)(signed char)(b>>24);
  return r;
#endif
}

// LDS-only barrier: orders ds ops across the workgroup WITHOUT draining vmcnt
// (global stores/loads stay in flight). Compiler-visible (no inline asm), so
// vmcnt bookkeeping for the X prefetch stays precise. If the toolchain ignores
// the "local" AS hint this degrades to a full fence (= __syncthreads perf).
__device__ __forceinline__ void barrier_lds_only(){
  __builtin_amdgcn_fence(__ATOMIC_RELEASE, "workgroup", "local");
  __builtin_amdgcn_s_barrier();
  __builtin_amdgcn_fence(__ATOMIC_ACQUIRE, "workgroup", "local");
}

// pack 4 dims (4n..4n+3) of a bf16 row into one int8 uint
__device__ __forceinline__ uint p4(const ushort* __restrict__ row, int n, float inv){
  uint r = 0;
#pragma unroll
  for (int b=0;b<4;++b){
    float w = bf2f(row[4*n+b]);
    int q = (int)rintf(w * inv);
    q = q < -127 ? -127 : (q > 127 ? 127 : q);
    r |= ((uint)(q & 0xff)) << (8*b);
  }
  return r;
}

// ---------------- K2: LSTM input projections (direct emb gather, f16 out) ----------------
// X layout: [t][j*4 + gate]  so k_lstm reads all 4 gate inputs of row j with ONE 8B load.
__global__ void k_xproj(const int* __restrict__ tok, const ushort* __restrict__ emb,
                        const ushort* __restrict__ wf, const ushort* __restrict__ bfv,
                        const ushort* __restrict__ wb, const ushort* __restrict__ bbv,
                        _Float16* __restrict__ Xf, _Float16* __restrict__ Xb){
  __shared__ float x4[4][EE];
  __shared__ int tk[4];
  int t0 = blockIdx.x*4;
  if (threadIdx.x < 4) tk[threadIdx.x] = tok[t0+threadIdx.x];
  __syncthreads();
  for (int i = threadIdx.x; i < 4*EE; i += 256){
    int m = i / EE, e = i - m*EE;
    x4[m][e] = bf2f(emb[tk[m]*EE + e]);
  }
  __syncthreads();
  for (int tt = threadIdx.x; tt < 2*G4; tt += 256){
    int dir = (tt >= G4);
    int row = dir ? tt - G4 : tt;
    const ushort* wr = (dir ? wb : wf) + row*EE;
    float bias = bf2f((dir ? bbv : bfv)[row]);
    float a0=bias,a1=bias,a2=bias,a3=bias;
    for (int k=0;k<EE;k+=4){
      ushort4 wv = *(const ushort4*)(wr+k);
      float w0=bf2f(wv.x), w1=bf2f(wv.y), w2=bf2f(wv.z), w3=bf2f(wv.w);
      a0 += w0*x4[0][k] + w1*x4[0][k+1] + w2*x4[0][k+2] + w3*x4[0][k+3];
      a1 += w0*x4[1][k] + w1*x4[1][k+1] + w2*x4[1][k+2] + w3*x4[1][k+3];
      a2 += w0*x4[2][k] + w1*x4[2][k+1] + w2*x4[2][k+2] + w3*x4[2][k+3];
      a3 += w0*x4[3][k] + w1*x4[3][k+1] + w2*x4[3][k+2] + w3*x4[3][k+3];
    }
    _Float16* X = dir ? Xb : Xf;
    int g = row / HH, jj = row - g*HH;
    int col = jj*4 + g;
    X[(t0+0)*G4+col]=(_Float16)a0; X[(t0+1)*G4+col]=(_Float16)a1;
    X[(t0+2)*G4+col]=(_Float16)a2; X[(t0+3)*G4+col]=(_Float16)a3;
  }
}

// ---------------- K3: sequential bi-LSTM (block0=fwd, block1=bwd) ----------------
// Weights in registers (int8, 25 uint4/lane). Per step: prefetch next-step X
// (one 8B load, consumed NEXT iteration), 7 broadcast LDS h reads, 100 sdot4,
// shfl-pair reduce, activations. Barrier = LDS-only fence + s_barrier: the
// global hout store and the X prefetch stay in flight across it, and (unlike
// the asm variant) vmcnt tracking stays precise so the prefetch never forces
// a vmcnt(0) drain at its use.
__global__ __launch_bounds__(448, 2) void k_lstm(const ushort* __restrict__ whh_f,
                        const ushort* __restrict__ whh_b,
                        const _Float16* __restrict__ Xf, const _Float16* __restrict__ Xb,
                        float* __restrict__ hf, float* __restrict__ hb){
  __shared__ __align__(16) uint  hq[112];       // 2 x 224-B int8 h buffers (28dw halves)
  const int tid = threadIdx.x;
  const int fwd = (blockIdx.x == 0);
  const ushort* whh = fwd ? whh_f : whh_b;
  const _Float16* X = fwd ? Xf : Xb;
  float* hout = fwd ? hf : hb;
  const bool act = (tid < 400);
  const int j = tid >> 1;                // 0..199
  const int half = tid & 1;              // dim half

  uint4 wreg[25];                        // per-lane int8 weights, in registers
  float mx0=1e-20f, mx1=1e-20f, mx2=1e-20f, mx3=1e-20f;
  if (act){
    const ushort* r0 = whh + (0*HH + j)*HH + half*100;
    const ushort* r1 = whh + (1*HH + j)*HH + half*100;
    const ushort* r2 = whh + (2*HH + j)*HH + half*100;
    const ushort* r3 = whh + (3*HH + j)*HH + half*100;
    for (int d=0; d<100; d+=2){
      ushort2 v0 = *(const ushort2*)(r0+d);
      ushort2 v1 = *(const ushort2*)(r1+d);
      ushort2 v2 = *(const ushort2*)(r2+d);
      ushort2 v3 = *(const ushort2*)(r3+d);
      mx0 = fmaxf(mx0, fmaxf(fabsf(bf2f(v0.x)), fabsf(bf2f(v0.y))));
      mx1 = fmaxf(mx1, fmaxf(fabsf(bf2f(v1.x)), fabsf(bf2f(v1.y))));
      mx2 = fmaxf(mx2, fmaxf(fabsf(bf2f(v2.x)), fabsf(bf2f(v2.y))));
      mx3 = fmaxf(mx3, fmaxf(fabsf(bf2f(v3.x)), fabsf(bf2f(v3.y))));
    }
    float i0=127.f/mx0, i1=127.f/mx1, i2=127.f/mx2, i3=127.f/mx3;
#pragma unroll
    for (int n=0;n<25;++n){
      uint4 wv;
      wv.x = p4(r0,n,i0); wv.y = p4(r1,n,i1); wv.z = p4(r2,n,i2); wv.w = p4(r3,n,i3);
      wreg[n] = wv;
    }
  }
  const float sc0 = mx0*(1.f/16129.f), sc1 = mx1*(1.f/16129.f);
  const float sc2 = mx2*(1.f/16129.f), sc3 = mx3*(1.f/16129.f);
  if (tid < 112) hq[tid] = 0u;
  float c = 0.f;
  // prefetch X for step 0
  half4 xv = half4{0,0,0,0};
  if (act) xv = *(const half4*)(X + (fwd ? 0 : (TT-1))*G4 + (j<<2));
  __syncthreads();
  for (int step=0; step<TT; ++step){
    int ts = fwd ? step : (TT-1-step);
    if (act){
      // prefetch next step's X early: consumed only next iteration
      int sn = (step+1 < TT) ? (step+1) : step;
      int tsn = fwd ? sn : (TT-1-sn);
      half4 xvn = *(const half4*)(X + tsn*G4 + (j<<2));
      // h window for this half (broadcast across lanes)
      const uint* hbp = hq + (step&1)*56 + half*28;
      uint4 hA = *(const uint4*)(hbp+0);
      uint4 hB = *(const uint4*)(hbp+4);
      uint4 hC = *(const uint4*)(hbp+8);
      uint4 hD = *(const uint4*)(hbp+12);
      uint4 hE = *(const uint4*)(hbp+16);
      uint4 hF = *(const uint4*)(hbp+20);
      uint  hG = hbp[24];
      int d0=0,d1=0,d2=0,d3=0;
#define DD(n,hu) { uint4 wv = wreg[n]; \
  d0=sdot4((int)wv.x,(int)(hu),d0); d1=sdot4((int)wv.y,(int)(hu),d1); \
  d2=sdot4((int)wv.z,(int)(hu),d2); d3=sdot4((int)wv.w,(int)(hu),d3); }
      DD(0,hA.x) DD(1,hA.y) DD(2,hA.z) DD(3,hA.w)
      DD(4,hB.x) DD(5,hB.y) DD(6,hB.z) DD(7,hB.w)
      DD(8,hC.x) DD(9,hC.y) DD(10,hC.z) DD(11,hC.w)
      DD(12,hD.x) DD(13,hD.y) DD(14,hD.z) DD(15,hD.w)
      DD(16,hE.x) DD(17,hE.y) DD(18,hE.z) DD(19,hE.w)
      DD(20,hF.x) DD(21,hF.y) DD(22,hF.z) DD(23,hF.w)
      DD(24,hG)
#undef DD
      float a0 = (float)d0*sc0 + (float)xv.x*0.5f;
      float a1 = (float)d1*sc1 + (float)xv.y*0.5f;
      float a2 = (float)d2*sc2 + (float)xv.z*0.5f;
      float a3 = (float)d3*sc3 + (float)xv.w*0.5f;
      // sum the two dim-halves (x added half in each lane -> once total)
      a0 += __shfl_xor(a0, 1, 64);
      a1 += __shfl_xor(a1, 1, 64);
      a2 += __shfl_xor(a2, 1, 64);
      a3 += __shfl_xor(a3, 1, 64);
      // gates: 0=i, 1=f, 2=g, 3=o
      c = sigf(a1)*c + sigf(a0)*tanhf_fast(a2);
      float h = sigf(a3)*tanhf_fast(c);
      if (half == 0){
        hout[ts*HH + j] = h;             // fire-and-forget: never drained per-step
        int q = (int)rintf(h*127.f);
        q = q<-127?-127:(q>127?127:q);
        int bufbyte = ((step+1)&1)*224 + (j<100 ? j : 112 + (j-100));
        ((unsigned char*)hq)[bufbyte] = (unsigned char)(q & 0xff);
      }
      xv = xvn;
    }
    // LDS-only barrier: h double-buffer visibility without vmcnt drain
    barrier_lds_only();
  }
}

// ---------------- K4: token attention-score MLP ----------------
__global__ void k_attn(const float* __restrict__ hf, const float* __restrict__ hb,
    const ushort* w1, const ushort* b1, const ushort* w2, const ushort* b2,
    const ushort* w3, const ushort* b3, float* __restrict__ attns){
  __shared__ float s[2*HH];
  __shared__ float h1[HS], h2[HS];
  int t = blockIdx.x;
  for (int k=threadIdx.x;k<2*HH;k+=256)
    s[k] = (k<HH) ? hf[t*HH+k] : hb[t*HH + (k-HH)];
  __syncthreads();
  int o = threadIdx.x;
  if (o < HS){
    float acc = bf2f(b1[o]);
    const ushort* wr = w1 + o*2*HH;
    for (int k=0;k<2*HH;k+=4){
      ushort4 wv = *(const ushort4*)(wr+k);
      acc += bf2f(wv.x)*s[k] + bf2f(wv.y)*s[k+1] + bf2f(wv.z)*s[k+2] + bf2f(wv.w)*s[k+3];
    }
    h1[o] = fmaxf(acc, 0.f);
  }
  __syncthreads();
  if (o < HS){
    float acc = bf2f(b2[o]);
    const ushort* wr = w2 + o*HS;
    for (int k=0;k<HS;k+=2) acc += bf2f(wr[k])*h1[k] + bf2f(wr[k+1])*h1[k+1];
    h2[o] = fmaxf(acc, 0.f);
  }
  __syncthreads();
  if (o == 0){
    float acc = bf2f(b3[0]);
    for (int k=0;k<HS;k++) acc += bf2f(w3[k])*h2[k];
    attns[t] = acc;
  }
}

// ---------------- K5: span features + mention MLP (8 spans/block) ----------------
__global__ void k_ment(const int* __restrict__ sstart, const int* __restrict__ send,
    const int* __restrict__ tok,
    const float* __restrict__ hf, const float* __restrict__ hb,
    const ushort* __restrict__ emb, const float* __restrict__ attns,
    const ushort* wemb,
    const ushort* w1, const ushort* b1, const ushort* w2, const ushort* b2,
    const ushort* w3, const ushort* b3, float* __restrict__ si){
  __shared__ __align__(16) float G[8][GDIM];
  __shared__ float H1[8][152], H2[8][152];
  __shared__ float aw[8][WMAX];
  __shared__ int stok[8][WMAX];
  __shared__ int sst[8], sen[8], sbin[8];
  int s0 = blockIdx.x*8;
  if (threadIdx.x < 8){
    int sp = threadIdx.x;
    int st = sstart[s0+sp], en = send[s0+sp];
    sst[sp]=st; sen[sp]=en;
    int width = en - st + 1;
    sbin[sp] = binv(width);
    float lg[WMAX]; float mx = -1e30f;
    for (int wt=0; wt<WMAX; ++wt){
      int idx = st + wt; if (idx > TT-1) idx = TT-1;
      float l = (wt < width) ? attns[idx] : -1e9f;
      lg[wt] = l; mx = fmaxf(mx, l);
    }
    float den = 0.f;
    for (int wt=0; wt<WMAX; ++wt){ lg[wt] = __expf(lg[wt]-mx); den += lg[wt]; }
    float inv = 1.f/den;
    for (int wt=0; wt<WMAX; ++wt) aw[sp][wt] = lg[wt]*inv;
  }
  if (threadIdx.x < 8*WMAX){
    int sp = threadIdx.x / WMAX, wt = threadIdx.x - sp*WMAX;
    int idx = sstart[s0+sp] + wt; if (idx > TT-1) idx = TT-1;
    stok[sp][wt] = tok[idx];
  }
  __syncthreads();
  for (int i = threadIdx.x; i < 8*GDIM; i += 256){
    int sp = i / GDIM, f = i - sp*GDIM;
    int st = sst[sp], en = sen[sp];
    float v;
    if (f < HH) v = hf[st*HH + f];
    else if (f < 2*HH) v = hb[st*HH + (f-HH)];
    else if (f < 3*HH) v = hf[en*HH + (f-2*HH)];
    else if (f < 4*HH) v = hb[en*HH + (f-3*HH)];
    else if (f < 4*HH + EE){
      int e = f - 4*HH;
      float acc = 0.f;
      for (int wt=0; wt<WMAX; ++wt)
        acc += aw[sp][wt] * bf2f(emb[stok[sp][wt]*EE + e]);
      v = acc;
    } else {
      v = bf2f(wemb[sbin[sp]*FD + (f - (4*HH+EE))]);
    }
    G[sp][f] = v;
  }
  __syncthreads();
  for (int tt = threadIdx.x; tt < 8*HS; tt += 256){
    int sp = tt & 7, o = tt >> 3;
    float acc = bf2f(b1[o]);
    const ushort* wr = w1 + o*GDIM;
    for (int k=0;k<GDIM;k+=4){
      ushort4 wv = *(const ushort4*)(wr+k);
      acc += bf2f(wv.x)*G[sp][k] + bf2f(wv.y)*G[sp][k+1]
           + bf2f(wv.z)*G[sp][k+2] + bf2f(wv.w)*G[sp][k+3];
    }
    H1[sp][o] = fmaxf(acc, 0.f);
  }
  __syncthreads();
  for (int tt = threadIdx.x; tt < 8*HS; tt += 256){
    int sp = tt & 7, o = tt >> 3;
    float acc = bf2f(b2[o]);
    const ushort* wr = w2 + o*HS;
    for (int k=0;k<HS;k+=2) acc += bf2f(wr[k])*H1[sp][k] + bf2f(wr[k+1])*H1[sp][k+1];
    H2[sp][o] = fmaxf(acc, 0.f);
  }
  __syncthreads();
  if (threadIdx.x < 8){
    int sp = threadIdx.x;
    float acc = bf2f(b3[0]);
    for (int k=0;k<HS;k++) acc += bf2f(w3[k])*H2[sp][k];
    si[s0+sp] = sanit(acc);
  }
}

// ---------------- K6: top-384 + index-ordered compaction (single block) ----------------
__global__ __launch_bounds__(1024) void k_select(const float* __restrict__ si,
    const int* __restrict__ sstart, const int* __restrict__ send,
    uint* __restrict__ keysb, int* __restrict__ keep, float* __restrict__ sk,
    int* __restrict__ stk, int* __restrict__ enk){
  __shared__ uint hist[256];
  __shared__ uint sG[1024], sE[1024];
  __shared__ uint bc[2];
  int tid = threadIdx.x;
  if (tid < NK){ keep[tid]=0; sk[tid]=0.f; stk[tid]=0; enk[tid]=0; }
  for (int i=tid;i<NS;i+=1024){
    uint u = __float_as_uint(si[i]);
    uint m = (u & 0x80000000u) ? ~u : (u | 0x80000000u);  // order-preserving map
    keysb[i] = m;
  }
  __syncthreads();
  uint prefix=0, mask=0; int K = NK;
  for (int p=3;p>=0;--p){
    int sh = p*8;
    if (tid<256) hist[tid]=0;
    __syncthreads();
    for (int i=tid;i<NS;i+=1024){
      uint m = keysb[i];
      if ((m & mask) == prefix) atomicAdd(&hist[(m>>sh)&255u], 1u);
    }
    __syncthreads();
    if (tid==0){
      uint cum=0;
      bc[0]=0; bc[1]=(uint)K;
      for (int b=255; b>=0; --b){
        uint c = hist[b];
        if ((uint)K <= cum + c){ bc[0]=(uint)b; bc[1]=(uint)(K - (int)cum); break; }
        cum += c;
      }
    }
    __syncthreads();
    prefix |= bc[0] << sh;
    mask |= 0xFFu << sh;
    K = (int)bc[1];
    __syncthreads();
  }
  const uint V = prefix; const uint Eneed = (uint)K;
  int base = tid*20;
  uint cg=0, ce=0;
  for (int r=0;r<20;++r){
    uint m = keysb[base+r];
    cg += (m > V); ce += (m == V);
  }
  sG[tid]=cg; sE[tid]=ce;
  __syncthreads();
  for (int off=1; off<1024; off<<=1){
    uint aG=0,aE=0;
    if (tid>=off){ aG=sG[tid-off]; aE=sE[tid-off]; }
    __syncthreads();
    if (tid>=off){ sG[tid]+=aG; sE[tid]+=aE; }
    __syncthreads();
  }
  uint gbase = sG[tid]-cg, ebase = sE[tid]-ce;
  uint gseen=0, eseen=0;
  for (int r=0;r<20;++r){
    int i = base+r;
    uint m = keysb[i];
    if (m > V){
      uint eb = ebase+eseen; if (eb > Eneed) eb = Eneed;
      uint pos = gbase + gseen + eb;
      if (pos < NK){ keep[pos]=i; sk[pos]=si[i]; stk[pos]=sstart[i]; enk[pos]=send[i]; }
      gseen++;
    } else if (m == V){
      uint eb = ebase + eseen;
      if (eb < Eneed){
        uint pos = gbase + gseen + eb;
        if (pos < NK){ keep[pos]=i; sk[pos]=si[i]; stk[pos]=sstart[i]; enk[pos]=send[i]; }
      }
      eseen++;
    }
  }
}

// ---------------- K7: rebuild g for kept spans ----------------
__global__ void k_gk(const int* __restrict__ keep, const int* __restrict__ tok,
    const float* __restrict__ hf, const float* __restrict__ hb,
    const ushort* __restrict__ emb, const float* __restrict__ attns,
    const ushort* wemb, const int* __restrict__ sstart, const int* __restrict__ send,
    float* __restrict__ gk){
  __shared__ float aw[WMAX];
  __shared__ int stok1[WMAX];
  __shared__ int sstv, senv, sbinv;
  int b = blockIdx.x;
  if (threadIdx.x == 0){
    int s = keep[b]; s = s < 0 ? 0 : (s >= NS ? NS-1 : s);
    int st = sstart[s], en = send[s];
    sstv=st; senv=en;
    int width = en-st+1;
    sbinv = binv(width);
    float lg[WMAX]; float mx=-1e30f;
    for (int wt=0;wt<WMAX;++wt){
      int idx = st+wt; if (idx>TT-1) idx=TT-1;
      float l = (wt<width)? attns[idx] : -1e9f;
      lg[wt]=l; mx=fmaxf(mx,l);
    }
    float den=0.f;
    for (int wt=0;wt<WMAX;++wt){ lg[wt]=__expf(lg[wt]-mx); den+=lg[wt]; }
    float inv=1.f/den;
    for (int wt=0;wt<WMAX;++wt) aw[wt]=lg[wt]*inv;
  }
  if (threadIdx.x < WMAX){
    int s = keep[b]; s = s < 0 ? 0 : (s >= NS ? NS-1 : s);
    int idx = sstart[s] + threadIdx.x; if (idx>TT-1) idx=TT-1;
    stok1[threadIdx.x] = tok[idx];
  }
  __syncthreads();
  int st=sstv, en=senv;
  for (int f=threadIdx.x; f<GDIM; f+=256){
    float v;
    if (f < HH) v = hf[st*HH + f];
    else if (f < 2*HH) v = hb[st*HH + (f-HH)];
    else if (f < 3*HH) v = hf[en*HH + (f-2*HH)];
    else if (f < 4*HH) v = hb[en*HH + (f-3*HH)];
    else if (f < 4*HH + EE){
      int e = f - 4*HH;
      float acc = 0.f;
      for (int wt=0; wt<WMAX; ++wt)
        acc += aw[wt] * bf2f(emb[stok1[wt]*EE + e]);
      v = acc;
    } else {
      v = bf2f(wemb[sbinv*FD + (f - (4*HH+EE))]);
    }
    gk[b*GDIM + f] = v;
  }
}

// ---------------- K8a: P[i]=w1a.gk[i], Q[i]=w1b.gk[i]; also eps column ----------------
__global__ void k_pq(const float* __restrict__ gk, const ushort* __restrict__ w1,
                     float* __restrict__ P, float* __restrict__ Q, float* __restrict__ out){
  __shared__ __align__(16) float gi[GDIM];
  int i = blockIdx.x, which = blockIdx.y;
  for (int k=threadIdx.x;k<GDIM;k+=256) gi[k]=gk[i*GDIM+k];
  __syncthreads();
  if (which==0 && threadIdx.x==0) out[i*OUTC + NA] = 0.0f;   // eps column
  int o = threadIdx.x;
  if (o < HS){
    const ushort* wr = w1 + o*3680 + which*GDIM;
    float acc=0.f;
    for (int k=0;k<GDIM;k+=4){
      ushort4 wv = *(const ushort4*)(wr+k);
      acc += bf2f(wv.x)*gi[k]+bf2f(wv.y)*gi[k+1]+bf2f(wv.z)*gi[k+2]+bf2f(wv.w)*gi[k+3];
    }
    (which? Q : P)[i*HS+o] = acc;
  }
}

// ---------------- K8b: pair MLP (decomposed layer-1), 16 antecedents/block ----------------
__global__ void k_pair(const float* __restrict__ gk, const float* __restrict__ P,
    const float* __restrict__ Q, const float* __restrict__ sk,
    const int* __restrict__ stk, const int* __restrict__ enk,
    const ushort* w1, const ushort* b1, const ushort* w2, const ushort* b2,
    const ushort* w3, const ushort* b3, const ushort* demb, float* __restrict__ out){
  __shared__ __align__(16) float gi[GDIM];
  __shared__ float Pi[152];
  __shared__ float Dall[9*HS];
  __shared__ __align__(16) float GIJ[8][GDIM];
  __shared__ float H1[8][152], H2[8][152];
  __shared__ int jcA[16], dbA[16], vA[16];
  __shared__ float skj[16];
  int i = blockIdx.x;
  int d0 = blockIdx.y*16;
  if (i - 1 - d0 < 0){
    for (int d = threadIdx.x; d < 16; d += 256) out[i*OUTC + d0 + d] = -1e9f;
    return;
  }
  for (int k=threadIdx.x;k<GDIM;k+=256) gi[k]=gk[i*GDIM+k];
  for (int o=threadIdx.x;o<HS;o+=256) Pi[o]=P[i*HS+o];
  if (threadIdx.x < 16){
    int dcol = d0 + threadIdx.x;
    int j = i - 1 - dcol;
    int jc = j<0?0:j;
    vA[threadIdx.x]=(j>=0);
    jcA[threadIdx.x]=jc;
    dbA[threadIdx.x]=binv(enk[i]-stk[jc]);
    skj[threadIdx.x]=sk[jc];
  }
  for (int tt=threadIdx.x; tt<9*HS; tt+=256){
    int o = tt/9, b = tt - (tt/9)*9;
    float acc = bf2f(b1[o]);
    const ushort* wr = w1 + o*3680 + 3660;
    const ushort* de = demb + b*FD;
    for (int k=0;k<FD;k++) acc += bf2f(wr[k])*bf2f(de[k]);
    Dall[b*HS+o] = acc;
  }
  __syncthreads();
  float ski = sk[i];
  for (int dt=0; dt<2; ++dt){
    if (i - 1 - (d0 + dt*8) < 0){
      if (threadIdx.x < 8) out[i*OUTC + d0 + dt*8 + threadIdx.x] = -1e9f;
      continue;
    }
    __syncthreads();
    for (int idx=threadIdx.x; idx<8*GDIM; idx+=256){
      int dd = idx / GDIM, k = idx - dd*GDIM;
      GIJ[dd][k] = gi[k]*gk[jcA[dt*8+dd]*GDIM + k];
    }
    __syncthreads();
    {
      int dd = threadIdx.x & 7, og = threadIdx.x >> 3;
      for (int o=og; o<HS; o+=32){
        const ushort* wr = w1 + o*3680 + 2*GDIM;
        float acc = 0.f;
        for (int k=0;k<GDIM;k+=4){
          ushort4 wv = *(const ushort4*)(wr+k);
          float4 gv = *(const float4*)&GIJ[dd][k];
          acc += bf2f(wv.x)*gv.x + bf2f(wv.y)*gv.y + bf2f(wv.z)*gv.z + bf2f(wv.w)*gv.w;
        }
        int d = dt*8+dd;
        acc += Pi[o] + Q[jcA[d]*HS+o] + Dall[dbA[d]*HS+o];
        H1[dd][o] = fmaxf(acc, 0.f);
      }
    }
    __syncthreads();
    {
      int dd = threadIdx.x & 7, og = threadIdx.x >> 3;
      for (int o=og;o<HS;o+=32){
        float acc = bf2f(b2[o]);
        const ushort* wr = w2 + o*HS;
        for (int k=0;k<HS;k+=2) acc += bf2f(wr[k])*H1[dd][k] + bf2f(wr[k+1])*H1[dd][k+1];
        H2[dd][o]=fmaxf(acc,0.f);
      }
    }
    __syncthreads();
    if (threadIdx.x < 8){
      int dd = threadIdx.x;
      float acc = bf2f(b3[0]);
      for (int k=0;k<HS;k++) acc += bf2f(w3[k])*H2[dd][k];
      int d = dt*8+dd;
      float raw = sanit(ski + skj[d] + acc);
      float v = vA[d] ? raw : -1e9f;
      out[i*OUTC + d0 + d] = v;
    }
  }
}

extern "C" void kernel_launch(void* const* d_in, const int* in_sizes, int n_in,
                              void* d_out, int out_size, void* d_ws, size_t ws_size,
                              hipStream_t stream){
  (void)in_sizes; (void)n_in; (void)out_size; (void)ws_size;
  const int*    tok   = (const int*)d_in[0];
  const int*    sst   = (const int*)d_in[1];
  const int*    sen   = (const int*)d_in[2];
  const ushort* emb   = (const ushort*)d_in[3];
  const ushort* wih_f = (const ushort*)d_in[4];
  const ushort* whh_f = (const ushort*)d_in[5];
  const ushort* b_f   = (const ushort*)d_in[6];
  const ushort* wih_b = (const ushort*)d_in[7];
  const ushort* whh_b = (const ushort*)d_in[8];
  const ushort* b_b   = (const ushort*)d_in[9];
  const ushort* aw1=(const ushort*)d_in[10]; const ushort* ab1=(const ushort*)d_in[11];
  const ushort* aw2=(const ushort*)d_in[12]; const ushort* ab2=(const ushort*)d_in[13];
  const ushort* aw3=(const ushort*)d_in[14]; const ushort* ab3=(const ushort*)d_in[15];
  const ushort* wemb=(const ushort*)d_in[16];
  const ushort* mw1=(const ushort*)d_in[17]; const ushort* mb1=(const ushort*)d_in[18];
  const ushort* mw2=(const ushort*)d_in[19]; const ushort* mb2=(const ushort*)d_in[20];
  const ushort* mw3=(const ushort*)d_in[21]; const ushort* mb3=(const ushort*)d_in[22];
  const ushort* demb=(const ushort*)d_in[23];
  const ushort* pw1=(const ushort*)d_in[24]; const ushort* pb1=(const ushort*)d_in[25];
  const ushort* pw2=(const ushort*)d_in[26]; const ushort* pb2=(const ushort*)d_in[27];
  const ushort* pw3=(const ushort*)d_in[28]; const ushort* pb3=(const ushort*)d_in[29];
  float* out = (float*)d_out;

  float* ws     = (float*)d_ws;
  float* hfw    = ws;                       // 409600
  float* hbw    = hfw + TT*HH;              // 409600
  float* attns  = hbw + TT*HH;              // 2048
  float* si     = attns + TT;               // 20480
  float* sk     = si + NS;                  // 384
  float* Pb     = sk + NK;                  // 57600
  float* Qb     = Pb + NK*HS;               // 57600
  float* gkw    = Qb + NK*HS;               // 468480
  _Float16* Xf  = (_Float16*)(gkw + NK*GDIM); // 1638400 halves
  _Float16* Xb  = Xf + TT*G4;                 // 1638400 halves
  int*   keep   = (int*)(Xb + TT*G4);       // 384
  int*   stk    = keep + NK;                // 384
  int*   enk    = stk + NK;                 // 384
  uint*  keysb  = (uint*)(enk + NK);        // 20480
  // total ~12.34 MB of d_ws

  k_xproj<<<TT/4,256,0,stream>>>(tok, emb, wih_f, b_f, wih_b, b_b, Xf, Xb);
  k_lstm<<<2,448,0,stream>>>(whh_f, whh_b, Xf, Xb, hfw, hbw);
  k_attn<<<TT,256,0,stream>>>(hfw,hbw,aw1,ab1,aw2,ab2,aw3,ab3,attns);
  k_ment<<<NS/8,256,0,stream>>>(sst,sen,tok,hfw,hbw,emb,attns,wemb,mw1,mb1,mw2,mb2,mw3,mb3,si);
  k_select<<<1,1024,0,stream>>>(si,sst,sen,keysb,keep,sk,stk,enk);
  k_gk<<<NK,256,0,stream>>>(keep,tok,hfw,hbw,emb,attns,wemb,sst,sen,gkw);
  k_pq<<<dim3(NK,2),256,0,stream>>>(gkw,pw1,Pb,Qb,out);
  k_pair<<<dim3(NK,8),256,0,stream>>>(gkw,Pb,Qb,sk,stk,enk,pw1,pb1,pw2,pb2,pw3,pb3,demb,out);
}

// Round 4
// 4826.941 us; speedup vs baseline: 1.0149x; 1.0149x over previous
//
#include <hip/hip_runtime.h>

#define TT 2048
#define EE 400
#define HH 200
#define G4 800
#define NS 20480
#define WMAX 10
#define HS 150
#define FD 20
#define GDIM 1220
#define NK 384
#define NA 128
#define OUTC 129

typedef unsigned int uint;
typedef unsigned short ushort;
typedef _Float16 half4 __attribute__((ext_vector_type(4)));

__device__ __forceinline__ float bf2f(ushort u){ return __uint_as_float(((uint)u)<<16); }
__device__ __forceinline__ int binv(int x){
  int b=0;
  b += (x>=1); b += (x>=2); b += (x>=3); b += (x>=4);
  b += (x>=8); b += (x>=16); b += (x>=32); b += (x>=64);
  return b;
}
__device__ __forceinline__ float sigf(float x){ return 1.0f/(1.0f+__expf(-x)); }
__device__ __forceinline__ float tanhf_fast(float x){
  float t = __expf(-2.0f*fabsf(x));       // in (0,1], never overflows
  float r = (1.0f - t)/(1.0f + t);
  return copysignf(r, x);
}
__device__ __forceinline__ float sanit(float x){ return (fabsf(x) <= 1e30f) ? x : 0.f; }

__device__ __forceinline__ int sdot4(int a, int b, int c){
#if __has_builtin(__builtin_amdgcn_sdot4)
  return __builtin_amdgcn_sdot4(a, b, c, false);
#else
  int r = c;
  r += (int)(signed char)(a)     * (int)(signed char)(b);
  r += (int)(signed char)(a>>8)  * (int)(signed char)(b>>8);
  r += (int)(signed char)(a>>16) * (int)(signed char)(b>>16);
  r += (int)(signed char)(a>>24) * (int)(signed char)(b>>24);
  return r;
#endif
}

// pack 4 dims (4n..4n+3) of a bf16 row into one int8 uint
__device__ __forceinline__ uint p4(const ushort* __restrict__ row, int n, float inv){
  uint r = 0;
#pragma unroll
  for (int b=0;b<4;++b){
    float w = bf2f(row[4*n+b]);
    int q = (int)rintf(w * inv);
    q = q < -127 ? -127 : (q > 127 ? 127 : q);
    r |= ((uint)(q & 0xff)) << (8*b);
  }
  return r;
}

// ---------------- K2: LSTM input projections (direct emb gather, f16 out) ----------------
// X layout: [t][j*4 + gate]  so k_lstm reads all 4 gate inputs of row j with ONE 8B read.
__global__ void k_xproj(const int* __restrict__ tok, const ushort* __restrict__ emb,
                        const ushort* __restrict__ wf, const ushort* __restrict__ bfv,
                        const ushort* __restrict__ wb, const ushort* __restrict__ bbv,
                        _Float16* __restrict__ Xf, _Float16* __restrict__ Xb){
  __shared__ float x4[4][EE];
  __shared__ int tk[4];
  int t0 = blockIdx.x*4;
  if (threadIdx.x < 4) tk[threadIdx.x] = tok[t0+threadIdx.x];
  __syncthreads();
  for (int i = threadIdx.x; i < 4*EE; i += 256){
    int m = i / EE, e = i - m*EE;
    x4[m][e] = bf2f(emb[tk[m]*EE + e]);
  }
  __syncthreads();
  for (int tt = threadIdx.x; tt < 2*G4; tt += 256){
    int dir = (tt >= G4);
    int row = dir ? tt - G4 : tt;
    const ushort* wr = (dir ? wb : wf) + row*EE;
    float bias = bf2f((dir ? bbv : bfv)[row]);
    float a0=bias,a1=bias,a2=bias,a3=bias;
    for (int k=0;k<EE;k+=4){
      ushort4 wv = *(const ushort4*)(wr+k);
      float w0=bf2f(wv.x), w1=bf2f(wv.y), w2=bf2f(wv.z), w3=bf2f(wv.w);
      a0 += w0*x4[0][k] + w1*x4[0][k+1] + w2*x4[0][k+2] + w3*x4[0][k+3];
      a1 += w0*x4[1][k] + w1*x4[1][k+1] + w2*x4[1][k+2] + w3*x4[1][k+3];
      a2 += w0*x4[2][k] + w1*x4[2][k+1] + w2*x4[2][k+2] + w3*x4[2][k+3];
      a3 += w0*x4[3][k] + w1*x4[3][k+1] + w2*x4[3][k+2] + w3*x4[3][k+3];
    }
    _Float16* X = dir ? Xb : Xf;
    int g = row / HH, jj = row - g*HH;
    int col = jj*4 + g;
    X[(t0+0)*G4+col]=(_Float16)a0; X[(t0+1)*G4+col]=(_Float16)a1;
    X[(t0+2)*G4+col]=(_Float16)a2; X[(t0+3)*G4+col]=(_Float16)a3;
  }
}

// ---------------- K3: sequential bi-LSTM (block0=fwd, block1=bwd) ----------------
// Round-1 step body + __syncthreads (proven fastest barrier), plus 8-step X
// chunk staging through LDS: at chunk start each act lane loads its 32 B of
// the NEXT chunk into regs (HBM latency ~900cy hides under a ~2000cy step,
// and the end-of-step vmcnt drain hits after completion -> free); at chunk
// end the regs are ds_written to the inactive buffer. Per-step X is then a
// ~120cy broadcast ds_read_b64 instead of an exposed HBM miss.
__global__ __launch_bounds__(448, 2) void k_lstm(const ushort* __restrict__ whh_f,
                        const ushort* __restrict__ whh_b,
                        const _Float16* __restrict__ Xf, const _Float16* __restrict__ Xb,
                        float* __restrict__ hf, float* __restrict__ hb){
  __shared__ __align__(16) uint  hq[112];        // 2 x 224-B int8 h buffers (28dw halves)
  __shared__ __align__(16) char  xlds[2*12800];  // 2 x 8-step X chunks (8 x 1600 B)
  const int tid = threadIdx.x;
  const int fwd = (blockIdx.x == 0);
  const ushort* whh = fwd ? whh_f : whh_b;
  const char* Xg = (const char*)(fwd ? Xf : Xb);
  float* hout = fwd ? hf : hb;
  const bool act = (tid < 400);
  const int j = tid >> 1;                // 0..199
  const int half = tid & 1;              // dim half

  uint4 wreg[25];                        // per-lane int8 weights, in registers
  float mx0=1e-20f, mx1=1e-20f, mx2=1e-20f, mx3=1e-20f;
  if (act){
    const ushort* r0 = whh + (0*HH + j)*HH + half*100;
    const ushort* r1 = whh + (1*HH + j)*HH + half*100;
    const ushort* r2 = whh + (2*HH + j)*HH + half*100;
    const ushort* r3 = whh + (3*HH + j)*HH + half*100;
    for (int d=0; d<100; d+=2){
      ushort2 v0 = *(const ushort2*)(r0+d);
      ushort2 v1 = *(const ushort2*)(r1+d);
      ushort2 v2 = *(const ushort2*)(r2+d);
      ushort2 v3 = *(const ushort2*)(r3+d);
      mx0 = fmaxf(mx0, fmaxf(fabsf(bf2f(v0.x)), fabsf(bf2f(v0.y))));
      mx1 = fmaxf(mx1, fmaxf(fabsf(bf2f(v1.x)), fabsf(bf2f(v1.y))));
      mx2 = fmaxf(mx2, fmaxf(fabsf(bf2f(v2.x)), fabsf(bf2f(v2.y))));
      mx3 = fmaxf(mx3, fmaxf(fabsf(bf2f(v3.x)), fabsf(bf2f(v3.y))));
    }
    float i0=127.f/mx0, i1=127.f/mx1, i2=127.f/mx2, i3=127.f/mx3;
#pragma unroll
    for (int n=0;n<25;++n){
      uint4 wv;
      wv.x = p4(r0,n,i0); wv.y = p4(r1,n,i1); wv.z = p4(r2,n,i2); wv.w = p4(r3,n,i3);
      wreg[n] = wv;
    }
  }
  const float sc0 = mx0*(1.f/16129.f), sc1 = mx1*(1.f/16129.f);
  const float sc2 = mx2*(1.f/16129.f), sc3 = mx3*(1.f/16129.f);
  if (tid < 112) hq[tid] = 0u;
  uint4 pf0 = uint4{0,0,0,0}, pf1 = uint4{0,0,0,0};
  if (act){
    // stage chunk 0 directly (400 lanes x 32 B = 12800 B = 8 rows x 1600 B)
    int rb0 = fwd ? 0 : (TT-8);
    const char* src = Xg + rb0*1600 + tid*32;
    uint4 a = *(const uint4*)(src);
    uint4 b = *(const uint4*)(src+16);
    *(uint4*)(xlds + tid*32) = a;
    *(uint4*)(xlds + tid*32 + 16) = b;
  }
  float c = 0.f;
  __syncthreads();
  for (int step=0; step<TT; ++step){
    int ts = fwd ? step : (TT-1-step);
    int cidx = step >> 3, si = step & 7;
    if (act){
      if (si == 0 && cidx < 255){
        // issue next chunk's loads; consumed (ds_write) 7 steps later
        int rb = fwd ? (cidx+1)*8 : (TT-8-(cidx+1)*8);
        const char* src = Xg + rb*1600 + tid*32;
        pf0 = *(const uint4*)(src);
        pf1 = *(const uint4*)(src+16);
      }
      // all 4 gate x-inputs for row j from LDS (2-lane broadcast, 8 B)
      int ri = fwd ? si : (7-si);
      half4 xv = *(const half4*)(xlds + (cidx&1)*12800 + ri*1600 + (j<<3));
      // h window for this half (broadcast across lanes)
      const uint* hbp = hq + (step&1)*56 + half*28;
      uint4 hA = *(const uint4*)(hbp+0);
      uint4 hB = *(const uint4*)(hbp+4);
      uint4 hC = *(const uint4*)(hbp+8);
      uint4 hD = *(const uint4*)(hbp+12);
      uint4 hE = *(const uint4*)(hbp+16);
      uint4 hF = *(const uint4*)(hbp+20);
      uint  hG = hbp[24];
      int d0=0,d1=0,d2=0,d3=0;
#define DD(n,hu) { uint4 wv = wreg[n]; \
  d0=sdot4((int)wv.x,(int)(hu),d0); d1=sdot4((int)wv.y,(int)(hu),d1); \
  d2=sdot4((int)wv.z,(int)(hu),d2); d3=sdot4((int)wv.w,(int)(hu),d3); }
      DD(0,hA.x) DD(1,hA.y) DD(2,hA.z) DD(3,hA.w)
      DD(4,hB.x) DD(5,hB.y) DD(6,hB.z) DD(7,hB.w)
      DD(8,hC.x) DD(9,hC.y) DD(10,hC.z) DD(11,hC.w)
      DD(12,hD.x) DD(13,hD.y) DD(14,hD.z) DD(15,hD.w)
      DD(16,hE.x) DD(17,hE.y) DD(18,hE.z) DD(19,hE.w)
      DD(20,hF.x) DD(21,hF.y) DD(22,hF.z) DD(23,hF.w)
      DD(24,hG)
#undef DD
      float a0 = (float)d0*sc0 + (float)xv.x*0.5f;
      float a1 = (float)d1*sc1 + (float)xv.y*0.5f;
      float a2 = (float)d2*sc2 + (float)xv.z*0.5f;
      float a3 = (float)d3*sc3 + (float)xv.w*0.5f;
      // sum the two dim-halves (x added half in each lane -> once total)
      a0 += __shfl_xor(a0, 1, 64);
      a1 += __shfl_xor(a1, 1, 64);
      a2 += __shfl_xor(a2, 1, 64);
      a3 += __shfl_xor(a3, 1, 64);
      // gates: 0=i, 1=f, 2=g, 3=o
      c = sigf(a1)*c + sigf(a0)*tanhf_fast(a2);
      float h = sigf(a3)*tanhf_fast(c);
      if (half == 0){
        hout[ts*HH + j] = h;             // fire-and-forget
        int q = (int)rintf(h*127.f);
        q = q<-127?-127:(q>127?127:q);
        int bufbyte = ((step+1)&1)*224 + (j<100 ? j : 112 + (j-100));
        ((unsigned char*)hq)[bufbyte] = (unsigned char)(q & 0xff);
      }
      if (si == 7 && cidx < 255){
        // commit next chunk to the inactive buffer (loads long complete)
        char* dst = xlds + ((cidx+1)&1)*12800 + tid*32;
        *(uint4*)dst = pf0;
        *(uint4*)(dst+16) = pf1;
      }
    }
    __syncthreads();
  }
}

// ---------------- K4: token attention-score MLP ----------------
__global__ void k_attn(const float* __restrict__ hf, const float* __restrict__ hb,
    const ushort* w1, const ushort* b1, const ushort* w2, const ushort* b2,
    const ushort* w3, const ushort* b3, float* __restrict__ attns){
  __shared__ float s[2*HH];
  __shared__ float h1[HS], h2[HS];
  int t = blockIdx.x;
  for (int k=threadIdx.x;k<2*HH;k+=256)
    s[k] = (k<HH) ? hf[t*HH+k] : hb[t*HH + (k-HH)];
  __syncthreads();
  int o = threadIdx.x;
  if (o < HS){
    float acc = bf2f(b1[o]);
    const ushort* wr = w1 + o*2*HH;
    for (int k=0;k<2*HH;k+=4){
      ushort4 wv = *(const ushort4*)(wr+k);
      acc += bf2f(wv.x)*s[k] + bf2f(wv.y)*s[k+1] + bf2f(wv.z)*s[k+2] + bf2f(wv.w)*s[k+3];
    }
    h1[o] = fmaxf(acc, 0.f);
  }
  __syncthreads();
  if (o < HS){
    float acc = bf2f(b2[o]);
    const ushort* wr = w2 + o*HS;
    for (int k=0;k<HS;k+=2) acc += bf2f(wr[k])*h1[k] + bf2f(wr[k+1])*h1[k+1];
    h2[o] = fmaxf(acc, 0.f);
  }
  __syncthreads();
  if (o == 0){
    float acc = bf2f(b3[0]);
    for (int k=0;k<HS;k++) acc += bf2f(w3[k])*h2[k];
    attns[t] = acc;
  }
}

// ---------------- K5: span features + mention MLP (8 spans/block) ----------------
__global__ void k_ment(const int* __restrict__ sstart, const int* __restrict__ send,
    const int* __restrict__ tok,
    const float* __restrict__ hf, const float* __restrict__ hb,
    const ushort* __restrict__ emb, const float* __restrict__ attns,
    const ushort* wemb,
    const ushort* w1, const ushort* b1, const ushort* w2, const ushort* b2,
    const ushort* w3, const ushort* b3, float* __restrict__ si){
  __shared__ __align__(16) float G[8][GDIM];
  __shared__ float H1[8][152], H2[8][152];
  __shared__ float aw[8][WMAX];
  __shared__ int stok[8][WMAX];
  __shared__ int sst[8], sen[8], sbin[8];
  int s0 = blockIdx.x*8;
  if (threadIdx.x < 8){
    int sp = threadIdx.x;
    int st = sstart[s0+sp], en = send[s0+sp];
    sst[sp]=st; sen[sp]=en;
    int width = en - st + 1;
    sbin[sp] = binv(width);
    float lg[WMAX]; float mx = -1e30f;
    for (int wt=0; wt<WMAX; ++wt){
      int idx = st + wt; if (idx > TT-1) idx = TT-1;
      float l = (wt < width) ? attns[idx] : -1e9f;
      lg[wt] = l; mx = fmaxf(mx, l);
    }
    float den = 0.f;
    for (int wt=0; wt<WMAX; ++wt){ lg[wt] = __expf(lg[wt]-mx); den += lg[wt]; }
    float inv = 1.f/den;
    for (int wt=0; wt<WMAX; ++wt) aw[sp][wt] = lg[wt]*inv;
  }
  if (threadIdx.x < 8*WMAX){
    int sp = threadIdx.x / WMAX, wt = threadIdx.x - sp*WMAX;
    int idx = sstart[s0+sp] + wt; if (idx > TT-1) idx = TT-1;
    stok[sp][wt] = tok[idx];
  }
  __syncthreads();
  for (int i = threadIdx.x; i < 8*GDIM; i += 256){
    int sp = i / GDIM, f = i - sp*GDIM;
    int st = sst[sp], en = sen[sp];
    float v;
    if (f < HH) v = hf[st*HH + f];
    else if (f < 2*HH) v = hb[st*HH + (f-HH)];
    else if (f < 3*HH) v = hf[en*HH + (f-2*HH)];
    else if (f < 4*HH) v = hb[en*HH + (f-3*HH)];
    else if (f < 4*HH + EE){
      int e = f - 4*HH;
      float acc = 0.f;
      for (int wt=0; wt<WMAX; ++wt)
        acc += aw[sp][wt] * bf2f(emb[stok[sp][wt]*EE + e]);
      v = acc;
    } else {
      v = bf2f(wemb[sbin[sp]*FD + (f - (4*HH+EE))]);
    }
    G[sp][f] = v;
  }
  __syncthreads();
  for (int tt = threadIdx.x; tt < 8*HS; tt += 256){
    int sp = tt & 7, o = tt >> 3;
    float acc = bf2f(b1[o]);
    const ushort* wr = w1 + o*GDIM;
    for (int k=0;k<GDIM;k+=4){
      ushort4 wv = *(const ushort4*)(wr+k);
      acc += bf2f(wv.x)*G[sp][k] + bf2f(wv.y)*G[sp][k+1]
           + bf2f(wv.z)*G[sp][k+2] + bf2f(wv.w)*G[sp][k+3];
    }
    H1[sp][o] = fmaxf(acc, 0.f);
  }
  __syncthreads();
  for (int tt = threadIdx.x; tt < 8*HS; tt += 256){
    int sp = tt & 7, o = tt >> 3;
    float acc = bf2f(b2[o]);
    const ushort* wr = w2 + o*HS;
    for (int k=0;k<HS;k+=2) acc += bf2f(wr[k])*H1[sp][k] + bf2f(wr[k+1])*H1[sp][k+1];
    H2[sp][o] = fmaxf(acc, 0.f);
  }
  __syncthreads();
  if (threadIdx.x < 8){
    int sp = threadIdx.x;
    float acc = bf2f(b3[0]);
    for (int k=0;k<HS;k++) acc += bf2f(w3[k])*H2[sp][k];
    si[s0+sp] = sanit(acc);
  }
}

// ---------------- K6: top-384 + index-ordered compaction (single block) ----------------
__global__ __launch_bounds__(1024) void k_select(const float* __restrict__ si,
    const int* __restrict__ sstart, const int* __restrict__ send,
    uint* __restrict__ keysb, int* __restrict__ keep, float* __restrict__ sk,
    int* __restrict__ stk, int* __restrict__ enk){
  __shared__ uint hist[256];
  __shared__ uint sG[1024], sE[1024];
  __shared__ uint bc[2];
  int tid = threadIdx.x;
  if (tid < NK){ keep[tid]=0; sk[tid]=0.f; stk[tid]=0; enk[tid]=0; }
  for (int i=tid;i<NS;i+=1024){
    uint u = __float_as_uint(si[i]);
    uint m = (u & 0x80000000u) ? ~u : (u | 0x80000000u);  // order-preserving map
    keysb[i] = m;
  }
  __syncthreads();
  uint prefix=0, mask=0; int K = NK;
  for (int p=3;p>=0;--p){
    int sh = p*8;
    if (tid<256) hist[tid]=0;
    __syncthreads();
    for (int i=tid;i<NS;i+=1024){
      uint m = keysb[i];
      if ((m & mask) == prefix) atomicAdd(&hist[(m>>sh)&255u], 1u);
    }
    __syncthreads();
    if (tid==0){
      uint cum=0;
      bc[0]=0; bc[1]=(uint)K;
      for (int b=255; b>=0; --b){
        uint c = hist[b];
        if ((uint)K <= cum + c){ bc[0]=(uint)b; bc[1]=(uint)(K - (int)cum); break; }
        cum += c;
      }
    }
    __syncthreads();
    prefix |= bc[0] << sh;
    mask |= 0xFFu << sh;
    K = (int)bc[1];
    __syncthreads();
  }
  const uint V = prefix; const uint Eneed = (uint)K;
  int base = tid*20;
  uint cg=0, ce=0;
  for (int r=0;r<20;++r){
    uint m = keysb[base+r];
    cg += (m > V); ce += (m == V);
  }
  sG[tid]=cg; sE[tid]=ce;
  __syncthreads();
  for (int off=1; off<1024; off<<=1){
    uint aG=0,aE=0;
    if (tid>=off){ aG=sG[tid-off]; aE=sE[tid-off]; }
    __syncthreads();
    if (tid>=off){ sG[tid]+=aG; sE[tid]+=aE; }
    __syncthreads();
  }
  uint gbase = sG[tid]-cg, ebase = sE[tid]-ce;
  uint gseen=0, eseen=0;
  for (int r=0;r<20;++r){
    int i = base+r;
    uint m = keysb[i];
    if (m > V){
      uint eb = ebase+eseen; if (eb > Eneed) eb = Eneed;
      uint pos = gbase + gseen + eb;
      if (pos < NK){ keep[pos]=i; sk[pos]=si[i]; stk[pos]=sstart[i]; enk[pos]=send[i]; }
      gseen++;
    } else if (m == V){
      uint eb = ebase + eseen;
      if (eb < Eneed){
        uint pos = gbase + gseen + eb;
        if (pos < NK){ keep[pos]=i; sk[pos]=si[i]; stk[pos]=sstart[i]; enk[pos]=send[i]; }
      }
      eseen++;
    }
  }
}

// ---------------- K7: rebuild g for kept spans ----------------
__global__ void k_gk(const int* __restrict__ keep, const int* __restrict__ tok,
    const float* __restrict__ hf, const float* __restrict__ hb,
    const ushort* __restrict__ emb, const float* __restrict__ attns,
    const ushort* wemb, const int* __restrict__ sstart, const int* __restrict__ send,
    float* __restrict__ gk){
  __shared__ float aw[WMAX];
  __shared__ int stok1[WMAX];
  __shared__ int sstv, senv, sbinv;
  int b = blockIdx.x;
  if (threadIdx.x == 0){
    int s = keep[b]; s = s < 0 ? 0 : (s >= NS ? NS-1 : s);
    int st = sstart[s], en = send[s];
    sstv=st; senv=en;
    int width = en-st+1;
    sbinv = binv(width);
    float lg[WMAX]; float mx=-1e30f;
    for (int wt=0;wt<WMAX;++wt){
      int idx = st+wt; if (idx>TT-1) idx=TT-1;
      float l = (wt<width)? attns[idx] : -1e9f;
      lg[wt]=l; mx=fmaxf(mx,l);
    }
    float den=0.f;
    for (int wt=0;wt<WMAX;++wt){ lg[wt]=__expf(lg[wt]-mx); den+=lg[wt]; }
    float inv=1.f/den;
    for (int wt=0;wt<WMAX;++wt) aw[wt]=lg[wt]*inv;
  }
  if (threadIdx.x < WMAX){
    int s = keep[b]; s = s < 0 ? 0 : (s >= NS ? NS-1 : s);
    int idx = sstart[s] + threadIdx.x; if (idx>TT-1) idx=TT-1;
    stok1[threadIdx.x] = tok[idx];
  }
  __syncthreads();
  int st=sstv, en=senv;
  for (int f=threadIdx.x; f<GDIM; f+=256){
    float v;
    if (f < HH) v = hf[st*HH + f];
    else if (f < 2*HH) v = hb[st*HH + (f-HH)];
    else if (f < 3*HH) v = hf[en*HH + (f-2*HH)];
    else if (f < 4*HH) v = hb[en*HH + (f-3*HH)];
    else if (f < 4*HH + EE){
      int e = f - 4*HH;
      float acc = 0.f;
      for (int wt=0; wt<WMAX; ++wt)
        acc += aw[wt] * bf2f(emb[stok1[wt]*EE + e]);
      v = acc;
    } else {
      v = bf2f(wemb[sbinv*FD + (f - (4*HH+EE))]);
    }
    gk[b*GDIM + f] = v;
  }
}

// ---------------- K8a: P[i]=w1a.gk[i], Q[i]=w1b.gk[i]; also eps column ----------------
__global__ void k_pq(const float* __restrict__ gk, const ushort* __restrict__ w1,
                     float* __restrict__ P, float* __restrict__ Q, float* __restrict__ out){
  __shared__ __align__(16) float gi[GDIM];
  int i = blockIdx.x, which = blockIdx.y;
  for (int k=threadIdx.x;k<GDIM;k+=256) gi[k]=gk[i*GDIM+k];
  __syncthreads();
  if (which==0 && threadIdx.x==0) out[i*OUTC + NA] = 0.0f;   // eps column
  int o = threadIdx.x;
  if (o < HS){
    const ushort* wr = w1 + o*3680 + which*GDIM;
    float acc=0.f;
    for (int k=0;k<GDIM;k+=4){
      ushort4 wv = *(const ushort4*)(wr+k);
      acc += bf2f(wv.x)*gi[k]+bf2f(wv.y)*gi[k+1]+bf2f(wv.z)*gi[k+2]+bf2f(wv.w)*gi[k+3];
    }
    (which? Q : P)[i*HS+o] = acc;
  }
}

// ---------------- K8b: pair MLP (decomposed layer-1), 16 antecedents/block ----------------
__global__ void k_pair(const float* __restrict__ gk, const float* __restrict__ P,
    const float* __restrict__ Q, const float* __restrict__ sk,
    const int* __restrict__ stk, const int* __restrict__ enk,
    const ushort* w1, const ushort* b1, const ushort* w2, const ushort* b2,
    const ushort* w3, const ushort* b3, const ushort* demb, float* __restrict__ out){
  __shared__ __align__(16) float gi[GDIM];
  __shared__ float Pi[152];
  __shared__ float Dall[9*HS];
  __shared__ __align__(16) float GIJ[8][GDIM];
  __shared__ float H1[8][152], H2[8][152];
  __shared__ int jcA[16], dbA[16], vA[16];
  __shared__ float skj[16];
  int i = blockIdx.x;
  int d0 = blockIdx.y*16;
  if (i - 1 - d0 < 0){
    for (int d = threadIdx.x; d < 16; d += 256) out[i*OUTC + d0 + d] = -1e9f;
    return;
  }
  for (int k=threadIdx.x;k<GDIM;k+=256) gi[k]=gk[i*GDIM+k];
  for (int o=threadIdx.x;o<HS;o+=256) Pi[o]=P[i*HS+o];
  if (threadIdx.x < 16){
    int dcol = d0 + threadIdx.x;
    int j = i - 1 - dcol;
    int jc = j<0?0:j;
    vA[threadIdx.x]=(j>=0);
    jcA[threadIdx.x]=jc;
    dbA[threadIdx.x]=binv(enk[i]-stk[jc]);
    skj[threadIdx.x]=sk[jc];
  }
  for (int tt=threadIdx.x; tt<9*HS; tt+=256){
    int o = tt/9, b = tt - (tt/9)*9;
    float acc = bf2f(b1[o]);
    const ushort* wr = w1 + o*3680 + 3660;
    const ushort* de = demb + b*FD;
    for (int k=0;k<FD;k++) acc += bf2f(wr[k])*bf2f(de[k]);
    Dall[b*HS+o] = acc;
  }
  __syncthreads();
  float ski = sk[i];
  for (int dt=0; dt<2; ++dt){
    if (i - 1 - (d0 + dt*8) < 0){
      if (threadIdx.x < 8) out[i*OUTC + d0 + dt*8 + threadIdx.x] = -1e9f;
      continue;
    }
    __syncthreads();
    for (int idx=threadIdx.x; idx<8*GDIM; idx+=256){
      int dd = idx / GDIM, k = idx - dd*GDIM;
      GIJ[dd][k] = gi[k]*gk[jcA[dt*8+dd]*GDIM + k];
    }
    __syncthreads();
    {
      int dd = threadIdx.x & 7, og = threadIdx.x >> 3;
      for (int o=og; o<HS; o+=32){
        const ushort* wr = w1 + o*3680 + 2*GDIM;
        float acc = 0.f;
        for (int k=0;k<GDIM;k+=4){
          ushort4 wv = *(const ushort4*)(wr+k);
          float4 gv = *(const float4*)&GIJ[dd][k];
          acc += bf2f(wv.x)*gv.x + bf2f(wv.y)*gv.y + bf2f(wv.z)*gv.z + bf2f(wv.w)*gv.w;
        }
        int d = dt*8+dd;
        acc += Pi[o] + Q[jcA[d]*HS+o] + Dall[dbA[d]*HS+o];
        H1[dd][o] = fmaxf(acc, 0.f);
      }
    }
    __syncthreads();
    {
      int dd = threadIdx.x & 7, og = threadIdx.x >> 3;
      for (int o=og;o<HS;o+=32){
        float acc = bf2f(b2[o]);
        const ushort* wr = w2 + o*HS;
        for (int k=0;k<HS;k+=2) acc += bf2f(wr[k])*H1[dd][k] + bf2f(wr[k+1])*H1[dd][k+1];
        H2[dd][o]=fmaxf(acc,0.f);
      }
    }
    __syncthreads();
    if (threadIdx.x < 8){
      int dd = threadIdx.x;
      float acc = bf2f(b3[0]);
      for (int k=0;k<HS;k++) acc += bf2f(w3[k])*H2[dd][k];
      int d = dt*8+dd;
      float raw = sanit(ski + skj[d] + acc);
      float v = vA[d] ? raw : -1e9f;
      out[i*OUTC + d0 + d] = v;
    }
  }
}

extern "C" void kernel_launch(void* const* d_in, const int* in_sizes, int n_in,
                              void* d_out, int out_size, void* d_ws, size_t ws_size,
                              hipStream_t stream){
  (void)in_sizes; (void)n_in; (void)out_size; (void)ws_size;
  const int*    tok   = (const int*)d_in[0];
  const int*    sst   = (const int*)d_in[1];
  const int*    sen   = (const int*)d_in[2];
  const ushort* emb   = (const ushort*)d_in[3];
  const ushort* wih_f = (const ushort*)d_in[4];
  const ushort* whh_f = (const ushort*)d_in[5];
  const ushort* b_f   = (const ushort*)d_in[6];
  const ushort* wih_b = (const ushort*)d_in[7];
  const ushort* whh_b = (const ushort*)d_in[8];
  const ushort* b_b   = (const ushort*)d_in[9];
  const ushort* aw1=(const ushort*)d_in[10]; const ushort* ab1=(const ushort*)d_in[11];
  const ushort* aw2=(const ushort*)d_in[12]; const ushort* ab2=(const ushort*)d_in[13];
  const ushort* aw3=(const ushort*)d_in[14]; const ushort* ab3=(const ushort*)d_in[15];
  const ushort* wemb=(const ushort*)d_in[16];
  const ushort* mw1=(const ushort*)d_in[17]; const ushort* mb1=(const ushort*)d_in[18];
  const ushort* mw2=(const ushort*)d_in[19]; const ushort* mb2=(const ushort*)d_in[20];
  const ushort* mw3=(const ushort*)d_in[21]; const ushort* mb3=(const ushort*)d_in[22];
  const ushort* demb=(const ushort*)d_in[23];
  const ushort* pw1=(const ushort*)d_in[24]; const ushort* pb1=(const ushort*)d_in[25];
  const ushort* pw2=(const ushort*)d_in[26]; const ushort* pb2=(const ushort*)d_in[27];
  const ushort* pw3=(const ushort*)d_in[28]; const ushort* pb3=(const ushort*)d_in[29];
  float* out = (float*)d_out;

  float* ws     = (float*)d_ws;
  float* hfw    = ws;                       // 409600
  float* hbw    = hfw + TT*HH;              // 409600
  float* attns  = hbw + TT*HH;              // 2048
  float* si     = attns + TT;               // 20480
  float* sk     = si + NS;                  // 384
  float* Pb     = sk + NK;                  // 57600
  float* Qb     = Pb + NK*HS;               // 57600
  float* gkw    = Qb + NK*HS;               // 468480
  _Float16* Xf  = (_Float16*)(gkw + NK*GDIM); // 1638400 halves
  _Float16* Xb  = Xf + TT*G4;                 // 1638400 halves
  int*   keep   = (int*)(Xb + TT*G4);       // 384
  int*   stk    = keep + NK;                // 384
  int*   enk    = stk + NK;                 // 384
  uint*  keysb  = (uint*)(enk + NK);        // 20480
  // total ~12.34 MB of d_ws

  k_xproj<<<TT/4,256,0,stream>>>(tok, emb, wih_f, b_f, wih_b, b_b, Xf, Xb);
  k_lstm<<<2,448,0,stream>>>(whh_f, whh_b, Xf, Xb, hfw, hbw);
  k_attn<<<TT,256,0,stream>>>(hfw,hbw,aw1,ab1,aw2,ab2,aw3,ab3,attns);
  k_ment<<<NS/8,256,0,stream>>>(sst,sen,tok,hfw,hbw,emb,attns,wemb,mw1,mb1,mw2,mb2,mw3,mb3,si);
  k_select<<<1,1024,0,stream>>>(si,sst,sen,keysb,keep,sk,stk,enk);
  k_gk<<<NK,256,0,stream>>>(keep,tok,hfw,hbw,emb,attns,wemb,sst,sen,gkw);
  k_pq<<<dim3(NK,2),256,0,stream>>>(gkw,pw1,Pb,Qb,out);
  k_pair<<<dim3(NK,8),256,0,stream>>>(gkw,Pb,Qb,sk,stk,enk,pw1,pb1,pw2,pb2,pw3,pb3,demb,out);
}

// Round 5
// 4801.924 us; speedup vs baseline: 1.0202x; 1.0052x over previous
//
#include <hip/hip_runtime.h>

#define TT 2048
#define EE 400
#define HH 200
#define G4 800
#define NS 20480
#define WMAX 10
#define HS 150
#define FD 20
#define GDIM 1220
#define NK 384
#define NA 128
#define OUTC 129

typedef unsigned int uint;
typedef unsigned short ushort;
typedef _Float16 half4 __attribute__((ext_vector_type(4)));

__device__ __forceinline__ float bf2f(ushort u){ return __uint_as_float(((uint)u)<<16); }
__device__ __forceinline__ int binv(int x){
  int b=0;
  b += (x>=1); b += (x>=2); b += (x>=3); b += (x>=4);
  b += (x>=8); b += (x>=16); b += (x>=32); b += (x>=64);
  return b;
}
__device__ __forceinline__ float sigf(float x){ return 1.0f/(1.0f+__expf(-x)); }
__device__ __forceinline__ float tanhf_fast(float x){
  float t = __expf(-2.0f*fabsf(x));       // in (0,1], never overflows
  float r = (1.0f - t)/(1.0f + t);
  return copysignf(r, x);
}
__device__ __forceinline__ float sanit(float x){ return (fabsf(x) <= 1e30f) ? x : 0.f; }

__device__ __forceinline__ int sdot4(int a, int b, int c){
#if __has_builtin(__builtin_amdgcn_sdot4)
  return __builtin_amdgcn_sdot4(a, b, c, false);
#else
  int r = c;
  r += (int)(signed char)(a)     * (int)(signed char)(b);
  r += (int)(signed char)(a>>8)  * (int)(signed char)(b>>8);
  r += (int)(signed char)(a>>16) * (int)(signed char)(b>>16);
  r += (int)(signed char)(a>>24) * (int)(signed char)(b>>24);
  return r;
#endif
}

// pack 4 dims (4n..4n+3) of a bf16 row into one int8 uint
__device__ __forceinline__ uint p4(const ushort* __restrict__ row, int n, float inv){
  uint r = 0;
#pragma unroll
  for (int b=0;b<4;++b){
    float w = bf2f(row[4*n+b]);
    int q = (int)rintf(w * inv);
    q = q < -127 ? -127 : (q > 127 ? 127 : q);
    r |= ((uint)(q & 0xff)) << (8*b);
  }
  return r;
}

// ---------------- K1: pre-convert hot bf16 weight matrices to f32 ----------------
// mw1 (ment layer-1, HSxGDIM) and the GIJ section of pw1 (pair layer-1,
// rows HS, cols [2*GDIM, 3*GDIM)) are re-read by thousands of blocks; the
// per-use bf16->f32 shifts are ~4 of the 11 insts in those inner loops.
__global__ void k_prep(const ushort* __restrict__ mw1, const ushort* __restrict__ pw1,
                       float* __restrict__ mw1f, float* __restrict__ pw1f){
  int i = blockIdx.x*256 + threadIdx.x;
  if (i < HS*GDIM){
    int o = i / GDIM, k = i - o*GDIM;
    mw1f[i] = bf2f(mw1[i]);                      // stride GDIM == flat
    pw1f[i] = bf2f(pw1[o*3680 + 2*GDIM + k]);
  }
}

// ---------------- K2: LSTM input projections (direct emb gather, f16 out) ----------------
// X layout: [t][j*4 + gate]  so k_lstm reads all 4 gate inputs of row j with ONE 8B load.
__global__ void k_xproj(const int* __restrict__ tok, const ushort* __restrict__ emb,
                        const ushort* __restrict__ wf, const ushort* __restrict__ bfv,
                        const ushort* __restrict__ wb, const ushort* __restrict__ bbv,
                        _Float16* __restrict__ Xf, _Float16* __restrict__ Xb){
  __shared__ float x4[4][EE];
  __shared__ int tk[4];
  int t0 = blockIdx.x*4;
  if (threadIdx.x < 4) tk[threadIdx.x] = tok[t0+threadIdx.x];
  __syncthreads();
  for (int i = threadIdx.x; i < 4*EE; i += 256){
    int m = i / EE, e = i - m*EE;
    x4[m][e] = bf2f(emb[tk[m]*EE + e]);
  }
  __syncthreads();
  for (int tt = threadIdx.x; tt < 2*G4; tt += 256){
    int dir = (tt >= G4);
    int row = dir ? tt - G4 : tt;
    const ushort* wr = (dir ? wb : wf) + row*EE;
    float bias = bf2f((dir ? bbv : bfv)[row]);
    float a0=bias,a1=bias,a2=bias,a3=bias;
    for (int k=0;k<EE;k+=4){
      ushort4 wv = *(const ushort4*)(wr+k);
      float w0=bf2f(wv.x), w1=bf2f(wv.y), w2=bf2f(wv.z), w3=bf2f(wv.w);
      a0 += w0*x4[0][k] + w1*x4[0][k+1] + w2*x4[0][k+2] + w3*x4[0][k+3];
      a1 += w0*x4[1][k] + w1*x4[1][k+1] + w2*x4[1][k+2] + w3*x4[1][k+3];
      a2 += w0*x4[2][k] + w1*x4[2][k+1] + w2*x4[2][k+2] + w3*x4[2][k+3];
      a3 += w0*x4[3][k] + w1*x4[3][k+1] + w2*x4[3][k+2] + w3*x4[3][k+3];
    }
    _Float16* X = dir ? Xb : Xf;
    int g = row / HH, jj = row - g*HH;
    int col = jj*4 + g;
    X[(t0+0)*G4+col]=(_Float16)a0; X[(t0+1)*G4+col]=(_Float16)a1;
    X[(t0+2)*G4+col]=(_Float16)a2; X[(t0+3)*G4+col]=(_Float16)a3;
  }
}

// ---------------- K3: sequential bi-LSTM (block0=fwd, block1=bwd) ----------------
// Round-1 form exactly: weights in registers (int8, 25 uint4/lane), direct
// per-step X load, plain __syncthreads. Rounds 2-4 proved every hand-pipelined
// variant (reg rotation, LDS-only barriers, LDS X staging) is 220-310us SLOWER:
// the compiler's own schedule of this simple form is the local optimum.
__global__ __launch_bounds__(448, 2) void k_lstm(const ushort* __restrict__ whh_f,
                        const ushort* __restrict__ whh_b,
                        const _Float16* __restrict__ Xf, const _Float16* __restrict__ Xb,
                        float* __restrict__ hf, float* __restrict__ hb){
  __shared__ __align__(16) uint  hq[112];       // 2 x 224-B int8 h buffers (28dw halves)
  const int tid = threadIdx.x;
  const int fwd = (blockIdx.x == 0);
  const ushort* whh = fwd ? whh_f : whh_b;
  const _Float16* X = fwd ? Xf : Xb;
  float* hout = fwd ? hf : hb;
  const bool act = (tid < 400);
  const int j = tid >> 1;                // 0..199
  const int half = tid & 1;              // dim half

  uint4 wreg[25];                        // per-lane int8 weights, in registers
  float mx0=1e-20f, mx1=1e-20f, mx2=1e-20f, mx3=1e-20f;
  if (act){
    const ushort* r0 = whh + (0*HH + j)*HH + half*100;
    const ushort* r1 = whh + (1*HH + j)*HH + half*100;
    const ushort* r2 = whh + (2*HH + j)*HH + half*100;
    const ushort* r3 = whh + (3*HH + j)*HH + half*100;
    for (int d=0; d<100; d+=2){
      ushort2 v0 = *(const ushort2*)(r0+d);
      ushort2 v1 = *(const ushort2*)(r1+d);
      ushort2 v2 = *(const ushort2*)(r2+d);
      ushort2 v3 = *(const ushort2*)(r3+d);
      mx0 = fmaxf(mx0, fmaxf(fabsf(bf2f(v0.x)), fabsf(bf2f(v0.y))));
      mx1 = fmaxf(mx1, fmaxf(fabsf(bf2f(v1.x)), fabsf(bf2f(v1.y))));
      mx2 = fmaxf(mx2, fmaxf(fabsf(bf2f(v2.x)), fabsf(bf2f(v2.y))));
      mx3 = fmaxf(mx3, fmaxf(fabsf(bf2f(v3.x)), fabsf(bf2f(v3.y))));
    }
    float i0=127.f/mx0, i1=127.f/mx1, i2=127.f/mx2, i3=127.f/mx3;
#pragma unroll
    for (int n=0;n<25;++n){
      uint4 wv;
      wv.x = p4(r0,n,i0); wv.y = p4(r1,n,i1); wv.z = p4(r2,n,i2); wv.w = p4(r3,n,i3);
      wreg[n] = wv;
    }
  }
  const float sc0 = mx0*(1.f/16129.f), sc1 = mx1*(1.f/16129.f);
  const float sc2 = mx2*(1.f/16129.f), sc3 = mx3*(1.f/16129.f);
  if (tid < 112) hq[tid] = 0u;
  float c = 0.f;
  __syncthreads();
  for (int step=0; step<TT; ++step){
    int ts = fwd ? step : (TT-1-step);
    if (act){
      // all 4 gate x-inputs for row j with one 8B load
      half4 xv = *(const half4*)(X + ts*G4 + j*4);
      // h window for this half (broadcast across lanes)
      const uint* hbp = hq + (step&1)*56 + half*28;
      uint4 hA = *(const uint4*)(hbp+0);
      uint4 hB = *(const uint4*)(hbp+4);
      uint4 hC = *(const uint4*)(hbp+8);
      uint4 hD = *(const uint4*)(hbp+12);
      uint4 hE = *(const uint4*)(hbp+16);
      uint4 hF = *(const uint4*)(hbp+20);
      uint  hG = hbp[24];
      int d0=0,d1=0,d2=0,d3=0;
#define DD(n,hu) { uint4 wv = wreg[n]; \
  d0=sdot4((int)wv.x,(int)(hu),d0); d1=sdot4((int)wv.y,(int)(hu),d1); \
  d2=sdot4((int)wv.z,(int)(hu),d2); d3=sdot4((int)wv.w,(int)(hu),d3); }
      DD(0,hA.x) DD(1,hA.y) DD(2,hA.z) DD(3,hA.w)
      DD(4,hB.x) DD(5,hB.y) DD(6,hB.z) DD(7,hB.w)
      DD(8,hC.x) DD(9,hC.y) DD(10,hC.z) DD(11,hC.w)
      DD(12,hD.x) DD(13,hD.y) DD(14,hD.z) DD(15,hD.w)
      DD(16,hE.x) DD(17,hE.y) DD(18,hE.z) DD(19,hE.w)
      DD(20,hF.x) DD(21,hF.y) DD(22,hF.z) DD(23,hF.w)
      DD(24,hG)
#undef DD
      float a0 = (float)d0*sc0 + (float)xv.x*0.5f;
      float a1 = (float)d1*sc1 + (float)xv.y*0.5f;
      float a2 = (float)d2*sc2 + (float)xv.z*0.5f;
      float a3 = (float)d3*sc3 + (float)xv.w*0.5f;
      // sum the two dim-halves (x added half in each lane -> once total)
      a0 += __shfl_xor(a0, 1, 64);
      a1 += __shfl_xor(a1, 1, 64);
      a2 += __shfl_xor(a2, 1, 64);
      a3 += __shfl_xor(a3, 1, 64);
      // gates: 0=i, 1=f, 2=g, 3=o
      c = sigf(a1)*c + sigf(a0)*tanhf_fast(a2);
      float h = sigf(a3)*tanhf_fast(c);
      if (half == 0){
        hout[ts*HH + j] = h;
        int q = (int)rintf(h*127.f);
        q = q<-127?-127:(q>127?127:q);
        int bufbyte = ((step+1)&1)*224 + (j<100 ? j : 112 + (j-100));
        ((unsigned char*)hq)[bufbyte] = (unsigned char)(q & 0xff);
      }
    }
    __syncthreads();
  }
}

// ---------------- K4: token attention-score MLP ----------------
__global__ void k_attn(const float* __restrict__ hf, const float* __restrict__ hb,
    const ushort* w1, const ushort* b1, const ushort* w2, const ushort* b2,
    const ushort* w3, const ushort* b3, float* __restrict__ attns){
  __shared__ float s[2*HH];
  __shared__ float h1[HS], h2[HS];
  int t = blockIdx.x;
  for (int k=threadIdx.x;k<2*HH;k+=256)
    s[k] = (k<HH) ? hf[t*HH+k] : hb[t*HH + (k-HH)];
  __syncthreads();
  int o = threadIdx.x;
  if (o < HS){
    float acc = bf2f(b1[o]);
    const ushort* wr = w1 + o*2*HH;
    for (int k=0;k<2*HH;k+=4){
      ushort4 wv = *(const ushort4*)(wr+k);
      acc += bf2f(wv.x)*s[k] + bf2f(wv.y)*s[k+1] + bf2f(wv.z)*s[k+2] + bf2f(wv.w)*s[k+3];
    }
    h1[o] = fmaxf(acc, 0.f);
  }
  __syncthreads();
  if (o < HS){
    float acc = bf2f(b2[o]);
    const ushort* wr = w2 + o*HS;
    for (int k=0;k<HS;k+=2) acc += bf2f(wr[k])*h1[k] + bf2f(wr[k+1])*h1[k+1];
    h2[o] = fmaxf(acc, 0.f);
  }
  __syncthreads();
  if (o == 0){
    float acc = bf2f(b3[0]);
    for (int k=0;k<HS;k++) acc += bf2f(w3[k])*h2[k];
    attns[t] = acc;
  }
}

// ---------------- K5: span features + mention MLP (8 spans/block) ----------------
__global__ void k_ment(const int* __restrict__ sstart, const int* __restrict__ send,
    const int* __restrict__ tok,
    const float* __restrict__ hf, const float* __restrict__ hb,
    const ushort* __restrict__ emb, const float* __restrict__ attns,
    const ushort* wemb,
    const float* __restrict__ w1f, const ushort* b1, const ushort* w2, const ushort* b2,
    const ushort* w3, const ushort* b3, float* __restrict__ si){
  __shared__ __align__(16) float G[8][GDIM];
  __shared__ float H1[8][152], H2[8][152];
  __shared__ float aw[8][WMAX];
  __shared__ int stok[8][WMAX];
  __shared__ int sst[8], sen[8], sbin[8];
  int s0 = blockIdx.x*8;
  if (threadIdx.x < 8){
    int sp = threadIdx.x;
    int st = sstart[s0+sp], en = send[s0+sp];
    sst[sp]=st; sen[sp]=en;
    int width = en - st + 1;
    sbin[sp] = binv(width);
    float lg[WMAX]; float mx = -1e30f;
    for (int wt=0; wt<WMAX; ++wt){
      int idx = st + wt; if (idx > TT-1) idx = TT-1;
      float l = (wt < width) ? attns[idx] : -1e9f;
      lg[wt] = l; mx = fmaxf(mx, l);
    }
    float den = 0.f;
    for (int wt=0; wt<WMAX; ++wt){ lg[wt] = __expf(lg[wt]-mx); den += lg[wt]; }
    float inv = 1.f/den;
    for (int wt=0; wt<WMAX; ++wt) aw[sp][wt] = lg[wt]*inv;
  }
  if (threadIdx.x < 8*WMAX){
    int sp = threadIdx.x / WMAX, wt = threadIdx.x - sp*WMAX;
    int idx = sstart[s0+sp] + wt; if (idx > TT-1) idx = TT-1;
    stok[sp][wt] = tok[idx];
  }
  __syncthreads();
  for (int i = threadIdx.x; i < 8*GDIM; i += 256){
    int sp = i / GDIM, f = i - sp*GDIM;
    int st = sst[sp], en = sen[sp];
    float v;
    if (f < HH) v = hf[st*HH + f];
    else if (f < 2*HH) v = hb[st*HH + (f-HH)];
    else if (f < 3*HH) v = hf[en*HH + (f-2*HH)];
    else if (f < 4*HH) v = hb[en*HH + (f-3*HH)];
    else if (f < 4*HH + EE){
      int e = f - 4*HH;
      float acc = 0.f;
      for (int wt=0; wt<WMAX; ++wt)
        acc += aw[sp][wt] * bf2f(emb[stok[sp][wt]*EE + e]);
      v = acc;
    } else {
      v = bf2f(wemb[sbin[sp]*FD + (f - (4*HH+EE))]);
    }
    G[sp][f] = v;
  }
  __syncthreads();
  for (int tt = threadIdx.x; tt < 8*HS; tt += 256){
    int sp = tt & 7, o = tt >> 3;
    float acc = bf2f(b1[o]);
    const float* wr = w1f + o*GDIM;
    for (int k=0;k<GDIM;k+=4){
      float4 wv = *(const float4*)(wr+k);
      float4 gv = *(const float4*)&G[sp][k];
      acc += wv.x*gv.x + wv.y*gv.y + wv.z*gv.z + wv.w*gv.w;
    }
    H1[sp][o] = fmaxf(acc, 0.f);
  }
  __syncthreads();
  for (int tt = threadIdx.x; tt < 8*HS; tt += 256){
    int sp = tt & 7, o = tt >> 3;
    float acc = bf2f(b2[o]);
    const ushort* wr = w2 + o*HS;
    for (int k=0;k<HS;k+=2) acc += bf2f(wr[k])*H1[sp][k] + bf2f(wr[k+1])*H1[sp][k+1];
    H2[sp][o] = fmaxf(acc, 0.f);
  }
  __syncthreads();
  if (threadIdx.x < 8){
    int sp = threadIdx.x;
    float acc = bf2f(b3[0]);
    for (int k=0;k<HS;k++) acc += bf2f(w3[k])*H2[sp][k];
    si[s0+sp] = sanit(acc);
  }
}

// ---------------- K6: top-384 + index-ordered compaction (single block) ----------------
// Histogram privatized per wave (16 copies): float keys cluster into few bins,
// so a single shared 256-bin histogram serializes on LDS atomics.
__global__ __launch_bounds__(1024) void k_select(const float* __restrict__ si,
    const int* __restrict__ sstart, const int* __restrict__ send,
    uint* __restrict__ keysb, int* __restrict__ keep, float* __restrict__ sk,
    int* __restrict__ stk, int* __restrict__ enk){
  __shared__ uint histw[16*256];
  __shared__ uint hist[256];
  __shared__ uint sG[1024], sE[1024];
  __shared__ uint bc[2];
  int tid = threadIdx.x;
  const int wv = tid >> 6;
  if (tid < NK){ keep[tid]=0; sk[tid]=0.f; stk[tid]=0; enk[tid]=0; }
  for (int i=tid;i<NS;i+=1024){
    uint u = __float_as_uint(si[i]);
    uint m = (u & 0x80000000u) ? ~u : (u | 0x80000000u);  // order-preserving map
    keysb[i] = m;
  }
  __syncthreads();
  uint prefix=0, mask=0; int K = NK;
  for (int p=3;p>=0;--p){
    int sh = p*8;
    for (int i=tid;i<16*256;i+=1024) histw[i]=0;
    __syncthreads();
    for (int i=tid;i<NS;i+=1024){
      uint m = keysb[i];
      if ((m & mask) == prefix) atomicAdd(&histw[wv*256 + ((m>>sh)&255u)], 1u);
    }
    __syncthreads();
    if (tid < 256){
      uint s = 0;
      for (int w=0;w<16;++w) s += histw[w*256 + tid];
      hist[tid] = s;
    }
    __syncthreads();
    if (tid==0){
      uint cum=0;
      bc[0]=0; bc[1]=(uint)K;
      for (int b=255; b>=0; --b){
        uint c = hist[b];
        if ((uint)K <= cum + c){ bc[0]=(uint)b; bc[1]=(uint)(K - (int)cum); break; }
        cum += c;
      }
    }
    __syncthreads();
    prefix |= bc[0] << sh;
    mask |= 0xFFu << sh;
    K = (int)bc[1];
    __syncthreads();
  }
  const uint V = prefix; const uint Eneed = (uint)K;
  int base = tid*20;
  uint cg=0, ce=0;
  for (int r=0;r<20;++r){
    uint m = keysb[base+r];
    cg += (m > V); ce += (m == V);
  }
  sG[tid]=cg; sE[tid]=ce;
  __syncthreads();
  for (int off=1; off<1024; off<<=1){
    uint aG=0,aE=0;
    if (tid>=off){ aG=sG[tid-off]; aE=sE[tid-off]; }
    __syncthreads();
    if (tid>=off){ sG[tid]+=aG; sE[tid]+=aE; }
    __syncthreads();
  }
  uint gbase = sG[tid]-cg, ebase = sE[tid]-ce;
  uint gseen=0, eseen=0;
  for (int r=0;r<20;++r){
    int i = base+r;
    uint m = keysb[i];
    if (m > V){
      uint eb = ebase+eseen; if (eb > Eneed) eb = Eneed;
      uint pos = gbase + gseen + eb;
      if (pos < NK){ keep[pos]=i; sk[pos]=si[i]; stk[pos]=sstart[i]; enk[pos]=send[i]; }
      gseen++;
    } else if (m == V){
      uint eb = ebase + eseen;
      if (eb < Eneed){
        uint pos = gbase + gseen + eb;
        if (pos < NK){ keep[pos]=i; sk[pos]=si[i]; stk[pos]=sstart[i]; enk[pos]=send[i]; }
      }
      eseen++;
    }
  }
}

// ---------------- K7: rebuild g for kept spans ----------------
__global__ void k_gk(const int* __restrict__ keep, const int* __restrict__ tok,
    const float* __restrict__ hf, const float* __restrict__ hb,
    const ushort* __restrict__ emb, const float* __restrict__ attns,
    const ushort* wemb, const int* __restrict__ sstart, const int* __restrict__ send,
    float* __restrict__ gk){
  __shared__ float aw[WMAX];
  __shared__ int stok1[WMAX];
  __shared__ int sstv, senv, sbinv;
  int b = blockIdx.x;
  if (threadIdx.x == 0){
    int s = keep[b]; s = s < 0 ? 0 : (s >= NS ? NS-1 : s);
    int st = sstart[s], en = send[s];
    sstv=st; senv=en;
    int width = en-st+1;
    sbinv = binv(width);
    float lg[WMAX]; float mx=-1e30f;
    for (int wt=0;wt<WMAX;++wt){
      int idx = st+wt; if (idx>TT-1) idx=TT-1;
      float l = (wt<width)? attns[idx] : -1e9f;
      lg[wt]=l; mx=fmaxf(mx,l);
    }
    float den=0.f;
    for (int wt=0;wt<WMAX;++wt){ lg[wt]=__expf(lg[wt]-mx); den+=lg[wt]; }
    float inv=1.f/den;
    for (int wt=0;wt<WMAX;++wt) aw[wt]=lg[wt]*inv;
  }
  if (threadIdx.x < WMAX){
    int s = keep[b]; s = s < 0 ? 0 : (s >= NS ? NS-1 : s);
    int idx = sstart[s] + threadIdx.x; if (idx>TT-1) idx=TT-1;
    stok1[threadIdx.x] = tok[idx];
  }
  __syncthreads();
  int st=sstv, en=senv;
  for (int f=threadIdx.x; f<GDIM; f+=256){
    float v;
    if (f < HH) v = hf[st*HH + f];
    else if (f < 2*HH) v = hb[st*HH + (f-HH)];
    else if (f < 3*HH) v = hf[en*HH + (f-2*HH)];
    else if (f < 4*HH) v = hb[en*HH + (f-3*HH)];
    else if (f < 4*HH + EE){
      int e = f - 4*HH;
      float acc = 0.f;
      for (int wt=0; wt<WMAX; ++wt)
        acc += aw[wt] * bf2f(emb[stok1[wt]*EE + e]);
      v = acc;
    } else {
      v = bf2f(wemb[sbinv*FD + (f - (4*HH+EE))]);
    }
    gk[b*GDIM + f] = v;
  }
}

// ---------------- K8a: P[i]=w1a.gk[i], Q[i]=w1b.gk[i]; also eps column ----------------
__global__ void k_pq(const float* __restrict__ gk, const ushort* __restrict__ w1,
                     float* __restrict__ P, float* __restrict__ Q, float* __restrict__ out){
  __shared__ __align__(16) float gi[GDIM];
  int i = blockIdx.x, which = blockIdx.y;
  for (int k=threadIdx.x;k<GDIM;k+=256) gi[k]=gk[i*GDIM+k];
  __syncthreads();
  if (which==0 && threadIdx.x==0) out[i*OUTC + NA] = 0.0f;   // eps column
  int o = threadIdx.x;
  if (o < HS){
    const ushort* wr = w1 + o*3680 + which*GDIM;
    float acc=0.f;
    for (int k=0;k<GDIM;k+=4){
      ushort4 wv = *(const ushort4*)(wr+k);
      acc += bf2f(wv.x)*gi[k]+bf2f(wv.y)*gi[k+1]+bf2f(wv.z)*gi[k+2]+bf2f(wv.w)*gi[k+3];
    }
    (which? Q : P)[i*HS+o] = acc;
  }
}

// ---------------- K8b: pair MLP (decomposed layer-1), 16 antecedents/block ----------------
__global__ void k_pair(const float* __restrict__ gk, const float* __restrict__ P,
    const float* __restrict__ Q, const float* __restrict__ sk,
    const int* __restrict__ stk, const int* __restrict__ enk,
    const float* __restrict__ w1f, const ushort* w1, const ushort* b1,
    const ushort* w2, const ushort* b2,
    const ushort* w3, const ushort* b3, const ushort* demb, float* __restrict__ out){
  __shared__ __align__(16) float gi[GDIM];
  __shared__ float Pi[152];
  __shared__ float Dall[9*HS];
  __shared__ __align__(16) float GIJ[8][GDIM];
  __shared__ float H1[8][152], H2[8][152];
  __shared__ int jcA[16], dbA[16], vA[16];
  __shared__ float skj[16];
  int i = blockIdx.x;
  int d0 = blockIdx.y*16;
  if (i - 1 - d0 < 0){
    for (int d = threadIdx.x; d < 16; d += 256) out[i*OUTC + d0 + d] = -1e9f;
    return;
  }
  for (int k=threadIdx.x;k<GDIM;k+=256) gi[k]=gk[i*GDIM+k];
  for (int o=threadIdx.x;o<HS;o+=256) Pi[o]=P[i*HS+o];
  if (threadIdx.x < 16){
    int dcol = d0 + threadIdx.x;
    int j = i - 1 - dcol;
    int jc = j<0?0:j;
    vA[threadIdx.x]=(j>=0);
    jcA[threadIdx.x]=jc;
    dbA[threadIdx.x]=binv(enk[i]-stk[jc]);
    skj[threadIdx.x]=sk[jc];
  }
  for (int tt=threadIdx.x; tt<9*HS; tt+=256){
    int o = tt/9, b = tt - (tt/9)*9;
    float acc = bf2f(b1[o]);
    const ushort* wr = w1 + o*3680 + 3660;
    const ushort* de = demb + b*FD;
    for (int k=0;k<FD;k++) acc += bf2f(wr[k])*bf2f(de[k]);
    Dall[b*HS+o] = acc;
  }
  __syncthreads();
  float ski = sk[i];
  for (int dt=0; dt<2; ++dt){
    if (i - 1 - (d0 + dt*8) < 0){
      if (threadIdx.x < 8) out[i*OUTC + d0 + dt*8 + threadIdx.x] = -1e9f;
      continue;
    }
    __syncthreads();
    for (int idx=threadIdx.x; idx<8*GDIM; idx+=256){
      int dd = idx / GDIM, k = idx - dd*GDIM;
      GIJ[dd][k] = gi[k]*gk[jcA[dt*8+dd]*GDIM + k];
    }
    __syncthreads();
    {
      int dd = threadIdx.x & 7, og = threadIdx.x >> 3;
      for (int o=og; o<HS; o+=32){
        const float* wr = w1f + o*GDIM;
        float acc = 0.f;
        for (int k=0;k<GDIM;k+=4){
          float4 wv = *(const float4*)(wr+k);
          float4 gv = *(const float4*)&GIJ[dd][k];
          acc += wv.x*gv.x + wv.y*gv.y + wv.z*gv.z + wv.w*gv.w;
        }
        int d = dt*8+dd;
        acc += Pi[o] + Q[jcA[d]*HS+o] + Dall[dbA[d]*HS+o];
        H1[dd][o] = fmaxf(acc, 0.f);
      }
    }
    __syncthreads();
    {
      int dd = threadIdx.x & 7, og = threadIdx.x >> 3;
      for (int o=og;o<HS;o+=32){
        float acc = bf2f(b2[o]);
        const ushort* wr = w2 + o*HS;
        for (int k=0;k<HS;k+=2) acc += bf2f(wr[k])*H1[dd][k] + bf2f(wr[k+1])*H1[dd][k+1];
        H2[dd][o]=fmaxf(acc,0.f);
      }
    }
    __syncthreads();
    if (threadIdx.x < 8){
      int dd = threadIdx.x;
      float acc = bf2f(b3[0]);
      for (int k=0;k<HS;k++) acc += bf2f(w3[k])*H2[dd][k];
      int d = dt*8+dd;
      float raw = sanit(ski + skj[d] + acc);
      float v = vA[d] ? raw : -1e9f;
      out[i*OUTC + d0 + d] = v;
    }
  }
}

extern "C" void kernel_launch(void* const* d_in, const int* in_sizes, int n_in,
                              void* d_out, int out_size, void* d_ws, size_t ws_size,
                              hipStream_t stream){
  (void)in_sizes; (void)n_in; (void)out_size; (void)ws_size;
  const int*    tok   = (const int*)d_in[0];
  const int*    sst   = (const int*)d_in[1];
  const int*    sen   = (const int*)d_in[2];
  const ushort* emb   = (const ushort*)d_in[3];
  const ushort* wih_f = (const ushort*)d_in[4];
  const ushort* whh_f = (const ushort*)d_in[5];
  const ushort* b_f   = (const ushort*)d_in[6];
  const ushort* wih_b = (const ushort*)d_in[7];
  const ushort* whh_b = (const ushort*)d_in[8];
  const ushort* b_b   = (const ushort*)d_in[9];
  const ushort* aw1=(const ushort*)d_in[10]; const ushort* ab1=(const ushort*)d_in[11];
  const ushort* aw2=(const ushort*)d_in[12]; const ushort* ab2=(const ushort*)d_in[13];
  const ushort* aw3=(const ushort*)d_in[14]; const ushort* ab3=(const ushort*)d_in[15];
  const ushort* wemb=(const ushort*)d_in[16];
  const ushort* mw1=(const ushort*)d_in[17]; const ushort* mb1=(const ushort*)d_in[18];
  const ushort* mw2=(const ushort*)d_in[19]; const ushort* mb2=(const ushort*)d_in[20];
  const ushort* mw3=(const ushort*)d_in[21]; const ushort* mb3=(const ushort*)d_in[22];
  const ushort* demb=(const ushort*)d_in[23];
  const ushort* pw1=(const ushort*)d_in[24]; const ushort* pb1=(const ushort*)d_in[25];
  const ushort* pw2=(const ushort*)d_in[26]; const ushort* pb2=(const ushort*)d_in[27];
  const ushort* pw3=(const ushort*)d_in[28]; const ushort* pb3=(const ushort*)d_in[29];
  float* out = (float*)d_out;

  float* ws     = (float*)d_ws;
  float* hfw    = ws;                       // 409600
  float* hbw    = hfw + TT*HH;              // 409600
  float* attns  = hbw + TT*HH;              // 2048
  float* si     = attns + TT;               // 20480
  float* sk     = si + NS;                  // 384
  float* Pb     = sk + NK;                  // 57600
  float* Qb     = Pb + NK*HS;               // 57600
  float* gkw    = Qb + NK*HS;               // 468480
  _Float16* Xf  = (_Float16*)(gkw + NK*GDIM); // 1638400 halves
  _Float16* Xb  = Xf + TT*G4;                 // 1638400 halves
  int*   keep   = (int*)(Xb + TT*G4);       // 384
  int*   stk    = keep + NK;                // 384
  int*   enk    = stk + NK;                 // 384
  uint*  keysb  = (uint*)(enk + NK);        // 20480
  float* mw1f   = (float*)(keysb + NS);     // 183000 floats
  float* pw1f   = mw1f + HS*GDIM;           // 183000 floats
  // total ~13.8 MB of d_ws

  k_prep<<<(HS*GDIM+255)/256,256,0,stream>>>(mw1, pw1, mw1f, pw1f);
  k_xproj<<<TT/4,256,0,stream>>>(tok, emb, wih_f, b_f, wih_b, b_b, Xf, Xb);
  k_lstm<<<2,448,0,stream>>>(whh_f, whh_b, Xf, Xb, hfw, hbw);
  k_attn<<<TT,256,0,stream>>>(hfw,hbw,aw1,ab1,aw2,ab2,aw3,ab3,attns);
  k_ment<<<NS/8,256,0,stream>>>(sst,sen,tok,hfw,hbw,emb,attns,wemb,mw1f,mb1,mw2,mb2,mw3,mb3,si);
  k_select<<<1,1024,0,stream>>>(si,sst,sen,keysb,keep,sk,stk,enk);
  k_gk<<<NK,256,0,stream>>>(keep,tok,hfw,hbw,emb,attns,wemb,sst,sen,gkw);
  k_pq<<<dim3(NK,2),256,0,stream>>>(gkw,pw1,Pb,Qb,out);
  k_pair<<<dim3(NK,8),256,0,stream>>>(gkw,Pb,Qb,sk,stk,enk,pw1f,pw1,pb1,pw2,pb2,pw3,pb3,demb,out);
}

// Round 6
// 4666.131 us; speedup vs baseline: 1.0499x; 1.0291x over previous
//
#include <hip/hip_runtime.h>

#define TT 2048
#define EE 400
#define HH 200
#define G4 800
#define NS 20480
#define WMAX 10
#define HS 150
#define FD 20
#define GDIM 1220
#define NK 384
#define NA 128
#define OUTC 129

typedef unsigned int uint;
typedef unsigned short ushort;
typedef _Float16 half4 __attribute__((ext_vector_type(4)));

__device__ __forceinline__ float bf2f(ushort u){ return __uint_as_float(((uint)u)<<16); }
__device__ __forceinline__ int binv(int x){
  int b=0;
  b += (x>=1); b += (x>=2); b += (x>=3); b += (x>=4);
  b += (x>=8); b += (x>=16); b += (x>=32); b += (x>=64);
  return b;
}
__device__ __forceinline__ float sigf(float x){ return 1.0f/(1.0f+__expf(-x)); }
__device__ __forceinline__ float tanhf_fast(float x){
  float t = __expf(-2.0f*fabsf(x));       // in (0,1], never overflows
  float r = (1.0f - t)/(1.0f + t);
  return copysignf(r, x);
}
__device__ __forceinline__ float sanit(float x){ return (fabsf(x) <= 1e30f) ? x : 0.f; }

__device__ __forceinline__ int sdot4(int a, int b, int c){
#if __has_builtin(__builtin_amdgcn_sdot4)
  return __builtin_amdgcn_sdot4(a, b, c, false);
#else
  int r = c;
  r += (int)(signed char)(a)     * (int)(signed char)(b);
  r += (int)(signed char)(a>>8)  * (int)(signed char)(b>>8);
  r += (int)(signed char)(a>>16) * (int)(signed char)(b>>16);
  r += (int)(signed char)(a>>24) * (int)(signed char)(b>>24);
  return r;
#endif
}

// pack 4 dims (4n..4n+3) of a bf16 row into one int8 uint
__device__ __forceinline__ uint p4(const ushort* __restrict__ row, int n, float inv){
  uint r = 0;
#pragma unroll
  for (int b=0;b<4;++b){
    float w = bf2f(row[4*n+b]);
    int q = (int)rintf(w * inv);
    q = q < -127 ? -127 : (q > 127 ? 127 : q);
    r |= ((uint)(q & 0xff)) << (8*b);
  }
  return r;
}

// ---------------- K2: LSTM input projections (direct emb gather, f16 out) ----------------
// X layout: [t][j*4 + gate]  so k_lstm reads all 4 gate inputs of row j with ONE 8B load.
__global__ void k_xproj(const int* __restrict__ tok, const ushort* __restrict__ emb,
                        const ushort* __restrict__ wf, const ushort* __restrict__ bfv,
                        const ushort* __restrict__ wb, const ushort* __restrict__ bbv,
                        _Float16* __restrict__ Xf, _Float16* __restrict__ Xb){
  __shared__ float x4[4][EE];
  __shared__ int tk[4];
  int t0 = blockIdx.x*4;
  if (threadIdx.x < 4) tk[threadIdx.x] = tok[t0+threadIdx.x];
  __syncthreads();
  for (int i = threadIdx.x; i < 4*EE; i += 256){
    int m = i / EE, e = i - m*EE;
    x4[m][e] = bf2f(emb[tk[m]*EE + e]);
  }
  __syncthreads();
  for (int tt = threadIdx.x; tt < 2*G4; tt += 256){
    int dir = (tt >= G4);
    int row = dir ? tt - G4 : tt;
    const ushort* wr = (dir ? wb : wf) + row*EE;
    float bias = bf2f((dir ? bbv : bfv)[row]);
    float a0=bias,a1=bias,a2=bias,a3=bias;
    for (int k=0;k<EE;k+=4){
      ushort4 wv = *(const ushort4*)(wr+k);
      float w0=bf2f(wv.x), w1=bf2f(wv.y), w2=bf2f(wv.z), w3=bf2f(wv.w);
      a0 += w0*x4[0][k] + w1*x4[0][k+1] + w2*x4[0][k+2] + w3*x4[0][k+3];
      a1 += w0*x4[1][k] + w1*x4[1][k+1] + w2*x4[1][k+2] + w3*x4[1][k+3];
      a2 += w0*x4[2][k] + w1*x4[2][k+1] + w2*x4[2][k+2] + w3*x4[2][k+3];
      a3 += w0*x4[3][k] + w1*x4[3][k+1] + w2*x4[3][k+2] + w3*x4[3][k+3];
    }
    _Float16* X = dir ? Xb : Xf;
    int g = row / HH, jj = row - g*HH;
    int col = jj*4 + g;
    X[(t0+0)*G4+col]=(_Float16)a0; X[(t0+1)*G4+col]=(_Float16)a1;
    X[(t0+2)*G4+col]=(_Float16)a2; X[(t0+3)*G4+col]=(_Float16)a3;
  }
}

// ---------------- K3: sequential bi-LSTM (block0=fwd, block1=bwd) ----------------
// Round-1 step body + plain __syncthreads (proven floor). Single change: h
// output is accumulated in an LDS double buffer and flushed to global once
// per 8 steps AT THE TOP of the step, so the flush store retires ~1800cy
// before its barrier and the per-step vmcnt(0) drain in __syncthreads never
// waits on a just-issued store (R1 paid store-ack latency at EVERY barrier).
__global__ __launch_bounds__(448, 2) void k_lstm(const ushort* __restrict__ whh_f,
                        const ushort* __restrict__ whh_b,
                        const _Float16* __restrict__ Xf, const _Float16* __restrict__ Xb,
                        float* __restrict__ hf, float* __restrict__ hb){
  __shared__ __align__(16) uint  hq[112];          // 2 x 224-B int8 h buffers (28dw halves)
  __shared__ __align__(16) float hob[2][8][HH];    // 2 x 8-step f32 h-out staging (12.8 KB)
  const int tid = threadIdx.x;
  const int fwd = (blockIdx.x == 0);
  const ushort* whh = fwd ? whh_f : whh_b;
  const _Float16* X = fwd ? Xf : Xb;
  float* hout = fwd ? hf : hb;
  const bool act = (tid < 400);
  const int j = tid >> 1;                // 0..199
  const int half = tid & 1;              // dim half

  uint4 wreg[25];                        // per-lane int8 weights, in registers
  float mx0=1e-20f, mx1=1e-20f, mx2=1e-20f, mx3=1e-20f;
  if (act){
    const ushort* r0 = whh + (0*HH + j)*HH + half*100;
    const ushort* r1 = whh + (1*HH + j)*HH + half*100;
    const ushort* r2 = whh + (2*HH + j)*HH + half*100;
    const ushort* r3 = whh + (3*HH + j)*HH + half*100;
    for (int d=0; d<100; d+=2){
      ushort2 v0 = *(const ushort2*)(r0+d);
      ushort2 v1 = *(const ushort2*)(r1+d);
      ushort2 v2 = *(const ushort2*)(r2+d);
      ushort2 v3 = *(const ushort2*)(r3+d);
      mx0 = fmaxf(mx0, fmaxf(fabsf(bf2f(v0.x)), fabsf(bf2f(v0.y))));
      mx1 = fmaxf(mx1, fmaxf(fabsf(bf2f(v1.x)), fabsf(bf2f(v1.y))));
      mx2 = fmaxf(mx2, fmaxf(fabsf(bf2f(v2.x)), fabsf(bf2f(v2.y))));
      mx3 = fmaxf(mx3, fmaxf(fabsf(bf2f(v3.x)), fabsf(bf2f(v3.y))));
    }
    float i0=127.f/mx0, i1=127.f/mx1, i2=127.f/mx2, i3=127.f/mx3;
#pragma unroll
    for (int n=0;n<25;++n){
      uint4 wv;
      wv.x = p4(r0,n,i0); wv.y = p4(r1,n,i1); wv.z = p4(r2,n,i2); wv.w = p4(r3,n,i3);
      wreg[n] = wv;
    }
  }
  const float sc0 = mx0*(1.f/16129.f), sc1 = mx1*(1.f/16129.f);
  const float sc2 = mx2*(1.f/16129.f), sc3 = mx3*(1.f/16129.f);
  if (tid < 112) hq[tid] = 0u;
  float c = 0.f;
  __syncthreads();
  for (int step=0; step<TT; ++step){
    int ts = fwd ? step : (TT-1-step);
    if (act){
      // flush previous 8-step chunk (its LDS writes are barrier-ordered; the
      // store has the whole step to retire before this step's barrier)
      if ((step & 7) == 0 && step > 0){
        int cprev = (step>>3) - 1;
        int g4 = tid*4;                       // 0..1596
        int row = g4 / HH;                    // 0..7
        int col = g4 - row*HH;
        int si_row = fwd ? row : (7-row);
        int base = fwd ? (cprev*8)*HH : (TT-8-cprev*8)*HH;
        float4 v = *(const float4*)&hob[cprev&1][si_row][col];
        *(float4*)&hout[base + g4] = v;
      }
      // all 4 gate x-inputs for row j with one 8B load
      half4 xv = *(const half4*)(X + ts*G4 + j*4);
      // h window for this half (broadcast across lanes)
      const uint* hbp = hq + (step&1)*56 + half*28;
      uint4 hA = *(const uint4*)(hbp+0);
      uint4 hB = *(const uint4*)(hbp+4);
      uint4 hC = *(const uint4*)(hbp+8);
      uint4 hD = *(const uint4*)(hbp+12);
      uint4 hE = *(const uint4*)(hbp+16);
      uint4 hF = *(const uint4*)(hbp+20);
      uint  hG = hbp[24];
      int d0=0,d1=0,d2=0,d3=0;
#define DD(n,hu) { uint4 wv = wreg[n]; \
  d0=sdot4((int)wv.x,(int)(hu),d0); d1=sdot4((int)wv.y,(int)(hu),d1); \
  d2=sdot4((int)wv.z,(int)(hu),d2); d3=sdot4((int)wv.w,(int)(hu),d3); }
      DD(0,hA.x) DD(1,hA.y) DD(2,hA.z) DD(3,hA.w)
      DD(4,hB.x) DD(5,hB.y) DD(6,hB.z) DD(7,hB.w)
      DD(8,hC.x) DD(9,hC.y) DD(10,hC.z) DD(11,hC.w)
      DD(12,hD.x) DD(13,hD.y) DD(14,hD.z) DD(15,hD.w)
      DD(16,hE.x) DD(17,hE.y) DD(18,hE.z) DD(19,hE.w)
      DD(20,hF.x) DD(21,hF.y) DD(22,hF.z) DD(23,hF.w)
      DD(24,hG)
#undef DD
      float a0 = (float)d0*sc0 + (float)xv.x*0.5f;
      float a1 = (float)d1*sc1 + (float)xv.y*0.5f;
      float a2 = (float)d2*sc2 + (float)xv.z*0.5f;
      float a3 = (float)d3*sc3 + (float)xv.w*0.5f;
      // sum the two dim-halves (x added half in each lane -> once total)
      a0 += __shfl_xor(a0, 1, 64);
      a1 += __shfl_xor(a1, 1, 64);
      a2 += __shfl_xor(a2, 1, 64);
      a3 += __shfl_xor(a3, 1, 64);
      // gates: 0=i, 1=f, 2=g, 3=o
      c = sigf(a1)*c + sigf(a0)*tanhf_fast(a2);
      float h = sigf(a3)*tanhf_fast(c);
      if (half == 0){
        hob[(step>>3)&1][step&7][j] = h;     // LDS staging (was: global store)
        int q = (int)rintf(h*127.f);
        q = q<-127?-127:(q>127?127:q);
        int bufbyte = ((step+1)&1)*224 + (j<100 ? j : 112 + (j-100));
        ((unsigned char*)hq)[bufbyte] = (unsigned char)(q & 0xff);
      }
    }
    __syncthreads();
  }
  // final flush: chunk 255 (buffer 1); last barrier made its writes visible
  if (act){
    const int cprev = 255;
    int g4 = tid*4;
    int row = g4 / HH;
    int col = g4 - row*HH;
    int si_row = fwd ? row : (7-row);
    int base = fwd ? (cprev*8)*HH : (TT-8-cprev*8)*HH;
    float4 v = *(const float4*)&hob[cprev&1][si_row][col];
    *(float4*)&hout[base + g4] = v;
  }
}

// ---------------- K4: token attention-score MLP ----------------
__global__ void k_attn(const float* __restrict__ hf, const float* __restrict__ hb,
    const ushort* w1, const ushort* b1, const ushort* w2, const ushort* b2,
    const ushort* w3, const ushort* b3, float* __restrict__ attns){
  __shared__ float s[2*HH];
  __shared__ float h1[HS], h2[HS];
  int t = blockIdx.x;
  for (int k=threadIdx.x;k<2*HH;k+=256)
    s[k] = (k<HH) ? hf[t*HH+k] : hb[t*HH + (k-HH)];
  __syncthreads();
  int o = threadIdx.x;
  if (o < HS){
    float acc = bf2f(b1[o]);
    const ushort* wr = w1 + o*2*HH;
    for (int k=0;k<2*HH;k+=4){
      ushort4 wv = *(const ushort4*)(wr+k);
      acc += bf2f(wv.x)*s[k] + bf2f(wv.y)*s[k+1] + bf2f(wv.z)*s[k+2] + bf2f(wv.w)*s[k+3];
    }
    h1[o] = fmaxf(acc, 0.f);
  }
  __syncthreads();
  if (o < HS){
    float acc = bf2f(b2[o]);
    const ushort* wr = w2 + o*HS;
    for (int k=0;k<HS;k+=2) acc += bf2f(wr[k])*h1[k] + bf2f(wr[k+1])*h1[k+1];
    h2[o] = fmaxf(acc, 0.f);
  }
  __syncthreads();
  if (o == 0){
    float acc = bf2f(b3[0]);
    for (int k=0;k<HS;k++) acc += bf2f(w3[k])*h2[k];
    attns[t] = acc;
  }
}

// ---------------- K5: span features + mention MLP (8 spans/block) ----------------
__global__ void k_ment(const int* __restrict__ sstart, const int* __restrict__ send,
    const int* __restrict__ tok,
    const float* __restrict__ hf, const float* __restrict__ hb,
    const ushort* __restrict__ emb, const float* __restrict__ attns,
    const ushort* wemb,
    const ushort* w1, const ushort* b1, const ushort* w2, const ushort* b2,
    const ushort* w3, const ushort* b3, float* __restrict__ si){
  __shared__ __align__(16) float G[8][GDIM];
  __shared__ float H1[8][152], H2[8][152];
  __shared__ float aw[8][WMAX];
  __shared__ int stok[8][WMAX];
  __shared__ int sst[8], sen[8], sbin[8];
  int s0 = blockIdx.x*8;
  if (threadIdx.x < 8){
    int sp = threadIdx.x;
    int st = sstart[s0+sp], en = send[s0+sp];
    sst[sp]=st; sen[sp]=en;
    int width = en - st + 1;
    sbin[sp] = binv(width);
    float lg[WMAX]; float mx = -1e30f;
    for (int wt=0; wt<WMAX; ++wt){
      int idx = st + wt; if (idx > TT-1) idx = TT-1;
      float l = (wt < width) ? attns[idx] : -1e9f;
      lg[wt] = l; mx = fmaxf(mx, l);
    }
    float den = 0.f;
    for (int wt=0; wt<WMAX; ++wt){ lg[wt] = __expf(lg[wt]-mx); den += lg[wt]; }
    float inv = 1.f/den;
    for (int wt=0; wt<WMAX; ++wt) aw[sp][wt] = lg[wt]*inv;
  }
  if (threadIdx.x < 8*WMAX){
    int sp = threadIdx.x / WMAX, wt = threadIdx.x - sp*WMAX;
    int idx = sstart[s0+sp] + wt; if (idx > TT-1) idx = TT-1;
    stok[sp][wt] = tok[idx];
  }
  __syncthreads();
  for (int i = threadIdx.x; i < 8*GDIM; i += 256){
    int sp = i / GDIM, f = i - sp*GDIM;
    int st = sst[sp], en = sen[sp];
    float v;
    if (f < HH) v = hf[st*HH + f];
    else if (f < 2*HH) v = hb[st*HH + (f-HH)];
    else if (f < 3*HH) v = hf[en*HH + (f-2*HH)];
    else if (f < 4*HH) v = hb[en*HH + (f-3*HH)];
    else if (f < 4*HH + EE){
      int e = f - 4*HH;
      float acc = 0.f;
      for (int wt=0; wt<WMAX; ++wt)
        acc += aw[sp][wt] * bf2f(emb[stok[sp][wt]*EE + e]);
      v = acc;
    } else {
      v = bf2f(wemb[sbin[sp]*FD + (f - (4*HH+EE))]);
    }
    G[sp][f] = v;
  }
  __syncthreads();
  for (int tt = threadIdx.x; tt < 8*HS; tt += 256){
    int sp = tt & 7, o = tt >> 3;
    float acc = bf2f(b1[o]);
    const ushort* wr = w1 + o*GDIM;
    for (int k=0;k<GDIM;k+=4){
      ushort4 wv = *(const ushort4*)(wr+k);
      acc += bf2f(wv.x)*G[sp][k] + bf2f(wv.y)*G[sp][k+1]
           + bf2f(wv.z)*G[sp][k+2] + bf2f(wv.w)*G[sp][k+3];
    }
    H1[sp][o] = fmaxf(acc, 0.f);
  }
  __syncthreads();
  for (int tt = threadIdx.x; tt < 8*HS; tt += 256){
    int sp = tt & 7, o = tt >> 3;
    float acc = bf2f(b2[o]);
    const ushort* wr = w2 + o*HS;
    for (int k=0;k<HS;k+=2) acc += bf2f(wr[k])*H1[sp][k] + bf2f(wr[k+1])*H1[sp][k+1];
    H2[sp][o] = fmaxf(acc, 0.f);
  }
  __syncthreads();
  if (threadIdx.x < 8){
    int sp = threadIdx.x;
    float acc = bf2f(b3[0]);
    for (int k=0;k<HS;k++) acc += bf2f(w3[k])*H2[sp][k];
    si[s0+sp] = sanit(acc);
  }
}

// ---------------- K6: top-384 + index-ordered compaction (single block) ----------------
__global__ __launch_bounds__(1024) void k_select(const float* __restrict__ si,
    const int* __restrict__ sstart, const int* __restrict__ send,
    uint* __restrict__ keysb, int* __restrict__ keep, float* __restrict__ sk,
    int* __restrict__ stk, int* __restrict__ enk){
  __shared__ uint hist[256];
  __shared__ uint sG[1024], sE[1024];
  __shared__ uint bc[2];
  int tid = threadIdx.x;
  if (tid < NK){ keep[tid]=0; sk[tid]=0.f; stk[tid]=0; enk[tid]=0; }
  for (int i=tid;i<NS;i+=1024){
    uint u = __float_as_uint(si[i]);
    uint m = (u & 0x80000000u) ? ~u : (u | 0x80000000u);  // order-preserving map
    keysb[i] = m;
  }
  __syncthreads();
  uint prefix=0, mask=0; int K = NK;
  for (int p=3;p>=0;--p){
    int sh = p*8;
    if (tid<256) hist[tid]=0;
    __syncthreads();
    for (int i=tid;i<NS;i+=1024){
      uint m = keysb[i];
      if ((m & mask) == prefix) atomicAdd(&hist[(m>>sh)&255u], 1u);
    }
    __syncthreads();
    if (tid==0){
      uint cum=0;
      bc[0]=0; bc[1]=(uint)K;
      for (int b=255; b>=0; --b){
        uint c = hist[b];
        if ((uint)K <= cum + c){ bc[0]=(uint)b; bc[1]=(uint)(K - (int)cum); break; }
        cum += c;
      }
    }
    __syncthreads();
    prefix |= bc[0] << sh;
    mask |= 0xFFu << sh;
    K = (int)bc[1];
    __syncthreads();
  }
  const uint V = prefix; const uint Eneed = (uint)K;
  int base = tid*20;
  uint cg=0, ce=0;
  for (int r=0;r<20;++r){
    uint m = keysb[base+r];
    cg += (m > V); ce += (m == V);
  }
  sG[tid]=cg; sE[tid]=ce;
  __syncthreads();
  for (int off=1; off<1024; off<<=1){
    uint aG=0,aE=0;
    if (tid>=off){ aG=sG[tid-off]; aE=sE[tid-off]; }
    __syncthreads();
    if (tid>=off){ sG[tid]+=aG; sE[tid]+=aE; }
    __syncthreads();
  }
  uint gbase = sG[tid]-cg, ebase = sE[tid]-ce;
  uint gseen=0, eseen=0;
  for (int r=0;r<20;++r){
    int i = base+r;
    uint m = keysb[i];
    if (m > V){
      uint eb = ebase+eseen; if (eb > Eneed) eb = Eneed;
      uint pos = gbase + gseen + eb;
      if (pos < NK){ keep[pos]=i; sk[pos]=si[i]; stk[pos]=sstart[i]; enk[pos]=send[i]; }
      gseen++;
    } else if (m == V){
      uint eb = ebase + eseen;
      if (eb < Eneed){
        uint pos = gbase + gseen + eb;
        if (pos < NK){ keep[pos]=i; sk[pos]=si[i]; stk[pos]=sstart[i]; enk[pos]=send[i]; }
      }
      eseen++;
    }
  }
}

// ---------------- K7: rebuild g for kept spans ----------------
__global__ void k_gk(const int* __restrict__ keep, const int* __restrict__ tok,
    const float* __restrict__ hf, const float* __restrict__ hb,
    const ushort* __restrict__ emb, const float* __restrict__ attns,
    const ushort* wemb, const int* __restrict__ sstart, const int* __restrict__ send,
    float* __restrict__ gk){
  __shared__ float aw[WMAX];
  __shared__ int stok1[WMAX];
  __shared__ int sstv, senv, sbinv;
  int b = blockIdx.x;
  if (threadIdx.x == 0){
    int s = keep[b]; s = s < 0 ? 0 : (s >= NS ? NS-1 : s);
    int st = sstart[s], en = send[s];
    sstv=st; senv=en;
    int width = en-st+1;
    sbinv = binv(width);
    float lg[WMAX]; float mx=-1e30f;
    for (int wt=0;wt<WMAX;++wt){
      int idx = st+wt; if (idx>TT-1) idx=TT-1;
      float l = (wt<width)? attns[idx] : -1e9f;
      lg[wt]=l; mx=fmaxf(mx,l);
    }
    float den=0.f;
    for (int wt=0;wt<WMAX;++wt){ lg[wt]=__expf(lg[wt]-mx); den+=lg[wt]; }
    float inv=1.f/den;
    for (int wt=0;wt<WMAX;++wt) aw[wt]=lg[wt]*inv;
  }
  if (threadIdx.x < WMAX){
    int s = keep[b]; s = s < 0 ? 0 : (s >= NS ? NS-1 : s);
    int idx = sstart[s] + threadIdx.x; if (idx>TT-1) idx=TT-1;
    stok1[threadIdx.x] = tok[idx];
  }
  __syncthreads();
  int st=sstv, en=senv;
  for (int f=threadIdx.x; f<GDIM; f+=256){
    float v;
    if (f < HH) v = hf[st*HH + f];
    else if (f < 2*HH) v = hb[st*HH + (f-HH)];
    else if (f < 3*HH) v = hf[en*HH + (f-2*HH)];
    else if (f < 4*HH) v = hb[en*HH + (f-3*HH)];
    else if (f < 4*HH + EE){
      int e = f - 4*HH;
      float acc = 0.f;
      for (int wt=0; wt<WMAX; ++wt)
        acc += aw[wt] * bf2f(emb[stok1[wt]*EE + e]);
      v = acc;
    } else {
      v = bf2f(wemb[sbinv*FD + (f - (4*HH+EE))]);
    }
    gk[b*GDIM + f] = v;
  }
}

// ---------------- K8a: P[i]=w1a.gk[i], Q[i]=w1b.gk[i]; also eps column ----------------
__global__ void k_pq(const float* __restrict__ gk, const ushort* __restrict__ w1,
                     float* __restrict__ P, float* __restrict__ Q, float* __restrict__ out){
  __shared__ __align__(16) float gi[GDIM];
  int i = blockIdx.x, which = blockIdx.y;
  for (int k=threadIdx.x;k<GDIM;k+=256) gi[k]=gk[i*GDIM+k];
  __syncthreads();
  if (which==0 && threadIdx.x==0) out[i*OUTC + NA] = 0.0f;   // eps column
  int o = threadIdx.x;
  if (o < HS){
    const ushort* wr = w1 + o*3680 + which*GDIM;
    float acc=0.f;
    for (int k=0;k<GDIM;k+=4){
      ushort4 wv = *(const ushort4*)(wr+k);
      acc += bf2f(wv.x)*gi[k]+bf2f(wv.y)*gi[k+1]+bf2f(wv.z)*gi[k+2]+bf2f(wv.w)*gi[k+3];
    }
    (which? Q : P)[i*HS+o] = acc;
  }
}

// ---------------- K8b: pair MLP (decomposed layer-1), 16 antecedents/block ----------------
__global__ void k_pair(const float* __restrict__ gk, const float* __restrict__ P,
    const float* __restrict__ Q, const float* __restrict__ sk,
    const int* __restrict__ stk, const int* __restrict__ enk,
    const ushort* w1, const ushort* b1, const ushort* w2, const ushort* b2,
    const ushort* w3, const ushort* b3, const ushort* demb, float* __restrict__ out){
  __shared__ __align__(16) float gi[GDIM];
  __shared__ float Pi[152];
  __shared__ float Dall[9*HS];
  __shared__ __align__(16) float GIJ[8][GDIM];
  __shared__ float H1[8][152], H2[8][152];
  __shared__ int jcA[16], dbA[16], vA[16];
  __shared__ float skj[16];
  int i = blockIdx.x;
  int d0 = blockIdx.y*16;
  if (i - 1 - d0 < 0){
    for (int d = threadIdx.x; d < 16; d += 256) out[i*OUTC + d0 + d] = -1e9f;
    return;
  }
  for (int k=threadIdx.x;k<GDIM;k+=256) gi[k]=gk[i*GDIM+k];
  for (int o=threadIdx.x;o<HS;o+=256) Pi[o]=P[i*HS+o];
  if (threadIdx.x < 16){
    int dcol = d0 + threadIdx.x;
    int j = i - 1 - dcol;
    int jc = j<0?0:j;
    vA[threadIdx.x]=(j>=0);
    jcA[threadIdx.x]=jc;
    dbA[threadIdx.x]=binv(enk[i]-stk[jc]);
    skj[threadIdx.x]=sk[jc];
  }
  for (int tt=threadIdx.x; tt<9*HS; tt+=256){
    int o = tt/9, b = tt - (tt/9)*9;
    float acc = bf2f(b1[o]);
    const ushort* wr = w1 + o*3680 + 3660;
    const ushort* de = demb + b*FD;
    for (int k=0;k<FD;k++) acc += bf2f(wr[k])*bf2f(de[k]);
    Dall[b*HS+o] = acc;
  }
  __syncthreads();
  float ski = sk[i];
  for (int dt=0; dt<2; ++dt){
    if (i - 1 - (d0 + dt*8) < 0){
      if (threadIdx.x < 8) out[i*OUTC + d0 + dt*8 + threadIdx.x] = -1e9f;
      continue;
    }
    __syncthreads();
    for (int idx=threadIdx.x; idx<8*GDIM; idx+=256){
      int dd = idx / GDIM, k = idx - dd*GDIM;
      GIJ[dd][k] = gi[k]*gk[jcA[dt*8+dd]*GDIM + k];
    }
    __syncthreads();
    {
      int dd = threadIdx.x & 7, og = threadIdx.x >> 3;
      for (int o=og; o<HS; o+=32){
        const ushort* wr = w1 + o*3680 + 2*GDIM;
        float acc = 0.f;
        for (int k=0;k<GDIM;k+=4){
          ushort4 wv = *(const ushort4*)(wr+k);
          float4 gv = *(const float4*)&GIJ[dd][k];
          acc += bf2f(wv.x)*gv.x + bf2f(wv.y)*gv.y + bf2f(wv.z)*gv.z + bf2f(wv.w)*gv.w;
        }
        int d = dt*8+dd;
        acc += Pi[o] + Q[jcA[d]*HS+o] + Dall[dbA[d]*HS+o];
        H1[dd][o] = fmaxf(acc, 0.f);
      }
    }
    __syncthreads();
    {
      int dd = threadIdx.x & 7, og = threadIdx.x >> 3;
      for (int o=og;o<HS;o+=32){
        float acc = bf2f(b2[o]);
        const ushort* wr = w2 + o*HS;
        for (int k=0;k<HS;k+=2) acc += bf2f(wr[k])*H1[dd][k] + bf2f(wr[k+1])*H1[dd][k+1];
        H2[dd][o]=fmaxf(acc,0.f);
      }
    }
    __syncthreads();
    if (threadIdx.x < 8){
      int dd = threadIdx.x;
      float acc = bf2f(b3[0]);
      for (int k=0;k<HS;k++) acc += bf2f(w3[k])*H2[dd][k];
      int d = dt*8+dd;
      float raw = sanit(ski + skj[d] + acc);
      float v = vA[d] ? raw : -1e9f;
      out[i*OUTC + d0 + d] = v;
    }
  }
}

extern "C" void kernel_launch(void* const* d_in, const int* in_sizes, int n_in,
                              void* d_out, int out_size, void* d_ws, size_t ws_size,
                              hipStream_t stream){
  (void)in_sizes; (void)n_in; (void)out_size; (void)ws_size;
  const int*    tok   = (const int*)d_in[0];
  const int*    sst   = (const int*)d_in[1];
  const int*    sen   = (const int*)d_in[2];
  const ushort* emb   = (const ushort*)d_in[3];
  const ushort* wih_f = (const ushort*)d_in[4];
  const ushort* whh_f = (const ushort*)d_in[5];
  const ushort* b_f   = (const ushort*)d_in[6];
  const ushort* wih_b = (const ushort*)d_in[7];
  const ushort* whh_b = (const ushort*)d_in[8];
  const ushort* b_b   = (const ushort*)d_in[9];
  const ushort* aw1=(const ushort*)d_in[10]; const ushort* ab1=(const ushort*)d_in[11];
  const ushort* aw2=(const ushort*)d_in[12]; const ushort* ab2=(const ushort*)d_in[13];
  const ushort* aw3=(const ushort*)d_in[14]; const ushort* ab3=(const ushort*)d_in[15];
  const ushort* wemb=(const ushort*)d_in[16];
  const ushort* mw1=(const ushort*)d_in[17]; const ushort* mb1=(const ushort*)d_in[18];
  const ushort* mw2=(const ushort*)d_in[19]; const ushort* mb2=(const ushort*)d_in[20];
  const ushort* mw3=(const ushort*)d_in[21]; const ushort* mb3=(const ushort*)d_in[22];
  const ushort* demb=(const ushort*)d_in[23];
  const ushort* pw1=(const ushort*)d_in[24]; const ushort* pb1=(const ushort*)d_in[25];
  const ushort* pw2=(const ushort*)d_in[26]; const ushort* pb2=(const ushort*)d_in[27];
  const ushort* pw3=(const ushort*)d_in[28]; const ushort* pb3=(const ushort*)d_in[29];
  float* out = (float*)d_out;

  float* ws     = (float*)d_ws;
  float* hfw    = ws;                       // 409600
  float* hbw    = hfw + TT*HH;              // 409600
  float* attns  = hbw + TT*HH;              // 2048
  float* si     = attns + TT;               // 20480
  float* sk     = si + NS;                  // 384
  float* Pb     = sk + NK;                  // 57600
  float* Qb     = Pb + NK*HS;               // 57600
  float* gkw    = Qb + NK*HS;               // 468480
  _Float16* Xf  = (_Float16*)(gkw + NK*GDIM); // 1638400 halves
  _Float16* Xb  = Xf + TT*G4;                 // 1638400 halves
  int*   keep   = (int*)(Xb + TT*G4);       // 384
  int*   stk    = keep + NK;                // 384
  int*   enk    = stk + NK;                 // 384
  uint*  keysb  = (uint*)(enk + NK);        // 20480
  // total ~12.34 MB of d_ws

  k_xproj<<<TT/4,256,0,stream>>>(tok, emb, wih_f, b_f, wih_b, b_b, Xf, Xb);
  k_lstm<<<2,448,0,stream>>>(whh_f, whh_b, Xf, Xb, hfw, hbw);
  k_attn<<<TT,256,0,stream>>>(hfw,hbw,aw1,ab1,aw2,ab2,aw3,ab3,attns);
  k_ment<<<NS/8,256,0,stream>>>(sst,sen,tok,hfw,hbw,emb,attns,wemb,mw1,mb1,mw2,mb2,mw3,mb3,si);
  k_select<<<1,1024,0,stream>>>(si,sst,sen,keysb,keep,sk,stk,enk);
  k_gk<<<NK,256,0,stream>>>(keep,tok,hfw,hbw,emb,attns,wemb,sst,sen,gkw);
  k_pq<<<dim3(NK,2),256,0,stream>>>(gkw,pw1,Pb,Qb,out);
  k_pair<<<dim3(NK,8),256,0,stream>>>(gkw,Pb,Qb,sk,stk,enk,pw1,pb1,pw2,pb2,pw3,pb3,demb,out);
}

// Round 8
// 3645.058 us; speedup vs baseline: 1.3440x; 1.2801x over previous
//
#include <hip/hip_runtime.h>

#define TT 2048
#define EE 400
#define HH 200
#define G4 800
#define NS 20480
#define WMAX 10
#define HS 150
#define FD 20
#define GDIM 1220
#define NK 384
#define NA 128
#define OUTC 129
#define PW 616   // padded row stride in dwords (1232 f16) for f16 weight/act rows

typedef unsigned int uint;
typedef unsigned short ushort;
typedef _Float16 half4 __attribute__((ext_vector_type(4)));
typedef _Float16 h2 __attribute__((ext_vector_type(2)));

__device__ __forceinline__ float bf2f(ushort u){ return __uint_as_float(((uint)u)<<16); }
__device__ __forceinline__ int binv(int x){
  int b=0;
  b += (x>=1); b += (x>=2); b += (x>=3); b += (x>=4);
  b += (x>=8); b += (x>=16); b += (x>=32); b += (x>=64);
  return b;
}
__device__ __forceinline__ float sigf(float x){ return 1.0f/(1.0f+__expf(-x)); }
__device__ __forceinline__ float tanhf_fast(float x){
  float t = __expf(-2.0f*fabsf(x));       // in (0,1], never overflows
  float r = (1.0f - t)/(1.0f + t);
  return copysignf(r, x);
}
__device__ __forceinline__ float sanit(float x){ return (fabsf(x) <= 1e30f) ? x : 0.f; }

__device__ __forceinline__ int sdot4(int a, int b, int c){
#if __has_builtin(__builtin_amdgcn_sdot4)
  return __builtin_amdgcn_sdot4(a, b, c, false);
#else
  int r = c;
  r += (int)(signed char)(a)     * (int)(signed char)(b);
  r += (int)(signed char)(a>>8)  * (int)(signed char)(b>>8);
  r += (int)(signed char)(a>>16) * (int)(signed char)(b>>16);
  r += (int)(signed char)(a>>24) * (int)(signed char)(b>>24);
  return r;
#endif
}

// f16-pair dot: acc += a.lo*b.lo + a.hi*b.hi  (v_dot2_f32_f16)
__device__ __forceinline__ float fdot2u(uint a, uint b, float c){
#if __has_builtin(__builtin_amdgcn_fdot2)
  return __builtin_amdgcn_fdot2(__builtin_bit_cast(h2,a), __builtin_bit_cast(h2,b), c, false);
#else
  h2 x = __builtin_bit_cast(h2,a), y = __builtin_bit_cast(h2,b);
  return c + (float)x[0]*(float)y[0] + (float)x[1]*(float)y[1];
#endif
}
// pack 2 f32 -> 2 f16 in one dword (builtin returns __fp16x2 -> bit_cast, not assign)
__device__ __forceinline__ uint pk2(float a, float b){
#if __has_builtin(__builtin_amdgcn_cvt_pkrtz)
  return __builtin_bit_cast(uint, __builtin_amdgcn_cvt_pkrtz(a,b));
#else
  h2 r; r[0]=(_Float16)a; r[1]=(_Float16)b;
  return __builtin_bit_cast(uint,r);
#endif
}

// pack 4 dims (4n..4n+3) of a bf16 row into one int8 uint
__device__ __forceinline__ uint p4(const ushort* __restrict__ row, int n, float inv){
  uint r = 0;
#pragma unroll
  for (int b=0;b<4;++b){
    float w = bf2f(row[4*n+b]);
    int q = (int)rintf(w * inv);
    q = q < -127 ? -127 : (q > 127 ? 127 : q);
    r |= ((uint)(q & 0xff)) << (8*b);
  }
  return r;
}

// ---------------- K0: pre-convert hot bf16 weight rows to padded f16 ----------------
// ment layer-1 (150x1220) and pair layer-1 GIJ section (150 rows, cols
// [2*GDIM,3*GDIM)) -> f16 rows padded to PW dwords (16B-aligned rows, same
// byte count as bf16 so no extra cache pressure).
__global__ void k_prep(const ushort* __restrict__ mw1, const ushort* __restrict__ pw1,
                       uint* __restrict__ w1hm, uint* __restrict__ w1hp){
  int i = blockIdx.x*256 + threadIdx.x;
  if (i < HS*GDIM){
    int o = i / GDIM, k = i - o*GDIM;
    ((_Float16*)w1hm)[o*(2*PW) + k] = (_Float16)bf2f(mw1[i]);
    ((_Float16*)w1hp)[o*(2*PW) + k] = (_Float16)bf2f(pw1[o*3680 + 2*GDIM + k]);
  }
}

// ---------------- K2: LSTM input projections (direct emb gather, f16 out) ----------------
// X layout: [t][j*4 + gate]  so k_lstm reads all 4 gate inputs of row j with ONE 8B load.
__global__ void k_xproj(const int* __restrict__ tok, const ushort* __restrict__ emb,
                        const ushort* __restrict__ wf, const ushort* __restrict__ bfv,
                        const ushort* __restrict__ wb, const ushort* __restrict__ bbv,
                        _Float16* __restrict__ Xf, _Float16* __restrict__ Xb){
  __shared__ float x4[4][EE];
  __shared__ int tk[4];
  int t0 = blockIdx.x*4;
  if (threadIdx.x < 4) tk[threadIdx.x] = tok[t0+threadIdx.x];
  __syncthreads();
  for (int i = threadIdx.x; i < 4*EE; i += 256){
    int m = i / EE, e = i - m*EE;
    x4[m][e] = bf2f(emb[tk[m]*EE + e]);
  }
  __syncthreads();
  for (int tt = threadIdx.x; tt < 2*G4; tt += 256){
    int dir = (tt >= G4);
    int row = dir ? tt - G4 : tt;
    const ushort* wr = (dir ? wb : wf) + row*EE;
    float bias = bf2f((dir ? bbv : bfv)[row]);
    float a0=bias,a1=bias,a2=bias,a3=bias;
    for (int k=0;k<EE;k+=4){
      ushort4 wv = *(const ushort4*)(wr+k);
      float w0=bf2f(wv.x), w1=bf2f(wv.y), w2=bf2f(wv.z), w3=bf2f(wv.w);
      a0 += w0*x4[0][k] + w1*x4[0][k+1] + w2*x4[0][k+2] + w3*x4[0][k+3];
      a1 += w0*x4[1][k] + w1*x4[1][k+1] + w2*x4[1][k+2] + w3*x4[1][k+3];
      a2 += w0*x4[2][k] + w1*x4[2][k+1] + w2*x4[2][k+2] + w3*x4[2][k+3];
      a3 += w0*x4[3][k] + w1*x4[3][k+1] + w2*x4[3][k+2] + w3*x4[3][k+3];
    }
    _Float16* X = dir ? Xb : Xf;
    int g = row / HH, jj = row - g*HH;
    int col = jj*4 + g;
    X[(t0+0)*G4+col]=(_Float16)a0; X[(t0+1)*G4+col]=(_Float16)a1;
    X[(t0+2)*G4+col]=(_Float16)a2; X[(t0+3)*G4+col]=(_Float16)a3;
  }
}

// ---------------- K3: sequential bi-LSTM (block0=fwd, block1=bwd) ----------------
// Round-1 form EXACTLY (proven floor; rounds 2/3/4/6 all regressed it):
// weights in registers (int8, 25 uint4/lane), direct per-step X load,
// per-step global h store, plain __syncthreads. FROZEN.
__global__ __launch_bounds__(448, 2) void k_lstm(const ushort* __restrict__ whh_f,
                        const ushort* __restrict__ whh_b,
                        const _Float16* __restrict__ Xf, const _Float16* __restrict__ Xb,
                        float* __restrict__ hf, float* __restrict__ hb){
  __shared__ __align__(16) uint  hq[112];       // 2 x 224-B int8 h buffers (28dw halves)
  const int tid = threadIdx.x;
  const int fwd = (blockIdx.x == 0);
  const ushort* whh = fwd ? whh_f : whh_b;
  const _Float16* X = fwd ? Xf : Xb;
  float* hout = fwd ? hf : hb;
  const bool act = (tid < 400);
  const int j = tid >> 1;                // 0..199
  const int half = tid & 1;              // dim half

  uint4 wreg[25];                        // per-lane int8 weights, in registers
  float mx0=1e-20f, mx1=1e-20f, mx2=1e-20f, mx3=1e-20f;
  if (act){
    const ushort* r0 = whh + (0*HH + j)*HH + half*100;
    const ushort* r1 = whh + (1*HH + j)*HH + half*100;
    const ushort* r2 = whh + (2*HH + j)*HH + half*100;
    const ushort* r3 = whh + (3*HH + j)*HH + half*100;
    for (int d=0; d<100; d+=2){
      ushort2 v0 = *(const ushort2*)(r0+d);
      ushort2 v1 = *(const ushort2*)(r1+d);
      ushort2 v2 = *(const ushort2*)(r2+d);
      ushort2 v3 = *(const ushort2*)(r3+d);
      mx0 = fmaxf(mx0, fmaxf(fabsf(bf2f(v0.x)), fabsf(bf2f(v0.y))));
      mx1 = fmaxf(mx1, fmaxf(fabsf(bf2f(v1.x)), fabsf(bf2f(v1.y))));
      mx2 = fmaxf(mx2, fmaxf(fabsf(bf2f(v2.x)), fabsf(bf2f(v2.y))));
      mx3 = fmaxf(mx3, fmaxf(fabsf(bf2f(v3.x)), fabsf(bf2f(v3.y))));
    }
    float i0=127.f/mx0, i1=127.f/mx1, i2=127.f/mx2, i3=127.f/mx3;
#pragma unroll
    for (int n=0;n<25;++n){
      uint4 wv;
      wv.x = p4(r0,n,i0); wv.y = p4(r1,n,i1); wv.z = p4(r2,n,i2); wv.w = p4(r3,n,i3);
      wreg[n] = wv;
    }
  }
  const float sc0 = mx0*(1.f/16129.f), sc1 = mx1*(1.f/16129.f);
  const float sc2 = mx2*(1.f/16129.f), sc3 = mx3*(1.f/16129.f);
  if (tid < 112) hq[tid] = 0u;
  float c = 0.f;
  __syncthreads();
  for (int step=0; step<TT; ++step){
    int ts = fwd ? step : (TT-1-step);
    if (act){
      // all 4 gate x-inputs for row j with one 8B load
      half4 xv = *(const half4*)(X + ts*G4 + j*4);
      // h window for this half (broadcast across lanes)
      const uint* hbp = hq + (step&1)*56 + half*28;
      uint4 hA = *(const uint4*)(hbp+0);
      uint4 hB = *(const uint4*)(hbp+4);
      uint4 hC = *(const uint4*)(hbp+8);
      uint4 hD = *(const uint4*)(hbp+12);
      uint4 hE = *(const uint4*)(hbp+16);
      uint4 hF = *(const uint4*)(hbp+20);
      uint  hG = hbp[24];
      int d0=0,d1=0,d2=0,d3=0;
#define DD(n,hu) { uint4 wv = wreg[n]; \
  d0=sdot4((int)wv.x,(int)(hu),d0); d1=sdot4((int)wv.y,(int)(hu),d1); \
  d2=sdot4((int)wv.z,(int)(hu),d2); d3=sdot4((int)wv.w,(int)(hu),d3); }
      DD(0,hA.x) DD(1,hA.y) DD(2,hA.z) DD(3,hA.w)
      DD(4,hB.x) DD(5,hB.y) DD(6,hB.z) DD(7,hB.w)
      DD(8,hC.x) DD(9,hC.y) DD(10,hC.z) DD(11,hC.w)
      DD(12,hD.x) DD(13,hD.y) DD(14,hD.z) DD(15,hD.w)
      DD(16,hE.x) DD(17,hE.y) DD(18,hE.z) DD(19,hE.w)
      DD(20,hF.x) DD(21,hF.y) DD(22,hF.z) DD(23,hF.w)
      DD(24,hG)
#undef DD
      float a0 = (float)d0*sc0 + (float)xv.x*0.5f;
      float a1 = (float)d1*sc1 + (float)xv.y*0.5f;
      float a2 = (float)d2*sc2 + (float)xv.z*0.5f;
      float a3 = (float)d3*sc3 + (float)xv.w*0.5f;
      // sum the two dim-halves (x added half in each lane -> once total)
      a0 += __shfl_xor(a0, 1, 64);
      a1 += __shfl_xor(a1, 1, 64);
      a2 += __shfl_xor(a2, 1, 64);
      a3 += __shfl_xor(a3, 1, 64);
      // gates: 0=i, 1=f, 2=g, 3=o
      c = sigf(a1)*c + sigf(a0)*tanhf_fast(a2);
      float h = sigf(a3)*tanhf_fast(c);
      if (half == 0){
        hout[ts*HH + j] = h;
        int q = (int)rintf(h*127.f);
        q = q<-127?-127:(q>127?127:q);
        int bufbyte = ((step+1)&1)*224 + (j<100 ? j : 112 + (j-100));
        ((unsigned char*)hq)[bufbyte] = (unsigned char)(q & 0xff);
      }
    }
    __syncthreads();
  }
}

// ---------------- K4: token attention-score MLP ----------------
__global__ void k_attn(const float* __restrict__ hf, const float* __restrict__ hb,
    const ushort* w1, const ushort* b1, const ushort* w2, const ushort* b2,
    const ushort* w3, const ushort* b3, float* __restrict__ attns){
  __shared__ float s[2*HH];
  __shared__ float h1[HS], h2v[HS];
  int t = blockIdx.x;
  for (int k=threadIdx.x;k<2*HH;k+=256)
    s[k] = (k<HH) ? hf[t*HH+k] : hb[t*HH + (k-HH)];
  __syncthreads();
  int o = threadIdx.x;
  if (o < HS){
    float acc = bf2f(b1[o]);
    const ushort* wr = w1 + o*2*HH;
    for (int k=0;k<2*HH;k+=4){
      ushort4 wv = *(const ushort4*)(wr+k);
      acc += bf2f(wv.x)*s[k] + bf2f(wv.y)*s[k+1] + bf2f(wv.z)*s[k+2] + bf2f(wv.w)*s[k+3];
    }
    h1[o] = fmaxf(acc, 0.f);
  }
  __syncthreads();
  if (o < HS){
    float acc = bf2f(b2[o]);
    const ushort* wr = w2 + o*HS;
    for (int k=0;k<HS;k+=2) acc += bf2f(wr[k])*h1[k] + bf2f(wr[k+1])*h1[k+1];
    h2v[o] = fmaxf(acc, 0.f);
  }
  __syncthreads();
  if (o == 0){
    float acc = bf2f(b3[0]);
    for (int k=0;k<HS;k++) acc += bf2f(w3[k])*h2v[k];
    attns[t] = acc;
  }
}

// ---------------- K5: span features + mention MLP (8 spans/block) ----------------
// G stored packed f16 in LDS (halves LDS: ~30KB/block -> higher occupancy);
// layer-1 uses v_dot2_f32_f16 with f16 weights (same bytes as bf16, ~3x fewer
// inner-loop instructions than shift+fma on bf16).
__global__ void k_ment(const int* __restrict__ sstart, const int* __restrict__ send,
    const int* __restrict__ tok,
    const float* __restrict__ hf, const float* __restrict__ hb,
    const ushort* __restrict__ emb, const float* __restrict__ attns,
    const ushort* wemb,
    const uint* __restrict__ w1h, const ushort* b1, const ushort* w2, const ushort* b2,
    const ushort* w3, const ushort* b3, float* __restrict__ si){
  __shared__ __align__(16) uint Gh[8*PW];       // 8 spans x 1232 f16 (pad 12)
  __shared__ float H1[8][152], H2[8][152];
  __shared__ float aw[8][WMAX];
  __shared__ int stok[8][WMAX];
  __shared__ int sst[8], sen[8], sbin[8];
  int s0 = blockIdx.x*8;
  if (threadIdx.x < 8){
    int sp = threadIdx.x;
    int st = sstart[s0+sp], en = send[s0+sp];
    sst[sp]=st; sen[sp]=en;
    int width = en - st + 1;
    sbin[sp] = binv(width);
    float lg[WMAX]; float mx = -1e30f;
    for (int wt=0; wt<WMAX; ++wt){
      int idx = st + wt; if (idx > TT-1) idx = TT-1;
      float l = (wt < width) ? attns[idx] : -1e9f;
      lg[wt] = l; mx = fmaxf(mx, l);
    }
    float den = 0.f;
    for (int wt=0; wt<WMAX; ++wt){ lg[wt] = __expf(lg[wt]-mx); den += lg[wt]; }
    float inv = 1.f/den;
    for (int wt=0; wt<WMAX; ++wt) aw[sp][wt] = lg[wt]*inv;
  }
  if (threadIdx.x < 8*WMAX){
    int sp = threadIdx.x / WMAX, wt = threadIdx.x - sp*WMAX;
    int idx = sstart[s0+sp] + wt; if (idx > TT-1) idx = TT-1;
    stok[sp][wt] = tok[idx];
  }
  __syncthreads();
  for (int i = threadIdx.x; i < 8*GDIM; i += 256){
    int sp = i / GDIM, f = i - sp*GDIM;
    int st = sst[sp], en = sen[sp];
    float v;
    if (f < HH) v = hf[st*HH + f];
    else if (f < 2*HH) v = hb[st*HH + (f-HH)];
    else if (f < 3*HH) v = hf[en*HH + (f-2*HH)];
    else if (f < 4*HH) v = hb[en*HH + (f-3*HH)];
    else if (f < 4*HH + EE){
      int e = f - 4*HH;
      float acc = 0.f;
      for (int wt=0; wt<WMAX; ++wt)
        acc += aw[sp][wt] * bf2f(emb[stok[sp][wt]*EE + e]);
      v = acc;
    } else {
      v = bf2f(wemb[sbin[sp]*FD + (f - (4*HH+EE))]);
    }
    ((_Float16*)Gh)[sp*(2*PW) + f] = (_Float16)v;
  }
  __syncthreads();
  for (int tt = threadIdx.x; tt < 8*HS; tt += 256){
    int sp = tt & 7, o = tt >> 3;
    const uint* wr = w1h + o*PW;
    const uint* gr = Gh + sp*PW;
    float a0=0.f,a1=0.f,a2=0.f,a3=0.f;
    for (int k=0;k<152;++k){
      uint4 wv = *(const uint4*)(wr + k*4);
      uint4 gv = *(const uint4*)(gr + k*4);
      a0 = fdot2u(wv.x, gv.x, a0);
      a1 = fdot2u(wv.y, gv.y, a1);
      a2 = fdot2u(wv.z, gv.z, a2);
      a3 = fdot2u(wv.w, gv.w, a3);
    }
    // tail: dwords 608,609 (f16 elems 1216..1219)
    a0 = fdot2u(wr[608], gr[608], a0);
    a1 = fdot2u(wr[609], gr[609], a1);
    float acc = bf2f(b1[o]) + (a0+a2) + (a1+a3);
    H1[sp][o] = fmaxf(acc, 0.f);
  }
  __syncthreads();
  for (int tt = threadIdx.x; tt < 8*HS; tt += 256){
    int sp = tt & 7, o = tt >> 3;
    float acc = bf2f(b2[o]);
    const ushort* wr = w2 + o*HS;
    for (int k=0;k<HS;k+=2) acc += bf2f(wr[k])*H1[sp][k] + bf2f(wr[k+1])*H1[sp][k+1];
    H2[sp][o] = fmaxf(acc, 0.f);
  }
  __syncthreads();
  if (threadIdx.x < 8){
    int sp = threadIdx.x;
    float acc = bf2f(b3[0]);
    for (int k=0;k<HS;k++) acc += bf2f(w3[k])*H2[sp][k];
    si[s0+sp] = sanit(acc);
  }
}

// ---------------- K6: top-384 + index-ordered compaction (single block) ----------------
__global__ __launch_bounds__(1024) void k_select(const float* __restrict__ si,
    const int* __restrict__ sstart, const int* __restrict__ send,
    uint* __restrict__ keysb, int* __restrict__ keep, float* __restrict__ sk,
    int* __restrict__ stk, int* __restrict__ enk){
  __shared__ uint hist[256];
  __shared__ uint sG[1024], sE[1024];
  __shared__ uint bc[2];
  int tid = threadIdx.x;
  if (tid < NK){ keep[tid]=0; sk[tid]=0.f; stk[tid]=0; enk[tid]=0; }
  for (int i=tid;i<NS;i+=1024){
    uint u = __float_as_uint(si[i]);
    uint m = (u & 0x80000000u) ? ~u : (u | 0x80000000u);  // order-preserving map
    keysb[i] = m;
  }
  __syncthreads();
  uint prefix=0, mask=0; int K = NK;
  for (int p=3;p>=0;--p){
    int sh = p*8;
    if (tid<256) hist[tid]=0;
    __syncthreads();
    for (int i=tid;i<NS;i+=1024){
      uint m = keysb[i];
      if ((m & mask) == prefix) atomicAdd(&hist[(m>>sh)&255u], 1u);
    }
    __syncthreads();
    if (tid==0){
      uint cum=0;
      bc[0]=0; bc[1]=(uint)K;
      for (int b=255; b>=0; --b){
        uint c = hist[b];
        if ((uint)K <= cum + c){ bc[0]=(uint)b; bc[1]=(uint)(K - (int)cum); break; }
        cum += c;
      }
    }
    __syncthreads();
    prefix |= bc[0] << sh;
    mask |= 0xFFu << sh;
    K = (int)bc[1];
    __syncthreads();
  }
  const uint V = prefix; const uint Eneed = (uint)K;
  int base = tid*20;
  uint cg=0, ce=0;
  for (int r=0;r<20;++r){
    uint m = keysb[base+r];
    cg += (m > V); ce += (m == V);
  }
  sG[tid]=cg; sE[tid]=ce;
  __syncthreads();
  for (int off=1; off<1024; off<<=1){
    uint aG=0,aE=0;
    if (tid>=off){ aG=sG[tid-off]; aE=sE[tid-off]; }
    __syncthreads();
    if (tid>=off){ sG[tid]+=aG; sE[tid]+=aE; }
    __syncthreads();
  }
  uint gbase = sG[tid]-cg, ebase = sE[tid]-ce;
  uint gseen=0, eseen=0;
  for (int r=0;r<20;++r){
    int i = base+r;
    uint m = keysb[i];
    if (m > V){
      uint eb = ebase+eseen; if (eb > Eneed) eb = Eneed;
      uint pos = gbase + gseen + eb;
      if (pos < NK){ keep[pos]=i; sk[pos]=si[i]; stk[pos]=sstart[i]; enk[pos]=send[i]; }
      gseen++;
    } else if (m == V){
      uint eb = ebase + eseen;
      if (eb < Eneed){
        uint pos = gbase + gseen + eb;
        if (pos < NK){ keep[pos]=i; sk[pos]=si[i]; stk[pos]=sstart[i]; enk[pos]=send[i]; }
      }
      eseen++;
    }
  }
}

// ---------------- K7: rebuild g for kept spans ----------------
__global__ void k_gk(const int* __restrict__ keep, const int* __restrict__ tok,
    const float* __restrict__ hf, const float* __restrict__ hb,
    const ushort* __restrict__ emb, const float* __restrict__ attns,
    const ushort* wemb, const int* __restrict__ sstart, const int* __restrict__ send,
    float* __restrict__ gk){
  __shared__ float aw[WMAX];
  __shared__ int stok1[WMAX];
  __shared__ int sstv, senv, sbinv;
  int b = blockIdx.x;
  if (threadIdx.x == 0){
    int s = keep[b]; s = s < 0 ? 0 : (s >= NS ? NS-1 : s);
    int st = sstart[s], en = send[s];
    sstv=st; senv=en;
    int width = en-st+1;
    sbinv = binv(width);
    float lg[WMAX]; float mx=-1e30f;
    for (int wt=0;wt<WMAX;++wt){
      int idx = st+wt; if (idx>TT-1) idx=TT-1;
      float l = (wt<width)? attns[idx] : -1e9f;
      lg[wt]=l; mx=fmaxf(mx,l);
    }
    float den=0.f;
    for (int wt=0;wt<WMAX;++wt){ lg[wt]=__expf(lg[wt]-mx); den+=lg[wt]; }
    float inv=1.f/den;
    for (int wt=0;wt<WMAX;++wt) aw[wt]=lg[wt]*inv;
  }
  if (threadIdx.x < WMAX){
    int s = keep[b]; s = s < 0 ? 0 : (s >= NS ? NS-1 : s);
    int idx = sstart[s] + threadIdx.x; if (idx>TT-1) idx=TT-1;
    stok1[threadIdx.x] = tok[idx];
  }
  __syncthreads();
  int st=sstv, en=senv;
  for (int f=threadIdx.x; f<GDIM; f+=256){
    float v;
    if (f < HH) v = hf[st*HH + f];
    else if (f < 2*HH) v = hb[st*HH + (f-HH)];
    else if (f < 3*HH) v = hf[en*HH + (f-2*HH)];
    else if (f < 4*HH) v = hb[en*HH + (f-3*HH)];
    else if (f < 4*HH + EE){
      int e = f - 4*HH;
      float acc = 0.f;
      for (int wt=0; wt<WMAX; ++wt)
        acc += aw[wt] * bf2f(emb[stok1[wt]*EE + e]);
      v = acc;
    } else {
      v = bf2f(wemb[sbinv*FD + (f - (4*HH+EE))]);
    }
    gk[b*GDIM + f] = v;
  }
}

// ---------------- K8a: P[i]=w1a.gk[i], Q[i]=w1b.gk[i]; also eps column ----------------
__global__ void k_pq(const float* __restrict__ gk, const ushort* __restrict__ w1,
                     float* __restrict__ P, float* __restrict__ Q, float* __restrict__ out){
  __shared__ __align__(16) float gi[GDIM];
  int i = blockIdx.x, which = blockIdx.y;
  for (int k=threadIdx.x;k<GDIM;k+=256) gi[k]=gk[i*GDIM+k];
  __syncthreads();
  if (which==0 && threadIdx.x==0) out[i*OUTC + NA] = 0.0f;   // eps column
  int o = threadIdx.x;
  if (o < HS){
    const ushort* wr = w1 + o*3680 + which*GDIM;
    float acc=0.f;
    for (int k=0;k<GDIM;k+=4){
      ushort4 wv = *(const ushort4*)(wr+k);
      acc += bf2f(wv.x)*gi[k]+bf2f(wv.y)*gi[k+1]+bf2f(wv.z)*gi[k+2]+bf2f(wv.w)*gi[k+3];
    }
    (which? Q : P)[i*HS+o] = acc;
  }
}

// ---------------- K8b: pair MLP (decomposed layer-1), 16 antecedents/block ----------------
// GIJ packed f16 in LDS; layer-1 via v_dot2_f32_f16 with preconverted f16
// weights. LDS ~41KB (was ~79KB) -> 3 blocks/CU.
__global__ void k_pair(const float* __restrict__ gk, const float* __restrict__ P,
    const float* __restrict__ Q, const float* __restrict__ sk,
    const int* __restrict__ stk, const int* __restrict__ enk,
    const uint* __restrict__ w1h, const ushort* w1, const ushort* b1,
    const ushort* w2, const ushort* b2,
    const ushort* w3, const ushort* b3, const ushort* demb, float* __restrict__ out){
  __shared__ __align__(16) float gi[GDIM];
  __shared__ float Pi[152];
  __shared__ float Dall[9*HS];
  __shared__ __align__(16) uint GIJp[8*PW];     // 8 dd x 1232 f16
  __shared__ float H1[8][152], H2[8][152];
  __shared__ int jcA[16], dbA[16], vA[16];
  __shared__ float skj[16];
  int i = blockIdx.x;
  int d0 = blockIdx.y*16;
  if (i - 1 - d0 < 0){
    for (int d = threadIdx.x; d < 16; d += 256) out[i*OUTC + d0 + d] = -1e9f;
    return;
  }
  for (int k=threadIdx.x;k<GDIM;k+=256) gi[k]=gk[i*GDIM+k];
  for (int o=threadIdx.x;o<HS;o+=256) Pi[o]=P[i*HS+o];
  if (threadIdx.x < 16){
    int dcol = d0 + threadIdx.x;
    int j = i - 1 - dcol;
    int jc = j<0?0:j;
    vA[threadIdx.x]=(j>=0);
    jcA[threadIdx.x]=jc;
    dbA[threadIdx.x]=binv(enk[i]-stk[jc]);
    skj[threadIdx.x]=sk[jc];
  }
  for (int tt=threadIdx.x; tt<9*HS; tt+=256){
    int o = tt/9, b = tt - (tt/9)*9;
    float acc = bf2f(b1[o]);
    const ushort* wr = w1 + o*3680 + 3660;
    const ushort* de = demb + b*FD;
    for (int k=0;k<FD;k++) acc += bf2f(wr[k])*bf2f(de[k]);
    Dall[b*HS+o] = acc;
  }
  __syncthreads();
  float ski = sk[i];
  for (int dt=0; dt<2; ++dt){
    if (i - 1 - (d0 + dt*8) < 0){
      if (threadIdx.x < 8) out[i*OUTC + d0 + dt*8 + threadIdx.x] = -1e9f;
      continue;
    }
    __syncthreads();
    for (int idx=threadIdx.x; idx<8*610; idx+=256){
      int dd = idx / 610, kp = idx - dd*610;
      const float2 gj = *(const float2*)&gk[jcA[dt*8+dd]*GDIM + 2*kp];
      const float2 gv = *(const float2*)&gi[2*kp];
      GIJp[dd*PW + kp] = pk2(gv.x*gj.x, gv.y*gj.y);
    }
    __syncthreads();
    {
      int dd = threadIdx.x & 7, og = threadIdx.x >> 3;
      for (int o=og; o<HS; o+=32){
        const uint* wr = w1h + o*PW;
        const uint* gr = GIJp + dd*PW;
        float a0=0.f,a1=0.f,a2=0.f,a3=0.f;
        for (int k=0;k<152;++k){
          uint4 wv = *(const uint4*)(wr + k*4);
          uint4 gv = *(const uint4*)(gr + k*4);
          a0 = fdot2u(wv.x, gv.x, a0);
          a1 = fdot2u(wv.y, gv.y, a1);
          a2 = fdot2u(wv.z, gv.z, a2);
          a3 = fdot2u(wv.w, gv.w, a3);
        }
        a0 = fdot2u(wr[608], gr[608], a0);
        a1 = fdot2u(wr[609], gr[609], a1);
        int d = dt*8+dd;
        float acc = (a0+a2) + (a1+a3);
        acc += Pi[o] + Q[jcA[d]*HS+o] + Dall[dbA[d]*HS+o];
        H1[dd][o] = fmaxf(acc, 0.f);
      }
    }
    __syncthreads();
    {
      int dd = threadIdx.x & 7, og = threadIdx.x >> 3;
      for (int o=og;o<HS;o+=32){
        float acc = bf2f(b2[o]);
        const ushort* wr = w2 + o*HS;
        for (int k=0;k<HS;k+=2) acc += bf2f(wr[k])*H1[dd][k] + bf2f(wr[k+1])*H1[dd][k+1];
        H2[dd][o]=fmaxf(acc,0.f);
      }
    }
    __syncthreads();
    if (threadIdx.x < 8){
      int dd = threadIdx.x;
      float acc = bf2f(b3[0]);
      for (int k=0;k<HS;k++) acc += bf2f(w3[k])*H2[dd][k];
      int d = dt*8+dd;
      float raw = sanit(ski + skj[d] + acc);
      float v = vA[d] ? raw : -1e9f;
      out[i*OUTC + d0 + d] = v;
    }
  }
}

extern "C" void kernel_launch(void* const* d_in, const int* in_sizes, int n_in,
                              void* d_out, int out_size, void* d_ws, size_t ws_size,
                              hipStream_t stream){
  (void)in_sizes; (void)n_in; (void)out_size; (void)ws_size;
  const int*    tok   = (const int*)d_in[0];
  const int*    sst   = (const int*)d_in[1];
  const int*    sen   = (const int*)d_in[2];
  const ushort* emb   = (const ushort*)d_in[3];
  const ushort* wih_f = (const ushort*)d_in[4];
  const ushort* whh_f = (const ushort*)d_in[5];
  const ushort* b_f   = (const ushort*)d_in[6];
  const ushort* wih_b = (const ushort*)d_in[7];
  const ushort* whh_b = (const ushort*)d_in[8];
  const ushort* b_b   = (const ushort*)d_in[9];
  const ushort* aw1=(const ushort*)d_in[10]; const ushort* ab1=(const ushort*)d_in[11];
  const ushort* aw2=(const ushort*)d_in[12]; const ushort* ab2=(const ushort*)d_in[13];
  const ushort* aw3=(const ushort*)d_in[14]; const ushort* ab3=(const ushort*)d_in[15];
  const ushort* wemb=(const ushort*)d_in[16];
  const ushort* mw1=(const ushort*)d_in[17]; const ushort* mb1=(const ushort*)d_in[18];
  const ushort* mw2=(const ushort*)d_in[19]; const ushort* mb2=(const ushort*)d_in[20];
  const ushort* mw3=(const ushort*)d_in[21]; const ushort* mb3=(const ushort*)d_in[22];
  const ushort* demb=(const ushort*)d_in[23];
  const ushort* pw1=(const ushort*)d_in[24]; const ushort* pb1=(const ushort*)d_in[25];
  const ushort* pw2=(const ushort*)d_in[26]; const ushort* pb2=(const ushort*)d_in[27];
  const ushort* pw3=(const ushort*)d_in[28]; const ushort* pb3=(const ushort*)d_in[29];
  float* out = (float*)d_out;

  float* ws     = (float*)d_ws;
  float* hfw    = ws;                       // 409600
  float* hbw    = hfw + TT*HH;              // 409600
  float* attns  = hbw + TT*HH;              // 2048
  float* si     = attns + TT;               // 20480
  float* sk     = si + NS;                  // 384
  float* Pb     = sk + NK;                  // 57600
  float* Qb     = Pb + NK*HS;               // 57600
  float* gkw    = Qb + NK*HS;               // 468480
  _Float16* Xf  = (_Float16*)(gkw + NK*GDIM); // 1638400 halves
  _Float16* Xb  = Xf + TT*G4;                 // 1638400 halves
  int*   keep   = (int*)(Xb + TT*G4);       // 384
  int*   stk    = keep + NK;                // 384
  int*   enk    = stk + NK;                 // 384
  uint*  keysb  = (uint*)(enk + NK);        // 20480
  uint*  w1hm   = keysb + NS;               // 150 x PW dwords (f16 ment layer-1)
  uint*  w1hp   = w1hm + HS*PW;             // 150 x PW dwords (f16 pair layer-1 GIJ)
  // total ~13.1 MB of d_ws

  k_prep<<<(HS*GDIM+255)/256,256,0,stream>>>(mw1, pw1, w1hm, w1hp);
  k_xproj<<<TT/4,256,0,stream>>>(tok, emb, wih_f, b_f, wih_b, b_b, Xf, Xb);
  k_lstm<<<2,448,0,stream>>>(whh_f, whh_b, Xf, Xb, hfw, hbw);
  k_attn<<<TT,256,0,stream>>>(hfw,hbw,aw1,ab1,aw2,ab2,aw3,ab3,attns);
  k_ment<<<NS/8,256,0,stream>>>(sst,sen,tok,hfw,hbw,emb,attns,wemb,w1hm,mb1,mw2,mb2,mw3,mb3,si);
  k_select<<<1,1024,0,stream>>>(si,sst,sen,keysb,keep,sk,stk,enk);
  k_gk<<<NK,256,0,stream>>>(keep,tok,hfw,hbw,emb,attns,wemb,sst,sen,gkw);
  k_pq<<<dim3(NK,2),256,0,stream>>>(gkw,pw1,Pb,Qb,out);
  k_pair<<<dim3(NK,8),256,0,stream>>>(gkw,Pb,Qb,sk,stk,enk,w1hp,pw1,pb1,pw2,pb2,pw3,pb3,demb,out);
}

// Round 9
// 3544.383 us; speedup vs baseline: 1.3822x; 1.0284x over previous
//
#include <hip/hip_runtime.h>

#define TT 2048
#define EE 400
#define HH 200
#define G4 800
#define NS 20480
#define WMAX 10
#define HS 150
#define FD 20
#define GDIM 1220
#define NK 384
#define NA 128
#define OUTC 129
#define PW 616   // padded row stride in dwords (1232 f16) for f16 weight/act rows

typedef unsigned int uint;
typedef unsigned short ushort;
typedef _Float16 half4 __attribute__((ext_vector_type(4)));
typedef _Float16 h2 __attribute__((ext_vector_type(2)));

__device__ __forceinline__ float bf2f(ushort u){ return __uint_as_float(((uint)u)<<16); }
__device__ __forceinline__ int binv(int x){
  int b=0;
  b += (x>=1); b += (x>=2); b += (x>=3); b += (x>=4);
  b += (x>=8); b += (x>=16); b += (x>=32); b += (x>=64);
  return b;
}
__device__ __forceinline__ float sigf(float x){ return 1.0f/(1.0f+__expf(-x)); }
__device__ __forceinline__ float tanhf_fast(float x){
  float t = __expf(-2.0f*fabsf(x));       // in (0,1], never overflows
  float r = (1.0f - t)/(1.0f + t);
  return copysignf(r, x);
}
__device__ __forceinline__ float sanit(float x){ return (fabsf(x) <= 1e30f) ? x : 0.f; }

__device__ __forceinline__ int sdot4(int a, int b, int c){
#if __has_builtin(__builtin_amdgcn_sdot4)
  return __builtin_amdgcn_sdot4(a, b, c, false);
#else
  int r = c;
  r += (int)(signed char)(a)     * (int)(signed char)(b);
  r += (int)(signed char)(a>>8)  * (int)(signed char)(b>>8);
  r += (int)(signed char)(a>>16) * (int)(signed char)(b>>16);
  r += (int)(signed char)(a>>24) * (int)(signed char)(b>>24);
  return r;
#endif
}

// f16-pair dot: acc += a.lo*b.lo + a.hi*b.hi  (v_dot2_f32_f16)
__device__ __forceinline__ float fdot2u(uint a, uint b, float c){
#if __has_builtin(__builtin_amdgcn_fdot2)
  return __builtin_amdgcn_fdot2(__builtin_bit_cast(h2,a), __builtin_bit_cast(h2,b), c, false);
#else
  h2 x = __builtin_bit_cast(h2,a), y = __builtin_bit_cast(h2,b);
  return c + (float)x[0]*(float)y[0] + (float)x[1]*(float)y[1];
#endif
}
// pack 2 f32 -> 2 f16 in one dword (builtin returns __fp16x2 -> bit_cast, not assign)
__device__ __forceinline__ uint pk2(float a, float b){
#if __has_builtin(__builtin_amdgcn_cvt_pkrtz)
  return __builtin_bit_cast(uint, __builtin_amdgcn_cvt_pkrtz(a,b));
#else
  h2 r; r[0]=(_Float16)a; r[1]=(_Float16)b;
  return __builtin_bit_cast(uint,r);
#endif
}

// pack 4 dims (4n..4n+3) of a bf16 row into one int8 uint
__device__ __forceinline__ uint p4(const ushort* __restrict__ row, int n, float inv){
  uint r = 0;
#pragma unroll
  for (int b=0;b<4;++b){
    float w = bf2f(row[4*n+b]);
    int q = (int)rintf(w * inv);
    q = q < -127 ? -127 : (q > 127 ? 127 : q);
    r |= ((uint)(q & 0xff)) << (8*b);
  }
  return r;
}

// ---------------- K0: pre-convert hot bf16 weight rows to padded f16 ----------------
// ment layer-1 (150x1220) and pair layer-1 GIJ section (150 rows, cols
// [2*GDIM,3*GDIM)) -> f16 rows padded to PW dwords. Buffers allocated with
// 160 row slots so the register-tiled consumers can run branch-free over
// o0+{0,32,64,96,128} (rows 150..159 are read-and-discarded).
__global__ void k_prep(const ushort* __restrict__ mw1, const ushort* __restrict__ pw1,
                       uint* __restrict__ w1hm, uint* __restrict__ w1hp){
  int i = blockIdx.x*256 + threadIdx.x;
  if (i < HS*GDIM){
    int o = i / GDIM, k = i - o*GDIM;
    ((_Float16*)w1hm)[o*(2*PW) + k] = (_Float16)bf2f(mw1[i]);
    ((_Float16*)w1hp)[o*(2*PW) + k] = (_Float16)bf2f(pw1[o*3680 + 2*GDIM + k]);
  }
}

// ---------------- K2: LSTM input projections (direct emb gather, f16 out) ----------------
// X layout: [t][j*4 + gate]  so k_lstm reads all 4 gate inputs of row j with ONE 8B load.
__global__ void k_xproj(const int* __restrict__ tok, const ushort* __restrict__ emb,
                        const ushort* __restrict__ wf, const ushort* __restrict__ bfv,
                        const ushort* __restrict__ wb, const ushort* __restrict__ bbv,
                        _Float16* __restrict__ Xf, _Float16* __restrict__ Xb){
  __shared__ float x4[4][EE];
  __shared__ int tk[4];
  int t0 = blockIdx.x*4;
  if (threadIdx.x < 4) tk[threadIdx.x] = tok[t0+threadIdx.x];
  __syncthreads();
  for (int i = threadIdx.x; i < 4*EE; i += 256){
    int m = i / EE, e = i - m*EE;
    x4[m][e] = bf2f(emb[tk[m]*EE + e]);
  }
  __syncthreads();
  for (int tt = threadIdx.x; tt < 2*G4; tt += 256){
    int dir = (tt >= G4);
    int row = dir ? tt - G4 : tt;
    const ushort* wr = (dir ? wb : wf) + row*EE;
    float bias = bf2f((dir ? bbv : bfv)[row]);
    float a0=bias,a1=bias,a2=bias,a3=bias;
    for (int k=0;k<EE;k+=4){
      ushort4 wv = *(const ushort4*)(wr+k);
      float w0=bf2f(wv.x), w1=bf2f(wv.y), w2=bf2f(wv.z), w3=bf2f(wv.w);
      a0 += w0*x4[0][k] + w1*x4[0][k+1] + w2*x4[0][k+2] + w3*x4[0][k+3];
      a1 += w0*x4[1][k] + w1*x4[1][k+1] + w2*x4[1][k+2] + w3*x4[1][k+3];
      a2 += w0*x4[2][k] + w1*x4[2][k+1] + w2*x4[2][k+2] + w3*x4[2][k+3];
      a3 += w0*x4[3][k] + w1*x4[3][k+1] + w2*x4[3][k+2] + w3*x4[3][k+3];
    }
    _Float16* X = dir ? Xb : Xf;
    int g = row / HH, jj = row - g*HH;
    int col = jj*4 + g;
    X[(t0+0)*G4+col]=(_Float16)a0; X[(t0+1)*G4+col]=(_Float16)a1;
    X[(t0+2)*G4+col]=(_Float16)a2; X[(t0+3)*G4+col]=(_Float16)a3;
  }
}

// ---------------- K3: sequential bi-LSTM (block0=fwd, block1=bwd) ----------------
// Round-1 form EXACTLY (proven floor; rounds 2/3/4/6 all regressed it):
// weights in registers (int8, 25 uint4/lane), direct per-step X load,
// per-step global h store, plain __syncthreads. FROZEN.
__global__ __launch_bounds__(448, 2) void k_lstm(const ushort* __restrict__ whh_f,
                        const ushort* __restrict__ whh_b,
                        const _Float16* __restrict__ Xf, const _Float16* __restrict__ Xb,
                        float* __restrict__ hf, float* __restrict__ hb){
  __shared__ __align__(16) uint  hq[112];       // 2 x 224-B int8 h buffers (28dw halves)
  const int tid = threadIdx.x;
  const int fwd = (blockIdx.x == 0);
  const ushort* whh = fwd ? whh_f : whh_b;
  const _Float16* X = fwd ? Xf : Xb;
  float* hout = fwd ? hf : hb;
  const bool act = (tid < 400);
  const int j = tid >> 1;                // 0..199
  const int half = tid & 1;              // dim half

  uint4 wreg[25];                        // per-lane int8 weights, in registers
  float mx0=1e-20f, mx1=1e-20f, mx2=1e-20f, mx3=1e-20f;
  if (act){
    const ushort* r0 = whh + (0*HH + j)*HH + half*100;
    const ushort* r1 = whh + (1*HH + j)*HH + half*100;
    const ushort* r2 = whh + (2*HH + j)*HH + half*100;
    const ushort* r3 = whh + (3*HH + j)*HH + half*100;
    for (int d=0; d<100; d+=2){
      ushort2 v0 = *(const ushort2*)(r0+d);
      ushort2 v1 = *(const ushort2*)(r1+d);
      ushort2 v2 = *(const ushort2*)(r2+d);
      ushort2 v3 = *(const ushort2*)(r3+d);
      mx0 = fmaxf(mx0, fmaxf(fabsf(bf2f(v0.x)), fabsf(bf2f(v0.y))));
      mx1 = fmaxf(mx1, fmaxf(fabsf(bf2f(v1.x)), fabsf(bf2f(v1.y))));
      mx2 = fmaxf(mx2, fmaxf(fabsf(bf2f(v2.x)), fabsf(bf2f(v2.y))));
      mx3 = fmaxf(mx3, fmaxf(fabsf(bf2f(v3.x)), fabsf(bf2f(v3.y))));
    }
    float i0=127.f/mx0, i1=127.f/mx1, i2=127.f/mx2, i3=127.f/mx3;
#pragma unroll
    for (int n=0;n<25;++n){
      uint4 wv;
      wv.x = p4(r0,n,i0); wv.y = p4(r1,n,i1); wv.z = p4(r2,n,i2); wv.w = p4(r3,n,i3);
      wreg[n] = wv;
    }
  }
  const float sc0 = mx0*(1.f/16129.f), sc1 = mx1*(1.f/16129.f);
  const float sc2 = mx2*(1.f/16129.f), sc3 = mx3*(1.f/16129.f);
  if (tid < 112) hq[tid] = 0u;
  float c = 0.f;
  __syncthreads();
  for (int step=0; step<TT; ++step){
    int ts = fwd ? step : (TT-1-step);
    if (act){
      // all 4 gate x-inputs for row j with one 8B load
      half4 xv = *(const half4*)(X + ts*G4 + j*4);
      // h window for this half (broadcast across lanes)
      const uint* hbp = hq + (step&1)*56 + half*28;
      uint4 hA = *(const uint4*)(hbp+0);
      uint4 hB = *(const uint4*)(hbp+4);
      uint4 hC = *(const uint4*)(hbp+8);
      uint4 hD = *(const uint4*)(hbp+12);
      uint4 hE = *(const uint4*)(hbp+16);
      uint4 hF = *(const uint4*)(hbp+20);
      uint  hG = hbp[24];
      int d0=0,d1=0,d2=0,d3=0;
#define DD(n,hu) { uint4 wv = wreg[n]; \
  d0=sdot4((int)wv.x,(int)(hu),d0); d1=sdot4((int)wv.y,(int)(hu),d1); \
  d2=sdot4((int)wv.z,(int)(hu),d2); d3=sdot4((int)wv.w,(int)(hu),d3); }
      DD(0,hA.x) DD(1,hA.y) DD(2,hA.z) DD(3,hA.w)
      DD(4,hB.x) DD(5,hB.y) DD(6,hB.z) DD(7,hB.w)
      DD(8,hC.x) DD(9,hC.y) DD(10,hC.z) DD(11,hC.w)
      DD(12,hD.x) DD(13,hD.y) DD(14,hD.z) DD(15,hD.w)
      DD(16,hE.x) DD(17,hE.y) DD(18,hE.z) DD(19,hE.w)
      DD(20,hF.x) DD(21,hF.y) DD(22,hF.z) DD(23,hF.w)
      DD(24,hG)
#undef DD
      float a0 = (float)d0*sc0 + (float)xv.x*0.5f;
      float a1 = (float)d1*sc1 + (float)xv.y*0.5f;
      float a2 = (float)d2*sc2 + (float)xv.z*0.5f;
      float a3 = (float)d3*sc3 + (float)xv.w*0.5f;
      // sum the two dim-halves (x added half in each lane -> once total)
      a0 += __shfl_xor(a0, 1, 64);
      a1 += __shfl_xor(a1, 1, 64);
      a2 += __shfl_xor(a2, 1, 64);
      a3 += __shfl_xor(a3, 1, 64);
      // gates: 0=i, 1=f, 2=g, 3=o
      c = sigf(a1)*c + sigf(a0)*tanhf_fast(a2);
      float h = sigf(a3)*tanhf_fast(c);
      if (half == 0){
        hout[ts*HH + j] = h;
        int q = (int)rintf(h*127.f);
        q = q<-127?-127:(q>127?127:q);
        int bufbyte = ((step+1)&1)*224 + (j<100 ? j : 112 + (j-100));
        ((unsigned char*)hq)[bufbyte] = (unsigned char)(q & 0xff);
      }
    }
    __syncthreads();
  }
}

// ---------------- K4: token attention-score MLP ----------------
__global__ void k_attn(const float* __restrict__ hf, const float* __restrict__ hb,
    const ushort* w1, const ushort* b1, const ushort* w2, const ushort* b2,
    const ushort* w3, const ushort* b3, float* __restrict__ attns){
  __shared__ float s[2*HH];
  __shared__ float h1[HS], h2v[HS];
  int t = blockIdx.x;
  for (int k=threadIdx.x;k<2*HH;k+=256)
    s[k] = (k<HH) ? hf[t*HH+k] : hb[t*HH + (k-HH)];
  __syncthreads();
  int o = threadIdx.x;
  if (o < HS){
    float acc = bf2f(b1[o]);
    const ushort* wr = w1 + o*2*HH;
    for (int k=0;k<2*HH;k+=4){
      ushort4 wv = *(const ushort4*)(wr+k);
      acc += bf2f(wv.x)*s[k] + bf2f(wv.y)*s[k+1] + bf2f(wv.z)*s[k+2] + bf2f(wv.w)*s[k+3];
    }
    h1[o] = fmaxf(acc, 0.f);
  }
  __syncthreads();
  if (o < HS){
    float acc = bf2f(b2[o]);
    const ushort* wr = w2 + o*HS;
    for (int k=0;k<HS;k+=2) acc += bf2f(wr[k])*h1[k] + bf2f(wr[k+1])*h1[k+1];
    h2v[o] = fmaxf(acc, 0.f);
  }
  __syncthreads();
  if (o == 0){
    float acc = bf2f(b3[0]);
    for (int k=0;k<HS;k++) acc += bf2f(w3[k])*h2v[k];
    attns[t] = acc;
  }
}

// ---------------- K5: span features + mention MLP (8 spans/block) ----------------
// Layer-1: register-tiled f16 dot2. Each thread owns (sp, o0) and accumulates
// 5 output rows o = o0+{0,32,64,96,128}; an 8-uint4 chunk of the G row is
// loaded into VGPRs ONCE and reused for all 5 weight rows -> 4.7x fewer LDS
// reads than the per-(o,k) form (LDS b128 throughput was the loop's longest
// resource). Weight rows stream from L2 (8 lanes share each address).
__global__ void k_ment(const int* __restrict__ sstart, const int* __restrict__ send,
    const int* __restrict__ tok,
    const float* __restrict__ hf, const float* __restrict__ hb,
    const ushort* __restrict__ emb, const float* __restrict__ attns,
    const ushort* wemb,
    const uint* __restrict__ w1h, const ushort* b1, const ushort* w2, const ushort* b2,
    const ushort* w3, const ushort* b3, float* __restrict__ si){
  __shared__ __align__(16) uint Gh[8*PW];       // 8 spans x 1232 f16 (pad 12)
  __shared__ float H1[8][152], H2[8][152];
  __shared__ float aw[8][WMAX];
  __shared__ int stok[8][WMAX];
  __shared__ int sst[8], sen[8], sbin[8];
  int s0 = blockIdx.x*8;
  if (threadIdx.x < 8){
    int sp = threadIdx.x;
    int st = sstart[s0+sp], en = send[s0+sp];
    sst[sp]=st; sen[sp]=en;
    int width = en - st + 1;
    sbin[sp] = binv(width);
    float lg[WMAX]; float mx = -1e30f;
    for (int wt=0; wt<WMAX; ++wt){
      int idx = st + wt; if (idx > TT-1) idx = TT-1;
      float l = (wt < width) ? attns[idx] : -1e9f;
      lg[wt] = l; mx = fmaxf(mx, l);
    }
    float den = 0.f;
    for (int wt=0; wt<WMAX; ++wt){ lg[wt] = __expf(lg[wt]-mx); den += lg[wt]; }
    float inv = 1.f/den;
    for (int wt=0; wt<WMAX; ++wt) aw[sp][wt] = lg[wt]*inv;
  }
  if (threadIdx.x < 8*WMAX){
    int sp = threadIdx.x / WMAX, wt = threadIdx.x - sp*WMAX;
    int idx = sstart[s0+sp] + wt; if (idx > TT-1) idx = TT-1;
    stok[sp][wt] = tok[idx];
  }
  __syncthreads();
  for (int i = threadIdx.x; i < 8*GDIM; i += 256){
    int sp = i / GDIM, f = i - sp*GDIM;
    int st = sst[sp], en = sen[sp];
    float v;
    if (f < HH) v = hf[st*HH + f];
    else if (f < 2*HH) v = hb[st*HH + (f-HH)];
    else if (f < 3*HH) v = hf[en*HH + (f-2*HH)];
    else if (f < 4*HH) v = hb[en*HH + (f-3*HH)];
    else if (f < 4*HH + EE){
      int e = f - 4*HH;
      float acc = 0.f;
      for (int wt=0; wt<WMAX; ++wt)
        acc += aw[sp][wt] * bf2f(emb[stok[sp][wt]*EE + e]);
      v = acc;
    } else {
      v = bf2f(wemb[sbin[sp]*FD + (f - (4*HH+EE))]);
    }
    ((_Float16*)Gh)[sp*(2*PW) + f] = (_Float16)v;
  }
  __syncthreads();
  {
    int sp = threadIdx.x & 7, o0 = threadIdx.x >> 3;   // o0 in 0..31
    const uint* gr = Gh + sp*PW;
    float a[5][4];
#pragma unroll
    for (int oi=0;oi<5;++oi){ a[oi][0]=0.f; a[oi][1]=0.f; a[oi][2]=0.f; a[oi][3]=0.f; }
    for (int kc = 0; kc < 608; kc += 32){
      uint4 g[8];
#pragma unroll
      for (int u=0;u<8;++u) g[u] = *(const uint4*)(gr + kc + u*4);
#pragma unroll
      for (int oi=0;oi<5;++oi){
        const uint* wr = w1h + (o0 + oi*32)*PW + kc;   // rows up to 159 exist (padded)
#pragma unroll
        for (int u=0;u<8;++u){
          uint4 wv = *(const uint4*)(wr + u*4);
          a[oi][0] = fdot2u(wv.x, g[u].x, a[oi][0]);
          a[oi][1] = fdot2u(wv.y, g[u].y, a[oi][1]);
          a[oi][2] = fdot2u(wv.z, g[u].z, a[oi][2]);
          a[oi][3] = fdot2u(wv.w, g[u].w, a[oi][3]);
        }
      }
    }
#pragma unroll
    for (int oi=0;oi<5;++oi){
      int o = o0 + oi*32;
      if (o < HS){
        const uint* wr = w1h + o*PW;
        float acc = bf2f(b1[o]) + (a[oi][0]+a[oi][2]) + (a[oi][1]+a[oi][3]);
        acc = fdot2u(wr[608], gr[608], acc);
        acc = fdot2u(wr[609], gr[609], acc);
        H1[sp][o] = fmaxf(acc, 0.f);
      }
    }
  }
  __syncthreads();
  for (int tt = threadIdx.x; tt < 8*HS; tt += 256){
    int sp = tt & 7, o = tt >> 3;
    float acc = bf2f(b2[o]);
    const ushort* wr = w2 + o*HS;
    for (int k=0;k<HS;k+=2) acc += bf2f(wr[k])*H1[sp][k] + bf2f(wr[k+1])*H1[sp][k+1];
    H2[sp][o] = fmaxf(acc, 0.f);
  }
  __syncthreads();
  if (threadIdx.x < 8){
    int sp = threadIdx.x;
    float acc = bf2f(b3[0]);
    for (int k=0;k<HS;k++) acc += bf2f(w3[k])*H2[sp][k];
    si[s0+sp] = sanit(acc);
  }
}

// ---------------- K6: top-384 + index-ordered compaction (single block) ----------------
__global__ __launch_bounds__(1024) void k_select(const float* __restrict__ si,
    const int* __restrict__ sstart, const int* __restrict__ send,
    uint* __restrict__ keysb, int* __restrict__ keep, float* __restrict__ sk,
    int* __restrict__ stk, int* __restrict__ enk){
  __shared__ uint hist[256];
  __shared__ uint sG[1024], sE[1024];
  __shared__ uint bc[2];
  int tid = threadIdx.x;
  if (tid < NK){ keep[tid]=0; sk[tid]=0.f; stk[tid]=0; enk[tid]=0; }
  for (int i=tid;i<NS;i+=1024){
    uint u = __float_as_uint(si[i]);
    uint m = (u & 0x80000000u) ? ~u : (u | 0x80000000u);  // order-preserving map
    keysb[i] = m;
  }
  __syncthreads();
  uint prefix=0, mask=0; int K = NK;
  for (int p=3;p>=0;--p){
    int sh = p*8;
    if (tid<256) hist[tid]=0;
    __syncthreads();
    for (int i=tid;i<NS;i+=1024){
      uint m = keysb[i];
      if ((m & mask) == prefix) atomicAdd(&hist[(m>>sh)&255u], 1u);
    }
    __syncthreads();
    if (tid==0){
      uint cum=0;
      bc[0]=0; bc[1]=(uint)K;
      for (int b=255; b>=0; --b){
        uint c = hist[b];
        if ((uint)K <= cum + c){ bc[0]=(uint)b; bc[1]=(uint)(K - (int)cum); break; }
        cum += c;
      }
    }
    __syncthreads();
    prefix |= bc[0] << sh;
    mask |= 0xFFu << sh;
    K = (int)bc[1];
    __syncthreads();
  }
  const uint V = prefix; const uint Eneed = (uint)K;
  int base = tid*20;
  uint cg=0, ce=0;
  for (int r=0;r<20;++r){
    uint m = keysb[base+r];
    cg += (m > V); ce += (m == V);
  }
  sG[tid]=cg; sE[tid]=ce;
  __syncthreads();
  for (int off=1; off<1024; off<<=1){
    uint aG=0,aE=0;
    if (tid>=off){ aG=sG[tid-off]; aE=sE[tid-off]; }
    __syncthreads();
    if (tid>=off){ sG[tid]+=aG; sE[tid]+=aE; }
    __syncthreads();
  }
  uint gbase = sG[tid]-cg, ebase = sE[tid]-ce;
  uint gseen=0, eseen=0;
  for (int r=0;r<20;++r){
    int i = base+r;
    uint m = keysb[i];
    if (m > V){
      uint eb = ebase+eseen; if (eb > Eneed) eb = Eneed;
      uint pos = gbase + gseen + eb;
      if (pos < NK){ keep[pos]=i; sk[pos]=si[i]; stk[pos]=sstart[i]; enk[pos]=send[i]; }
      gseen++;
    } else if (m == V){
      uint eb = ebase + eseen;
      if (eb < Eneed){
        uint pos = gbase + gseen + eb;
        if (pos < NK){ keep[pos]=i; sk[pos]=si[i]; stk[pos]=sstart[i]; enk[pos]=send[i]; }
      }
      eseen++;
    }
  }
}

// ---------------- K7: rebuild g for kept spans ----------------
__global__ void k_gk(const int* __restrict__ keep, const int* __restrict__ tok,
    const float* __restrict__ hf, const float* __restrict__ hb,
    const ushort* __restrict__ emb, const float* __restrict__ attns,
    const ushort* wemb, const int* __restrict__ sstart, const int* __restrict__ send,
    float* __restrict__ gk){
  __shared__ float aw[WMAX];
  __shared__ int stok1[WMAX];
  __shared__ int sstv, senv, sbinv;
  int b = blockIdx.x;
  if (threadIdx.x == 0){
    int s = keep[b]; s = s < 0 ? 0 : (s >= NS ? NS-1 : s);
    int st = sstart[s], en = send[s];
    sstv=st; senv=en;
    int width = en-st+1;
    sbinv = binv(width);
    float lg[WMAX]; float mx=-1e30f;
    for (int wt=0;wt<WMAX;++wt){
      int idx = st+wt; if (idx>TT-1) idx=TT-1;
      float l = (wt<width)? attns[idx] : -1e9f;
      lg[wt]=l; mx=fmaxf(mx,l);
    }
    float den=0.f;
    for (int wt=0;wt<WMAX;++wt){ lg[wt]=__expf(lg[wt]-mx); den+=lg[wt]; }
    float inv=1.f/den;
    for (int wt=0;wt<WMAX;++wt) aw[wt]=lg[wt]*inv;
  }
  if (threadIdx.x < WMAX){
    int s = keep[b]; s = s < 0 ? 0 : (s >= NS ? NS-1 : s);
    int idx = sstart[s] + threadIdx.x; if (idx>TT-1) idx=TT-1;
    stok1[threadIdx.x] = tok[idx];
  }
  __syncthreads();
  int st=sstv, en=senv;
  for (int f=threadIdx.x; f<GDIM; f+=256){
    float v;
    if (f < HH) v = hf[st*HH + f];
    else if (f < 2*HH) v = hb[st*HH + (f-HH)];
    else if (f < 3*HH) v = hf[en*HH + (f-2*HH)];
    else if (f < 4*HH) v = hb[en*HH + (f-3*HH)];
    else if (f < 4*HH + EE){
      int e = f - 4*HH;
      float acc = 0.f;
      for (int wt=0; wt<WMAX; ++wt)
        acc += aw[wt] * bf2f(emb[stok1[wt]*EE + e]);
      v = acc;
    } else {
      v = bf2f(wemb[sbinv*FD + (f - (4*HH+EE))]);
    }
    gk[b*GDIM + f] = v;
  }
}

// ---------------- K8a: P[i]=w1a.gk[i], Q[i]=w1b.gk[i]; also eps column ----------------
__global__ void k_pq(const float* __restrict__ gk, const ushort* __restrict__ w1,
                     float* __restrict__ P, float* __restrict__ Q, float* __restrict__ out){
  __shared__ __align__(16) float gi[GDIM];
  int i = blockIdx.x, which = blockIdx.y;
  for (int k=threadIdx.x;k<GDIM;k+=256) gi[k]=gk[i*GDIM+k];
  __syncthreads();
  if (which==0 && threadIdx.x==0) out[i*OUTC + NA] = 0.0f;   // eps column
  int o = threadIdx.x;
  if (o < HS){
    const ushort* wr = w1 + o*3680 + which*GDIM;
    float acc=0.f;
    for (int k=0;k<GDIM;k+=4){
      ushort4 wv = *(const ushort4*)(wr+k);
      acc += bf2f(wv.x)*gi[k]+bf2f(wv.y)*gi[k+1]+bf2f(wv.z)*gi[k+2]+bf2f(wv.w)*gi[k+3];
    }
    (which? Q : P)[i*HS+o] = acc;
  }
}

// ---------------- K8b: pair MLP (decomposed layer-1), 16 antecedents/block ----------------
// GIJ packed f16 in LDS; layer-1 register-tiled like k_ment (8-uint4 GIJ chunk
// in VGPRs reused across the thread's 5 weight rows).
__global__ void k_pair(const float* __restrict__ gk, const float* __restrict__ P,
    const float* __restrict__ Q, const float* __restrict__ sk,
    const int* __restrict__ stk, const int* __restrict__ enk,
    const uint* __restrict__ w1h, const ushort* w1, const ushort* b1,
    const ushort* w2, const ushort* b2,
    const ushort* w3, const ushort* b3, const ushort* demb, float* __restrict__ out){
  __shared__ __align__(16) float gi[GDIM];
  __shared__ float Pi[152];
  __shared__ float Dall[9*HS];
  __shared__ __align__(16) uint GIJp[8*PW];     // 8 dd x 1232 f16
  __shared__ float H1[8][152], H2[8][152];
  __shared__ int jcA[16], dbA[16], vA[16];
  __shared__ float skj[16];
  int i = blockIdx.x;
  int d0 = blockIdx.y*16;
  if (i - 1 - d0 < 0){
    for (int d = threadIdx.x; d < 16; d += 256) out[i*OUTC + d0 + d] = -1e9f;
    return;
  }
  for (int k=threadIdx.x;k<GDIM;k+=256) gi[k]=gk[i*GDIM+k];
  for (int o=threadIdx.x;o<HS;o+=256) Pi[o]=P[i*HS+o];
  if (threadIdx.x < 16){
    int dcol = d0 + threadIdx.x;
    int j = i - 1 - dcol;
    int jc = j<0?0:j;
    vA[threadIdx.x]=(j>=0);
    jcA[threadIdx.x]=jc;
    dbA[threadIdx.x]=binv(enk[i]-stk[jc]);
    skj[threadIdx.x]=sk[jc];
  }
  for (int tt=threadIdx.x; tt<9*HS; tt+=256){
    int o = tt/9, b = tt - (tt/9)*9;
    float acc = bf2f(b1[o]);
    const ushort* wr = w1 + o*3680 + 3660;
    const ushort* de = demb + b*FD;
    for (int k=0;k<FD;k++) acc += bf2f(wr[k])*bf2f(de[k]);
    Dall[b*HS+o] = acc;
  }
  __syncthreads();
  float ski = sk[i];
  for (int dt=0; dt<2; ++dt){
    if (i - 1 - (d0 + dt*8) < 0){
      if (threadIdx.x < 8) out[i*OUTC + d0 + dt*8 + threadIdx.x] = -1e9f;
      continue;
    }
    __syncthreads();
    for (int idx=threadIdx.x; idx<8*610; idx+=256){
      int dd = idx / 610, kp = idx - dd*610;
      const float2 gj = *(const float2*)&gk[jcA[dt*8+dd]*GDIM + 2*kp];
      const float2 gv = *(const float2*)&gi[2*kp];
      GIJp[dd*PW + kp] = pk2(gv.x*gj.x, gv.y*gj.y);
    }
    __syncthreads();
    {
      int dd = threadIdx.x & 7, o0 = threadIdx.x >> 3;   // o0 in 0..31
      const uint* gr = GIJp + dd*PW;
      float a[5][4];
#pragma unroll
      for (int oi=0;oi<5;++oi){ a[oi][0]=0.f; a[oi][1]=0.f; a[oi][2]=0.f; a[oi][3]=0.f; }
      for (int kc = 0; kc < 608; kc += 32){
        uint4 g[8];
#pragma unroll
        for (int u=0;u<8;++u) g[u] = *(const uint4*)(gr + kc + u*4);
#pragma unroll
        for (int oi=0;oi<5;++oi){
          const uint* wr = w1h + (o0 + oi*32)*PW + kc;   // rows up to 159 exist (padded)
#pragma unroll
          for (int u=0;u<8;++u){
            uint4 wv = *(const uint4*)(wr + u*4);
            a[oi][0] = fdot2u(wv.x, g[u].x, a[oi][0]);
            a[oi][1] = fdot2u(wv.y, g[u].y, a[oi][1]);
            a[oi][2] = fdot2u(wv.z, g[u].z, a[oi][2]);
            a[oi][3] = fdot2u(wv.w, g[u].w, a[oi][3]);
          }
        }
      }
      int d = dt*8+dd;
#pragma unroll
      for (int oi=0;oi<5;++oi){
        int o = o0 + oi*32;
        if (o < HS){
          const uint* wr = w1h + o*PW;
          float acc = (a[oi][0]+a[oi][2]) + (a[oi][1]+a[oi][3]);
          acc = fdot2u(wr[608], gr[608], acc);
          acc = fdot2u(wr[609], gr[609], acc);
          acc += Pi[o] + Q[jcA[d]*HS+o] + Dall[dbA[d]*HS+o];
          H1[dd][o] = fmaxf(acc, 0.f);
        }
      }
    }
    __syncthreads();
    {
      int dd = threadIdx.x & 7, og = threadIdx.x >> 3;
      for (int o=og;o<HS;o+=32){
        float acc = bf2f(b2[o]);
        const ushort* wr = w2 + o*HS;
        for (int k=0;k<HS;k+=2) acc += bf2f(wr[k])*H1[dd][k] + bf2f(wr[k+1])*H1[dd][k+1];
        H2[dd][o]=fmaxf(acc,0.f);
      }
    }
    __syncthreads();
    if (threadIdx.x < 8){
      int dd = threadIdx.x;
      float acc = bf2f(b3[0]);
      for (int k=0;k<HS;k++) acc += bf2f(w3[k])*H2[dd][k];
      int d = dt*8+dd;
      float raw = sanit(ski + skj[d] + acc);
      float v = vA[d] ? raw : -1e9f;
      out[i*OUTC + d0 + d] = v;
    }
  }
}

extern "C" void kernel_launch(void* const* d_in, const int* in_sizes, int n_in,
                              void* d_out, int out_size, void* d_ws, size_t ws_size,
                              hipStream_t stream){
  (void)in_sizes; (void)n_in; (void)out_size; (void)ws_size;
  const int*    tok   = (const int*)d_in[0];
  const int*    sst   = (const int*)d_in[1];
  const int*    sen   = (const int*)d_in[2];
  const ushort* emb   = (const ushort*)d_in[3];
  const ushort* wih_f = (const ushort*)d_in[4];
  const ushort* whh_f = (const ushort*)d_in[5];
  const ushort* b_f   = (const ushort*)d_in[6];
  const ushort* wih_b = (const ushort*)d_in[7];
  const ushort* whh_b = (const ushort*)d_in[8];
  const ushort* b_b   = (const ushort*)d_in[9];
  const ushort* aw1=(const ushort*)d_in[10]; const ushort* ab1=(const ushort*)d_in[11];
  const ushort* aw2=(const ushort*)d_in[12]; const ushort* ab2=(const ushort*)d_in[13];
  const ushort* aw3=(const ushort*)d_in[14]; const ushort* ab3=(const ushort*)d_in[15];
  const ushort* wemb=(const ushort*)d_in[16];
  const ushort* mw1=(const ushort*)d_in[17]; const ushort* mb1=(const ushort*)d_in[18];
  const ushort* mw2=(const ushort*)d_in[19]; const ushort* mb2=(const ushort*)d_in[20];
  const ushort* mw3=(const ushort*)d_in[21]; const ushort* mb3=(const ushort*)d_in[22];
  const ushort* demb=(const ushort*)d_in[23];
  const ushort* pw1=(const ushort*)d_in[24]; const ushort* pb1=(const ushort*)d_in[25];
  const ushort* pw2=(const ushort*)d_in[26]; const ushort* pb2=(const ushort*)d_in[27];
  const ushort* pw3=(const ushort*)d_in[28]; const ushort* pb3=(const ushort*)d_in[29];
  float* out = (float*)d_out;

  float* ws     = (float*)d_ws;
  float* hfw    = ws;                       // 409600
  float* hbw    = hfw + TT*HH;              // 409600
  float* attns  = hbw + TT*HH;              // 2048
  float* si     = attns + TT;               // 20480
  float* sk     = si + NS;                  // 384
  float* Pb     = sk + NK;                  // 57600
  float* Qb     = Pb + NK*HS;               // 57600
  float* gkw    = Qb + NK*HS;               // 468480
  _Float16* Xf  = (_Float16*)(gkw + NK*GDIM); // 1638400 halves
  _Float16* Xb  = Xf + TT*G4;                 // 1638400 halves
  int*   keep   = (int*)(Xb + TT*G4);       // 384
  int*   stk    = keep + NK;                // 384
  int*   enk    = stk + NK;                 // 384
  uint*  keysb  = (uint*)(enk + NK);        // 20480
  uint*  w1hm   = keysb + NS;               // 160 x PW dwords (f16 ment layer-1, padded rows)
  uint*  w1hp   = w1hm + 160*PW;            // 160 x PW dwords (f16 pair layer-1 GIJ, padded rows)
  // total ~13.2 MB of d_ws

  k_prep<<<(HS*GDIM+255)/256,256,0,stream>>>(mw1, pw1, w1hm, w1hp);
  k_xproj<<<TT/4,256,0,stream>>>(tok, emb, wih_f, b_f, wih_b, b_b, Xf, Xb);
  k_lstm<<<2,448,0,stream>>>(whh_f, whh_b, Xf, Xb, hfw, hbw);
  k_attn<<<TT,256,0,stream>>>(hfw,hbw,aw1,ab1,aw2,ab2,aw3,ab3,attns);
  k_ment<<<NS/8,256,0,stream>>>(sst,sen,tok,hfw,hbw,emb,attns,wemb,w1hm,mb1,mw2,mb2,mw3,mb3,si);
  k_select<<<1,1024,0,stream>>>(si,sst,sen,keysb,keep,sk,stk,enk);
  k_gk<<<NK,256,0,stream>>>(keep,tok,hfw,hbw,emb,attns,wemb,sst,sen,gkw);
  k_pq<<<dim3(NK,2),256,0,stream>>>(gkw,pw1,Pb,Qb,out);
  k_pair<<<dim3(NK,8),256,0,stream>>>(gkw,Pb,Qb,sk,stk,enk,w1hp,pw1,pb1,pw2,pb2,pw3,pb3,demb,out);
}